// Round 1
// baseline (13576.216 us; speedup 1.0000x reference)
//
#include <hip/hip_runtime.h>
#include <math.h>

#define D 32

__device__ __forceinline__ float logsigf(float x) {
  // log(sigmoid(x)) stable
  return fminf(x, 0.f) - log1pf(expf(-fabsf(x)));
}

__global__ void deg_kernel(const int* __restrict__ edges, int E, int Nu,
                           int* __restrict__ deg) {
  int e = blockIdx.x * blockDim.x + threadIdx.x;
  if (e >= E) return;
  int u = edges[2 * e];
  int v = edges[2 * e + 1] + Nu;
  atomicAdd(&deg[u], 1);
  atomicAdd(&deg[v], 1);
}

__global__ void dinv_kernel(const int* __restrict__ a, const int* __restrict__ b,
                            float* __restrict__ dinv, int N) {
  int n = blockIdx.x * blockDim.x + threadIdx.x;
  if (n >= N) return;
  int d = a[n] + (b != nullptr ? b[n] : 0);
  dinv[n] = (d > 0) ? rsqrtf((float)d) : 0.f;
}

// Symmetric normalized scatter: for each undirected edge (u, v):
//   nxt[v] += w*cur[u];  nxt[u] += w*cur[v];  w = dinv[u]*dinv[v]
// 8 threads per edge, one float4 chunk each.
__global__ void scatter_kernel(const int* __restrict__ edges, int E, int Nu,
                               const float* __restrict__ dinv,
                               const float4* __restrict__ cur,
                               float* __restrict__ nxt) {
  int t = blockIdx.x * blockDim.x + threadIdx.x;
  int e = t >> 3;
  if (e >= E) return;
  int lane = t & 7;
  int u = edges[2 * e];
  int v = edges[2 * e + 1] + Nu;
  float w = dinv[u] * dinv[v];
  float4 au = cur[u * 8 + lane];
  float4 av = cur[v * 8 + lane];
  float* pv = nxt + (size_t)(v * 8 + lane) * 4;
  float* pu = nxt + (size_t)(u * 8 + lane) * 4;
  atomicAdd(pv + 0, w * au.x); atomicAdd(pv + 1, w * au.y);
  atomicAdd(pv + 2, w * au.z); atomicAdd(pv + 3, w * au.w);
  atomicAdd(pu + 0, w * av.x); atomicAdd(pu + 1, w * av.y);
  atomicAdd(pu + 2, w * av.z); atomicAdd(pu + 3, w * av.w);
}

__global__ void avg3_kernel(const float4* __restrict__ e, const float4* __restrict__ b,
                            const float4* __restrict__ c, float4* __restrict__ out,
                            int n4) {
  int i = blockIdx.x * blockDim.x + threadIdx.x;
  if (i >= n4) return;
  float4 x = e[i], y = b[i], z = c[i];
  out[i] = make_float4((x.x + y.x + z.x) * (1.f / 3.f),
                       (x.y + y.y + z.y) * (1.f / 3.f),
                       (x.z + y.z + z.z) * (1.f / 3.f),
                       (x.w + y.w + z.w) * (1.f / 3.f));
}

__device__ __forceinline__ float dot3_rows(const float* __restrict__ E0,
                                           const float* __restrict__ B0,
                                           const float* __restrict__ C0,
                                           int r1, int r2) {
  const float* e1 = E0 + (size_t)r1 * D;
  const float* b1 = B0 + (size_t)r1 * D;
  const float* c1 = C0 + (size_t)r1 * D;
  const float* e2 = E0 + (size_t)r2 * D;
  const float* b2 = B0 + (size_t)r2 * D;
  const float* c2 = C0 + (size_t)r2 * D;
  float s = 0.f;
#pragma unroll
  for (int k = 0; k < D; ++k)
    s += (e1[k] + b1[k] + c1[k]) * (e2[k] + b2[k] + c2[k]);
  return s * (1.f / 9.f);
}

__device__ __forceinline__ float dot1_rows(const float* __restrict__ A, int r1, int r2) {
  const float* a1 = A + (size_t)r1 * D;
  const float* a2 = A + (size_t)r2 * D;
  float s = 0.f;
#pragma unroll
  for (int k = 0; k < D; ++k) s += a1[k] * a2[k];
  return s;
}

// scores from a lightgcn output represented as (E0 + B + C)/3
__global__ void score3_kernel(const float* __restrict__ E0, const float* __restrict__ B0,
                              const float* __restrict__ C0, const int* __restrict__ batch,
                              int Bsz, int Nu, float* __restrict__ outp,
                              float* __restrict__ outn) {
  int b = blockIdx.x * blockDim.x + threadIdx.x;
  if (b >= Bsz) return;
  int u = batch[b * 9 + 0];
  int p = batch[b * 9 + 1] + Nu;
  int n = batch[b * 9 + 2] + Nu;
  outp[b] = fmaxf(dot3_rows(E0, B0, C0, u, p), 0.f);
  outn[b] = fmaxf(dot3_rows(E0, B0, C0, u, n), 0.f);
}

// scores from a materialized array A
__global__ void score1_kernel(const float* __restrict__ A, const int* __restrict__ batch,
                              int Bsz, int Nu, float* __restrict__ outp,
                              float* __restrict__ outn) {
  int b = blockIdx.x * blockDim.x + threadIdx.x;
  if (b >= Bsz) return;
  int u = batch[b * 9 + 0];
  int p = batch[b * 9 + 1] + Nu;
  int n = batch[b * 9 + 2] + Nu;
  outp[b] = fmaxf(dot1_rows(A, u, p), 0.f);
  outn[b] = fmaxf(dot1_rows(A, u, n), 0.f);
}

__global__ void auxloss_kernel(const float* __restrict__ A, const int* __restrict__ batch,
                               int Bsz, int Nu, int idx, float* __restrict__ acc) {
  int b = blockIdx.x * blockDim.x + threadIdx.x;
  float l = 0.f;
  if (b < Bsz) {
    const int* r = batch + b * 9 + 3 * (1 + idx);
    int u = r[0];
    int p = r[1] + Nu;
    int n = r[2] + Nu;
    float ps = dot1_rows(A, u, p);
    float ns = dot1_rows(A, u, n);
    l = -logsigf(ps - ns);  // no relu here
  }
  for (int o = 32; o > 0; o >>= 1) l += __shfl_down(l, o);
  if ((threadIdx.x & 63) == 0) atomicAdd(acc, l);
}

__global__ void recloss_kernel(const float* __restrict__ cps, const float* __restrict__ cns,
                               const float* __restrict__ aps, const float* __restrict__ ans_,
                               const float* __restrict__ dps, const float* __restrict__ dns,
                               int Bsz, int NA, float* __restrict__ acc) {
  int b = blockIdx.x * blockDim.x + threadIdx.x;
  float l = 0.f;
  if (b < Bsz) {
    float dp = 0.f, dn = 0.f, cap = 0.f, can = 0.f;
    for (int i = 0; i < NA; ++i) {
      dp += dps[i * Bsz + b];
      dn += dns[i * Bsz + b];
      cap += cps[i * Bsz + b] * aps[i * Bsz + b];
      can += cns[i * Bsz + b] * ans_[i * Bsz + b];
    }
    float p = dp * cap;
    float n = dn * can;
    l = -logsigf(p - n);
  }
  for (int o = 32; o > 0; o >>= 1) l += __shfl_down(l, o);
  if ((threadIdx.x & 63) == 0) atomicAdd(acc, l);
}

__global__ void sumsq_kernel(const float4* __restrict__ x, int n4, float* __restrict__ acc) {
  int i = blockIdx.x * blockDim.x + threadIdx.x;
  int stride = gridDim.x * blockDim.x;
  float s = 0.f;
  for (; i < n4; i += stride) {
    float4 v = x[i];
    s += v.x * v.x + v.y * v.y + v.z * v.z + v.w * v.w;
  }
  for (int o = 32; o > 0; o >>= 1) s += __shfl_down(s, o);
  if ((threadIdx.x & 63) == 0) atomicAdd(acc, s);
}

__global__ void final_kernel(const float* __restrict__ accs, int Bsz, int NA, int NiRows,
                             float* __restrict__ out) {
  float rec = accs[NA] / (float)Bsz;
  float aux = 0.f;
  for (int i = 0; i < NA; ++i) aux += accs[i] / (float)Bsz;
  aux /= (float)NA;
  float embl = (sqrtf(accs[NA + 1]) + sqrtf(accs[NA + 2])) / (float)NiRows;
  out[0] = rec + 0.5f * aux + 1e-4f * embl;
}

extern "C" void kernel_launch(void* const* d_in, const int* in_sizes, int n_in,
                              void* d_out, int out_size, void* d_ws, size_t ws_size,
                              hipStream_t stream) {
  const float* user_emb = (const float*)d_in[0];
  const float* item_emb = (const float*)d_in[1];
  const int* batch = (const int*)d_in[2];
  const int* aux_edges = (const int*)d_in[3];
  const int* tgt_edges = (const int*)d_in[4];

  const int NuRows = in_sizes[0] / D;          // 100001
  const int NiRows = in_sizes[1] / D;          // 50001
  const int Bsz = in_sizes[2] / 9;             // 4096
  const int E = in_sizes[4] / 2;               // 1,000,000
  const int NA = in_sizes[3] / (2 * E);        // 2
  const int N = NuRows + NiRows;               // 150002
  const size_t rowElems = (size_t)N * D;       // floats per node buffer
  const size_t rowBytes = rowElems * sizeof(float);

  // workspace layout
  float* EMB = (float*)d_ws;               // concat(user_emb, item_emb)
  float* A = EMB + rowElems;               // materialized ae
  float* Bb = A + rowElems;                // layer-1 output
  float* Cc = Bb + rowElems;               // layer-2 output
  int* deg_tgt = (int*)(Cc + rowElems);
  int* deg_aux = deg_tgt + N;
  float* dinv_tgt = (float*)(deg_aux + N);
  float* dinv_aux = dinv_tgt + N;
  float* dinv_comb = dinv_aux + N;
  float* cps = dinv_comb + N;
  float* cns = cps + (size_t)NA * Bsz;
  float* aps = cns + (size_t)NA * Bsz;
  float* ans_ = aps + (size_t)NA * Bsz;
  float* dps = ans_ + (size_t)NA * Bsz;
  float* dns = dps + (size_t)NA * Bsz;
  float* accs = dns + (size_t)NA * Bsz;    // [NA aux][rec][sumsq_u][sumsq_i]

  const int TB = 256;
  const int gE = (E + TB - 1) / TB;
  const int gE8 = (E * 8 + TB - 1) / TB;
  const int gN = (N + TB - 1) / TB;
  const int gB = (Bsz + TB - 1) / TB;
  const int gRow4 = (int)((rowElems / 4 + TB - 1) / TB);

  // EMB = concat(user_emb, item_emb)
  hipMemcpyAsync(EMB, user_emb, (size_t)NuRows * D * sizeof(float),
                 hipMemcpyDeviceToDevice, stream);
  hipMemcpyAsync(EMB + (size_t)NuRows * D, item_emb, (size_t)NiRows * D * sizeof(float),
                 hipMemcpyDeviceToDevice, stream);

  // target-graph degrees (shared across idx)
  hipMemsetAsync(deg_tgt, 0, (size_t)N * sizeof(int), stream);
  deg_kernel<<<gE, TB, 0, stream>>>(tgt_edges, E, NuRows, deg_tgt);
  dinv_kernel<<<gN, TB, 0, stream>>>(deg_tgt, nullptr, dinv_tgt, N);

  hipMemsetAsync(accs, 0, (size_t)(NA + 3) * sizeof(float), stream);

  for (int idx = 0; idx < NA; ++idx) {
    const int* ae_edges = aux_edges + (size_t)idx * E * 2;

    hipMemsetAsync(deg_aux, 0, (size_t)N * sizeof(int), stream);
    deg_kernel<<<gE, TB, 0, stream>>>(ae_edges, E, NuRows, deg_aux);
    dinv_kernel<<<gN, TB, 0, stream>>>(deg_aux, nullptr, dinv_aux, N);
    dinv_kernel<<<gN, TB, 0, stream>>>(deg_aux, deg_tgt, dinv_comb, N);

    // ---- ce = lightgcn(EMB, comb graph): layers into Bb, Cc ----
    hipMemsetAsync(Bb, 0, rowBytes, stream);
    scatter_kernel<<<gE8, TB, 0, stream>>>(ae_edges, E, NuRows, dinv_comb,
                                           (const float4*)EMB, Bb);
    scatter_kernel<<<gE8, TB, 0, stream>>>(tgt_edges, E, NuRows, dinv_comb,
                                           (const float4*)EMB, Bb);
    hipMemsetAsync(Cc, 0, rowBytes, stream);
    scatter_kernel<<<gE8, TB, 0, stream>>>(ae_edges, E, NuRows, dinv_comb,
                                           (const float4*)Bb, Cc);
    scatter_kernel<<<gE8, TB, 0, stream>>>(tgt_edges, E, NuRows, dinv_comb,
                                           (const float4*)Bb, Cc);
    score3_kernel<<<gB, TB, 0, stream>>>(EMB, Bb, Cc, batch, Bsz, NuRows,
                                         cps + (size_t)idx * Bsz, cns + (size_t)idx * Bsz);

    // ---- ae = lightgcn(EMB, aux graph): layers into Bb, Cc; materialize A ----
    hipMemsetAsync(Bb, 0, rowBytes, stream);
    scatter_kernel<<<gE8, TB, 0, stream>>>(ae_edges, E, NuRows, dinv_aux,
                                           (const float4*)EMB, Bb);
    hipMemsetAsync(Cc, 0, rowBytes, stream);
    scatter_kernel<<<gE8, TB, 0, stream>>>(ae_edges, E, NuRows, dinv_aux,
                                           (const float4*)Bb, Cc);
    avg3_kernel<<<gRow4, TB, 0, stream>>>((const float4*)EMB, (const float4*)Bb,
                                          (const float4*)Cc, (float4*)A,
                                          (int)(rowElems / 4));
    score1_kernel<<<gB, TB, 0, stream>>>(A, batch, Bsz, NuRows,
                                         aps + (size_t)idx * Bsz, ans_ + (size_t)idx * Bsz);
    auxloss_kernel<<<gB, TB, 0, stream>>>(A, batch, Bsz, NuRows, idx, accs + idx);

    // ---- de = lightgcn(A, tgt graph): layers into Bb, Cc ----
    hipMemsetAsync(Bb, 0, rowBytes, stream);
    scatter_kernel<<<gE8, TB, 0, stream>>>(tgt_edges, E, NuRows, dinv_tgt,
                                           (const float4*)A, Bb);
    hipMemsetAsync(Cc, 0, rowBytes, stream);
    scatter_kernel<<<gE8, TB, 0, stream>>>(tgt_edges, E, NuRows, dinv_tgt,
                                           (const float4*)Bb, Cc);
    score3_kernel<<<gB, TB, 0, stream>>>(A, Bb, Cc, batch, Bsz, NuRows,
                                         dps + (size_t)idx * Bsz, dns + (size_t)idx * Bsz);
  }

  // embedding norms
  sumsq_kernel<<<2048, TB, 0, stream>>>((const float4*)user_emb,
                                        (int)((size_t)NuRows * D / 4), accs + NA + 1);
  sumsq_kernel<<<2048, TB, 0, stream>>>((const float4*)item_emb,
                                        (int)((size_t)NiRows * D / 4), accs + NA + 2);

  // front-door rec loss
  recloss_kernel<<<gB, TB, 0, stream>>>(cps, cns, aps, ans_, dps, dns, Bsz, NA, accs + NA);

  final_kernel<<<1, 1, 0, stream>>>(accs, Bsz, NA, NiRows, (float*)d_out);
}

// Round 2
// 2301.456 us; speedup vs baseline: 5.8990x; 5.8990x over previous
//
#include <hip/hip_runtime.h>
#include <math.h>

#define D 32

__device__ __forceinline__ float logsigf(float x) {
  return fminf(x, 0.f) - log1pf(expf(-fabsf(x)));
}

__global__ void deg_kernel(const int* __restrict__ edges, int E, int Nu,
                           int* __restrict__ deg) {
  int e = blockIdx.x * blockDim.x + threadIdx.x;
  if (e >= E) return;
  int u = edges[2 * e];
  int v = edges[2 * e + 1] + Nu;
  atomicAdd(&deg[u], 1);
  atomicAdd(&deg[v], 1);
}

__global__ void dinv_kernel(const int* __restrict__ a, const int* __restrict__ b,
                            float* __restrict__ dinv, int N) {
  int n = blockIdx.x * blockDim.x + threadIdx.x;
  if (n >= N) return;
  int d = a[n] + (b != nullptr ? b[n] : 0);
  dinv[n] = (d > 0) ? rsqrtf((float)d) : 0.f;
}

// Single-workgroup exclusive scan of deg[0..N) -> rowptr[0..N], cursor copy.
// 1024 threads = 16 waves; wave shuffle scan + LDS wave-sum scan.
__global__ void scan_kernel(const int* __restrict__ deg, int N,
                            int* __restrict__ rowptr, int* __restrict__ cursor) {
  __shared__ int wsum[16];
  __shared__ int carry_s;
  const int lane = threadIdx.x & 63;
  const int wid = threadIdx.x >> 6;
  if (threadIdx.x == 0) carry_s = 0;
  __syncthreads();
  for (int base = 0; base < N; base += 1024) {
    int i = base + (int)threadIdx.x;
    int v = (i < N) ? deg[i] : 0;
    // inclusive wave scan
    int s = v;
    #pragma unroll
    for (int o = 1; o < 64; o <<= 1) {
      int t = __shfl_up(s, o);
      if (lane >= o) s += t;
    }
    if (lane == 63) wsum[wid] = s;
    __syncthreads();
    int carry = carry_s;
    __syncthreads();
    if (wid == 0 && lane < 16) {
      int w = wsum[lane];
      int ws = w;
      #pragma unroll
      for (int o = 1; o < 16; o <<= 1) {
        int t = __shfl_up(ws, o);
        if (lane >= o) ws += t;
      }
      wsum[lane] = ws - w;  // exclusive wave offset
      if (lane == 15) carry_s = carry + ws;
    }
    __syncthreads();
    int excl = carry + wsum[wid] + (s - v);
    if (i < N) {
      rowptr[i] = excl;
      cursor[i] = excl;
    }
    __syncthreads();
  }
  if (threadIdx.x == 0) rowptr[N] = carry_s;
}

__global__ void fill_kernel(const int* __restrict__ edges, int E, int Nu,
                            int* __restrict__ cursor, int* __restrict__ col) {
  int e = blockIdx.x * blockDim.x + threadIdx.x;
  if (e >= E) return;
  int u = edges[2 * e];
  int v = edges[2 * e + 1] + Nu;
  col[atomicAdd(&cursor[u], 1)] = v;
  col[atomicAdd(&cursor[v], 1)] = u;
}

// Pull-style propagation: out[n] = dinv[n] * sum_{j in adj(n)} dinv[j]*cur[j]
// 8 threads per node, float4 chunks.
__global__ void gather_kernel(const int* __restrict__ rowptr, const int* __restrict__ col,
                              const float* __restrict__ dinv,
                              const float4* __restrict__ cur, float4* __restrict__ out,
                              int N) {
  int t = blockIdx.x * blockDim.x + threadIdx.x;
  int n = t >> 3;
  if (n >= N) return;
  int lane = t & 7;
  int s = rowptr[n], e = rowptr[n + 1];
  float4 acc = make_float4(0.f, 0.f, 0.f, 0.f);
  for (int j = s; j < e; ++j) {
    int c = col[j];
    float w = dinv[c];
    float4 x = cur[c * 8 + lane];
    acc.x += w * x.x; acc.y += w * x.y; acc.z += w * x.z; acc.w += w * x.w;
  }
  float wn = dinv[n];
  out[n * 8 + lane] = make_float4(wn * acc.x, wn * acc.y, wn * acc.z, wn * acc.w);
}

// Propagation over the union graph (aux edges + tgt edges) with combined dinv.
__global__ void gather2_kernel(const int* __restrict__ rpA, const int* __restrict__ colA,
                               const int* __restrict__ rpT, const int* __restrict__ colT,
                               const float* __restrict__ dinv,
                               const float4* __restrict__ cur, float4* __restrict__ out,
                               int N) {
  int t = blockIdx.x * blockDim.x + threadIdx.x;
  int n = t >> 3;
  if (n >= N) return;
  int lane = t & 7;
  float4 acc = make_float4(0.f, 0.f, 0.f, 0.f);
  int s = rpA[n], e = rpA[n + 1];
  for (int j = s; j < e; ++j) {
    int c = colA[j];
    float w = dinv[c];
    float4 x = cur[c * 8 + lane];
    acc.x += w * x.x; acc.y += w * x.y; acc.z += w * x.z; acc.w += w * x.w;
  }
  s = rpT[n]; e = rpT[n + 1];
  for (int j = s; j < e; ++j) {
    int c = colT[j];
    float w = dinv[c];
    float4 x = cur[c * 8 + lane];
    acc.x += w * x.x; acc.y += w * x.y; acc.z += w * x.z; acc.w += w * x.w;
  }
  float wn = dinv[n];
  out[n * 8 + lane] = make_float4(wn * acc.x, wn * acc.y, wn * acc.z, wn * acc.w);
}

__global__ void avg3_kernel(const float4* __restrict__ e, const float4* __restrict__ b,
                            const float4* __restrict__ c, float4* __restrict__ out,
                            int n4) {
  int i = blockIdx.x * blockDim.x + threadIdx.x;
  if (i >= n4) return;
  float4 x = e[i], y = b[i], z = c[i];
  out[i] = make_float4((x.x + y.x + z.x) * (1.f / 3.f),
                       (x.y + y.y + z.y) * (1.f / 3.f),
                       (x.z + y.z + z.z) * (1.f / 3.f),
                       (x.w + y.w + z.w) * (1.f / 3.f));
}

__device__ __forceinline__ float dot3_rows(const float* __restrict__ E0,
                                           const float* __restrict__ B0,
                                           const float* __restrict__ C0,
                                           int r1, int r2) {
  const float* e1 = E0 + (size_t)r1 * D;
  const float* b1 = B0 + (size_t)r1 * D;
  const float* c1 = C0 + (size_t)r1 * D;
  const float* e2 = E0 + (size_t)r2 * D;
  const float* b2 = B0 + (size_t)r2 * D;
  const float* c2 = C0 + (size_t)r2 * D;
  float s = 0.f;
#pragma unroll
  for (int k = 0; k < D; ++k)
    s += (e1[k] + b1[k] + c1[k]) * (e2[k] + b2[k] + c2[k]);
  return s * (1.f / 9.f);
}

__device__ __forceinline__ float dot1_rows(const float* __restrict__ A, int r1, int r2) {
  const float* a1 = A + (size_t)r1 * D;
  const float* a2 = A + (size_t)r2 * D;
  float s = 0.f;
#pragma unroll
  for (int k = 0; k < D; ++k) s += a1[k] * a2[k];
  return s;
}

__global__ void score3_kernel(const float* __restrict__ E0, const float* __restrict__ B0,
                              const float* __restrict__ C0, const int* __restrict__ batch,
                              int Bsz, int Nu, float* __restrict__ outp,
                              float* __restrict__ outn) {
  int b = blockIdx.x * blockDim.x + threadIdx.x;
  if (b >= Bsz) return;
  int u = batch[b * 9 + 0];
  int p = batch[b * 9 + 1] + Nu;
  int n = batch[b * 9 + 2] + Nu;
  outp[b] = fmaxf(dot3_rows(E0, B0, C0, u, p), 0.f);
  outn[b] = fmaxf(dot3_rows(E0, B0, C0, u, n), 0.f);
}

__global__ void score1_kernel(const float* __restrict__ A, const int* __restrict__ batch,
                              int Bsz, int Nu, float* __restrict__ outp,
                              float* __restrict__ outn) {
  int b = blockIdx.x * blockDim.x + threadIdx.x;
  if (b >= Bsz) return;
  int u = batch[b * 9 + 0];
  int p = batch[b * 9 + 1] + Nu;
  int n = batch[b * 9 + 2] + Nu;
  outp[b] = fmaxf(dot1_rows(A, u, p), 0.f);
  outn[b] = fmaxf(dot1_rows(A, u, n), 0.f);
}

__global__ void auxloss_kernel(const float* __restrict__ A, const int* __restrict__ batch,
                               int Bsz, int Nu, int idx, float* __restrict__ acc) {
  int b = blockIdx.x * blockDim.x + threadIdx.x;
  float l = 0.f;
  if (b < Bsz) {
    const int* r = batch + b * 9 + 3 * (1 + idx);
    int u = r[0];
    int p = r[1] + Nu;
    int n = r[2] + Nu;
    float ps = dot1_rows(A, u, p);
    float ns = dot1_rows(A, u, n);
    l = -logsigf(ps - ns);
  }
  for (int o = 32; o > 0; o >>= 1) l += __shfl_down(l, o);
  if ((threadIdx.x & 63) == 0) atomicAdd(acc, l);
}

__global__ void recloss_kernel(const float* __restrict__ cps, const float* __restrict__ cns,
                               const float* __restrict__ aps, const float* __restrict__ ans_,
                               const float* __restrict__ dps, const float* __restrict__ dns,
                               int Bsz, int NA, float* __restrict__ acc) {
  int b = blockIdx.x * blockDim.x + threadIdx.x;
  float l = 0.f;
  if (b < Bsz) {
    float dp = 0.f, dn = 0.f, cap = 0.f, can = 0.f;
    for (int i = 0; i < NA; ++i) {
      dp += dps[i * Bsz + b];
      dn += dns[i * Bsz + b];
      cap += cps[i * Bsz + b] * aps[i * Bsz + b];
      can += cns[i * Bsz + b] * ans_[i * Bsz + b];
    }
    l = -logsigf(dp * cap - dn * can);
  }
  for (int o = 32; o > 0; o >>= 1) l += __shfl_down(l, o);
  if ((threadIdx.x & 63) == 0) atomicAdd(acc, l);
}

__global__ void sumsq_kernel(const float4* __restrict__ x, int n4, float* __restrict__ acc) {
  int i = blockIdx.x * blockDim.x + threadIdx.x;
  int stride = gridDim.x * blockDim.x;
  float s = 0.f;
  for (; i < n4; i += stride) {
    float4 v = x[i];
    s += v.x * v.x + v.y * v.y + v.z * v.z + v.w * v.w;
  }
  for (int o = 32; o > 0; o >>= 1) s += __shfl_down(s, o);
  if ((threadIdx.x & 63) == 0) atomicAdd(acc, s);
}

__global__ void final_kernel(const float* __restrict__ accs, int Bsz, int NA, int NiRows,
                             float* __restrict__ out) {
  float rec = accs[NA] / (float)Bsz;
  float aux = 0.f;
  for (int i = 0; i < NA; ++i) aux += accs[i] / (float)Bsz;
  aux /= (float)NA;
  float embl = (sqrtf(accs[NA + 1]) + sqrtf(accs[NA + 2])) / (float)NiRows;
  out[0] = rec + 0.5f * aux + 1e-4f * embl;
}

extern "C" void kernel_launch(void* const* d_in, const int* in_sizes, int n_in,
                              void* d_out, int out_size, void* d_ws, size_t ws_size,
                              hipStream_t stream) {
  const float* user_emb = (const float*)d_in[0];
  const float* item_emb = (const float*)d_in[1];
  const int* batch = (const int*)d_in[2];
  const int* aux_edges = (const int*)d_in[3];
  const int* tgt_edges = (const int*)d_in[4];

  const int NuRows = in_sizes[0] / D;          // 100001
  const int NiRows = in_sizes[1] / D;          // 50001
  const int Bsz = in_sizes[2] / 9;             // 4096
  const int E = in_sizes[4] / 2;               // 1,000,000
  const int NA = in_sizes[3] / (2 * E);        // 2
  const int N = NuRows + NiRows;               // 150002
  const size_t rowElems = (size_t)N * D;

  // ---- workspace layout ----
  float* EMB = (float*)d_ws;
  float* A = EMB + rowElems;
  float* Bb = A + rowElems;
  float* Cc = Bb + rowElems;
  int* deg_tgt = (int*)(Cc + rowElems);
  int* deg_aux = deg_tgt + N;
  float* dinv_tgt = (float*)(deg_aux + N);
  float* dinv_aux = dinv_tgt + N;
  float* dinv_comb = dinv_aux + N;
  int* rp_tgt = (int*)(dinv_comb + N);         // N+1
  int* rp_aux = rp_tgt + (N + 1);              // N+1
  int* cur_tgt = rp_aux + (N + 1);             // N
  int* cur_aux = cur_tgt + N;                  // N
  int* col_tgt = cur_aux + N;                  // 2E
  int* col_aux = col_tgt + 2 * (size_t)E;      // 2E
  float* cps = (float*)(col_aux + 2 * (size_t)E);
  float* cns = cps + (size_t)NA * Bsz;
  float* aps = cns + (size_t)NA * Bsz;
  float* ans_ = aps + (size_t)NA * Bsz;
  float* dps = ans_ + (size_t)NA * Bsz;
  float* dns = dps + (size_t)NA * Bsz;
  float* accs = dns + (size_t)NA * Bsz;        // [NA aux][rec][sumsq_u][sumsq_i]

  const int TB = 256;
  const int gE = (E + TB - 1) / TB;
  const int gN = (N + TB - 1) / TB;
  const int gN8 = (N * 8 + TB - 1) / TB;
  const int gB = (Bsz + TB - 1) / TB;
  const int gRow4 = (int)((rowElems / 4 + TB - 1) / TB);

  // EMB = concat(user_emb, item_emb)
  hipMemcpyAsync(EMB, user_emb, (size_t)NuRows * D * sizeof(float),
                 hipMemcpyDeviceToDevice, stream);
  hipMemcpyAsync(EMB + (size_t)NuRows * D, item_emb, (size_t)NiRows * D * sizeof(float),
                 hipMemcpyDeviceToDevice, stream);

  // ---- target graph: degrees + CSR (built once) ----
  hipMemsetAsync(deg_tgt, 0, (size_t)N * sizeof(int), stream);
  deg_kernel<<<gE, TB, 0, stream>>>(tgt_edges, E, NuRows, deg_tgt);
  dinv_kernel<<<gN, TB, 0, stream>>>(deg_tgt, nullptr, dinv_tgt, N);
  scan_kernel<<<1, 1024, 0, stream>>>(deg_tgt, N, rp_tgt, cur_tgt);
  fill_kernel<<<gE, TB, 0, stream>>>(tgt_edges, E, NuRows, cur_tgt, col_tgt);

  hipMemsetAsync(accs, 0, (size_t)(NA + 3) * sizeof(float), stream);

  for (int idx = 0; idx < NA; ++idx) {
    const int* ae_edges = aux_edges + (size_t)idx * E * 2;

    // aux graph: degrees + CSR
    hipMemsetAsync(deg_aux, 0, (size_t)N * sizeof(int), stream);
    deg_kernel<<<gE, TB, 0, stream>>>(ae_edges, E, NuRows, deg_aux);
    dinv_kernel<<<gN, TB, 0, stream>>>(deg_aux, nullptr, dinv_aux, N);
    dinv_kernel<<<gN, TB, 0, stream>>>(deg_aux, deg_tgt, dinv_comb, N);
    scan_kernel<<<1, 1024, 0, stream>>>(deg_aux, N, rp_aux, cur_aux);
    fill_kernel<<<gE, TB, 0, stream>>>(ae_edges, E, NuRows, cur_aux, col_aux);

    // ---- ce = lightgcn(EMB, comb graph) ----
    gather2_kernel<<<gN8, TB, 0, stream>>>(rp_aux, col_aux, rp_tgt, col_tgt, dinv_comb,
                                           (const float4*)EMB, (float4*)Bb, N);
    gather2_kernel<<<gN8, TB, 0, stream>>>(rp_aux, col_aux, rp_tgt, col_tgt, dinv_comb,
                                           (const float4*)Bb, (float4*)Cc, N);
    score3_kernel<<<gB, TB, 0, stream>>>(EMB, Bb, Cc, batch, Bsz, NuRows,
                                         cps + (size_t)idx * Bsz, cns + (size_t)idx * Bsz);

    // ---- ae = lightgcn(EMB, aux graph); materialize A ----
    gather_kernel<<<gN8, TB, 0, stream>>>(rp_aux, col_aux, dinv_aux,
                                          (const float4*)EMB, (float4*)Bb, N);
    gather_kernel<<<gN8, TB, 0, stream>>>(rp_aux, col_aux, dinv_aux,
                                          (const float4*)Bb, (float4*)Cc, N);
    avg3_kernel<<<gRow4, TB, 0, stream>>>((const float4*)EMB, (const float4*)Bb,
                                          (const float4*)Cc, (float4*)A,
                                          (int)(rowElems / 4));
    score1_kernel<<<gB, TB, 0, stream>>>(A, batch, Bsz, NuRows,
                                         aps + (size_t)idx * Bsz, ans_ + (size_t)idx * Bsz);
    auxloss_kernel<<<gB, TB, 0, stream>>>(A, batch, Bsz, NuRows, idx, accs + idx);

    // ---- de = lightgcn(A, tgt graph) ----
    gather_kernel<<<gN8, TB, 0, stream>>>(rp_tgt, col_tgt, dinv_tgt,
                                          (const float4*)A, (float4*)Bb, N);
    gather_kernel<<<gN8, TB, 0, stream>>>(rp_tgt, col_tgt, dinv_tgt,
                                          (const float4*)Bb, (float4*)Cc, N);
    score3_kernel<<<gB, TB, 0, stream>>>(A, Bb, Cc, batch, Bsz, NuRows,
                                         dps + (size_t)idx * Bsz, dns + (size_t)idx * Bsz);
  }

  sumsq_kernel<<<2048, TB, 0, stream>>>((const float4*)user_emb,
                                        (int)((size_t)NuRows * D / 4), accs + NA + 1);
  sumsq_kernel<<<2048, TB, 0, stream>>>((const float4*)item_emb,
                                        (int)((size_t)NiRows * D / 4), accs + NA + 2);

  recloss_kernel<<<gB, TB, 0, stream>>>(cps, cns, aps, ans_, dps, dns, Bsz, NA, accs + NA);

  final_kernel<<<1, 1, 0, stream>>>(accs, Bsz, NA, NiRows, (float*)d_out);
}

// Round 3
// 1840.760 us; speedup vs baseline: 7.3753x; 1.2503x over previous
//
#include <hip/hip_runtime.h>
#include <math.h>

#define D 32
#define SCAN_CHUNK 2048  // 256 threads x 8 elems per block

__device__ __forceinline__ float logsigf(float x) {
  return fminf(x, 0.f) - log1pf(expf(-fabsf(x)));
}

// ---- CSR build, batched over 3 graphs (seg 0 = tgt, 1 = aux0, 2 = aux1) ----

__global__ void deg_all_kernel(const int2* __restrict__ tgt, const int2* __restrict__ aux,
                               int E, int Nu, int* __restrict__ deg3, int N) {
  int t = blockIdx.x * blockDim.x + threadIdx.x;
  if (t >= 3 * E) return;
  int seg = t / E;
  int e = t - seg * E;
  int2 ed = (seg == 0) ? tgt[e] : aux[(size_t)(seg - 1) * E + e];
  int* deg = deg3 + (size_t)seg * N;
  atomicAdd(&deg[ed.x], 1);
  atomicAdd(&deg[ed.y + Nu], 1);
}

// dinv5: [0]=tgt [1]=aux0 [2]=aux1 [3]=comb0 [4]=comb1
__global__ void dinv_all_kernel(const int* __restrict__ deg3, float* __restrict__ dinv5,
                                int N) {
  int n = blockIdx.x * blockDim.x + threadIdx.x;
  if (n >= N) return;
  int dt = deg3[n], d0 = deg3[N + n], d1 = deg3[2 * N + n];
  dinv5[n]         = dt ? rsqrtf((float)dt) : 0.f;
  dinv5[N + n]     = d0 ? rsqrtf((float)d0) : 0.f;
  dinv5[2 * N + n] = d1 ? rsqrtf((float)d1) : 0.f;
  int c0 = dt + d0, c1 = dt + d1;
  dinv5[3 * N + n] = c0 ? rsqrtf((float)c0) : 0.f;
  dinv5[4 * N + n] = c1 ? rsqrtf((float)c1) : 0.f;
}

// phase 1: per-block sums. grid = 3*NB, block=256
__global__ void scan_p1_kernel(const int* __restrict__ deg3, int N, int NB,
                               int* __restrict__ bsum) {
  __shared__ int red[4];
  int seg = blockIdx.x / NB;
  int blk = blockIdx.x - seg * NB;
  const int* deg = deg3 + (size_t)seg * N;
  int base = blk * SCAN_CHUNK;
  int s = 0;
  for (int k = threadIdx.x; k < SCAN_CHUNK; k += 256) {
    int i = base + k;
    s += (i < N) ? deg[i] : 0;
  }
  for (int o = 32; o > 0; o >>= 1) s += __shfl_down(s, o);
  if ((threadIdx.x & 63) == 0) red[threadIdx.x >> 6] = s;
  __syncthreads();
  if (threadIdx.x == 0) bsum[blockIdx.x] = red[0] + red[1] + red[2] + red[3];
}

// phase 2: exclusive scan of each segment's block sums. grid = 3, block = 64
__global__ void scan_p2_kernel(int* __restrict__ bsum, int NB) {
  int* b = bsum + blockIdx.x * NB;
  int lane = threadIdx.x;
  int carry = 0;
  for (int base = 0; base < NB; base += 64) {
    int i = base + lane;
    int v = (i < NB) ? b[i] : 0;
    int s = v;
    #pragma unroll
    for (int o = 1; o < 64; o <<= 1) {
      int t = __shfl_up(s, o);
      if (lane >= o) s += t;
    }
    if (i < NB) b[i] = carry + s - v;
    carry += __shfl(s, 63);
  }
}

// phase 3: local scan + apply. grid = 3*NB, block=256. writes rowptr + cursor.
__global__ void scan_p3_kernel(const int* __restrict__ deg3, int N, int NB,
                               const int* __restrict__ bsum, int* __restrict__ rp3,
                               int* __restrict__ cur3) {
  __shared__ int wsum[4];
  int seg = blockIdx.x / NB;
  int blk = blockIdx.x - seg * NB;
  const int* deg = deg3 + (size_t)seg * N;
  int* rowptr = rp3 + (size_t)seg * (N + 1);
  int* cursor = cur3 + (size_t)seg * N;
  int lane = threadIdx.x & 63, wid = threadIdx.x >> 6;
  int idx0 = blk * SCAN_CHUNK + threadIdx.x * 8;
  int v[8];
  int tot = 0;
  #pragma unroll
  for (int k = 0; k < 8; ++k) {
    int i = idx0 + k;
    v[k] = (i < N) ? deg[i] : 0;
    tot += v[k];
  }
  int s = tot;
  #pragma unroll
  for (int o = 1; o < 64; o <<= 1) {
    int t = __shfl_up(s, o);
    if (lane >= o) s += t;
  }
  if (lane == 63) wsum[wid] = s;
  __syncthreads();
  int woff = 0;
  for (int w = 0; w < wid; ++w) woff += wsum[w];
  int excl = bsum[blockIdx.x] + woff + (s - tot);
  #pragma unroll
  for (int k = 0; k < 8; ++k) {
    int i = idx0 + k;
    if (i < N) {
      rowptr[i] = excl;
      cursor[i] = excl;
    }
    excl += v[k];
  }
  if (N - 1 >= idx0 && N - 1 < idx0 + 8) rowptr[N] = excl;
}

__global__ void fill_all_kernel(const int2* __restrict__ tgt, const int2* __restrict__ aux,
                                int E, int Nu, int N, int* __restrict__ cur3,
                                int* __restrict__ col_all) {
  int t = blockIdx.x * blockDim.x + threadIdx.x;
  if (t >= 3 * E) return;
  int seg = t / E;
  int e = t - seg * E;
  int2 ed = (seg == 0) ? tgt[e] : aux[(size_t)(seg - 1) * E + e];
  int u = ed.x;
  int v = ed.y + Nu;
  int* cursor = cur3 + (size_t)seg * N;
  int* col = col_all + (size_t)seg * 2 * E;
  col[atomicAdd(&cursor[u], 1)] = v;
  col[atomicAdd(&cursor[v], 1)] = u;
}

// ---- propagation (pull / gather) ----

__global__ void gather_kernel(const int* __restrict__ rowptr, const int* __restrict__ col,
                              const float* __restrict__ dinv,
                              const float4* __restrict__ cur, float4* __restrict__ out,
                              int N) {
  int t = blockIdx.x * blockDim.x + threadIdx.x;
  int n = t >> 3;
  if (n >= N) return;
  int lane = t & 7;
  int s = rowptr[n], e = rowptr[n + 1];
  float4 acc = make_float4(0.f, 0.f, 0.f, 0.f);
  for (int j = s; j < e; ++j) {
    int c = col[j];
    float w = dinv[c];
    float4 x = cur[c * 8 + lane];
    acc.x += w * x.x; acc.y += w * x.y; acc.z += w * x.z; acc.w += w * x.w;
  }
  float wn = dinv[n];
  out[n * 8 + lane] = make_float4(wn * acc.x, wn * acc.y, wn * acc.z, wn * acc.w);
}

__global__ void gather2_kernel(const int* __restrict__ rpA, const int* __restrict__ colA,
                               const int* __restrict__ rpT, const int* __restrict__ colT,
                               const float* __restrict__ dinv,
                               const float4* __restrict__ cur, float4* __restrict__ out,
                               int N) {
  int t = blockIdx.x * blockDim.x + threadIdx.x;
  int n = t >> 3;
  if (n >= N) return;
  int lane = t & 7;
  float4 acc = make_float4(0.f, 0.f, 0.f, 0.f);
  int s = rpA[n], e = rpA[n + 1];
  for (int j = s; j < e; ++j) {
    int c = colA[j];
    float w = dinv[c];
    float4 x = cur[c * 8 + lane];
    acc.x += w * x.x; acc.y += w * x.y; acc.z += w * x.z; acc.w += w * x.w;
  }
  s = rpT[n]; e = rpT[n + 1];
  for (int j = s; j < e; ++j) {
    int c = colT[j];
    float w = dinv[c];
    float4 x = cur[c * 8 + lane];
    acc.x += w * x.x; acc.y += w * x.y; acc.z += w * x.z; acc.w += w * x.w;
  }
  float wn = dinv[n];
  out[n * 8 + lane] = make_float4(wn * acc.x, wn * acc.y, wn * acc.z, wn * acc.w);
}

// fused layer-1: aux graph (dinvA) -> outA, comb graph (dinvC) -> outC; shares aux row reads
__global__ void gather_fused_kernel(const int* __restrict__ rpA, const int* __restrict__ colA,
                                    const int* __restrict__ rpT, const int* __restrict__ colT,
                                    const float* __restrict__ dinvA,
                                    const float* __restrict__ dinvC,
                                    const float4* __restrict__ cur,
                                    float4* __restrict__ outA, float4* __restrict__ outC,
                                    int N) {
  int t = blockIdx.x * blockDim.x + threadIdx.x;
  int n = t >> 3;
  if (n >= N) return;
  int lane = t & 7;
  float4 aA = make_float4(0.f, 0.f, 0.f, 0.f);
  float4 aC = make_float4(0.f, 0.f, 0.f, 0.f);
  int s = rpA[n], e = rpA[n + 1];
  for (int j = s; j < e; ++j) {
    int c = colA[j];
    float wA = dinvA[c];
    float wC = dinvC[c];
    float4 x = cur[c * 8 + lane];
    aA.x += wA * x.x; aA.y += wA * x.y; aA.z += wA * x.z; aA.w += wA * x.w;
    aC.x += wC * x.x; aC.y += wC * x.y; aC.z += wC * x.z; aC.w += wC * x.w;
  }
  s = rpT[n]; e = rpT[n + 1];
  for (int j = s; j < e; ++j) {
    int c = colT[j];
    float wC = dinvC[c];
    float4 x = cur[c * 8 + lane];
    aC.x += wC * x.x; aC.y += wC * x.y; aC.z += wC * x.z; aC.w += wC * x.w;
  }
  float wnA = dinvA[n];
  float wnC = dinvC[n];
  outA[n * 8 + lane] = make_float4(wnA * aA.x, wnA * aA.y, wnA * aA.z, wnA * aA.w);
  outC[n * 8 + lane] = make_float4(wnC * aC.x, wnC * aC.y, wnC * aC.z, wnC * aC.w);
}

// ---- scores / losses ----

__device__ __forceinline__ float dot3_rows(const float* __restrict__ E0,
                                           const float* __restrict__ B0,
                                           const float* __restrict__ C0,
                                           int r1, int r2) {
  const float* e1 = E0 + (size_t)r1 * D;
  const float* b1 = B0 + (size_t)r1 * D;
  const float* c1 = C0 + (size_t)r1 * D;
  const float* e2 = E0 + (size_t)r2 * D;
  const float* b2 = B0 + (size_t)r2 * D;
  const float* c2 = C0 + (size_t)r2 * D;
  float s = 0.f;
#pragma unroll
  for (int k = 0; k < D; ++k)
    s += (e1[k] + b1[k] + c1[k]) * (e2[k] + b2[k] + c2[k]);
  return s * (1.f / 9.f);
}

__device__ __forceinline__ float dot1_rows(const float* __restrict__ A, int r1, int r2) {
  const float* a1 = A + (size_t)r1 * D;
  const float* a2 = A + (size_t)r2 * D;
  float s = 0.f;
#pragma unroll
  for (int k = 0; k < D; ++k) s += a1[k] * a2[k];
  return s;
}

__global__ void score3_kernel(const float* __restrict__ E0, const float* __restrict__ B0,
                              const float* __restrict__ C0, const int* __restrict__ batch,
                              int Bsz, int Nu, float* __restrict__ outp,
                              float* __restrict__ outn) {
  int b = blockIdx.x * blockDim.x + threadIdx.x;
  if (b >= Bsz) return;
  int u = batch[b * 9 + 0];
  int p = batch[b * 9 + 1] + Nu;
  int n = batch[b * 9 + 2] + Nu;
  outp[b] = fmaxf(dot3_rows(E0, B0, C0, u, p), 0.f);
  outn[b] = fmaxf(dot3_rows(E0, B0, C0, u, n), 0.f);
}

__global__ void score1_kernel(const float* __restrict__ A, const int* __restrict__ batch,
                              int Bsz, int Nu, float* __restrict__ outp,
                              float* __restrict__ outn) {
  int b = blockIdx.x * blockDim.x + threadIdx.x;
  if (b >= Bsz) return;
  int u = batch[b * 9 + 0];
  int p = batch[b * 9 + 1] + Nu;
  int n = batch[b * 9 + 2] + Nu;
  outp[b] = fmaxf(dot1_rows(A, u, p), 0.f);
  outn[b] = fmaxf(dot1_rows(A, u, n), 0.f);
}

__global__ void auxloss_kernel(const float* __restrict__ A, const int* __restrict__ batch,
                               int Bsz, int Nu, int idx, float* __restrict__ acc) {
  int b = blockIdx.x * blockDim.x + threadIdx.x;
  float l = 0.f;
  if (b < Bsz) {
    const int* r = batch + b * 9 + 3 * (1 + idx);
    int u = r[0];
    int p = r[1] + Nu;
    int n = r[2] + Nu;
    l = -logsigf(dot1_rows(A, u, p) - dot1_rows(A, u, n));
  }
  for (int o = 32; o > 0; o >>= 1) l += __shfl_down(l, o);
  if ((threadIdx.x & 63) == 0) atomicAdd(acc, l);
}

__global__ void avg3_kernel(const float4* __restrict__ e, const float4* __restrict__ b,
                            const float4* __restrict__ c, float4* __restrict__ out,
                            int n4) {
  int i = blockIdx.x * blockDim.x + threadIdx.x;
  if (i >= n4) return;
  float4 x = e[i], y = b[i], z = c[i];
  out[i] = make_float4((x.x + y.x + z.x) * (1.f / 3.f),
                       (x.y + y.y + z.y) * (1.f / 3.f),
                       (x.z + y.z + z.z) * (1.f / 3.f),
                       (x.w + y.w + z.w) * (1.f / 3.f));
}

__global__ void recloss_kernel(const float* __restrict__ cps, const float* __restrict__ cns,
                               const float* __restrict__ aps, const float* __restrict__ ans_,
                               const float* __restrict__ dps, const float* __restrict__ dns,
                               int Bsz, int NA, float* __restrict__ acc) {
  int b = blockIdx.x * blockDim.x + threadIdx.x;
  float l = 0.f;
  if (b < Bsz) {
    float dp = 0.f, dn = 0.f, cap = 0.f, can = 0.f;
    for (int i = 0; i < NA; ++i) {
      dp += dps[i * Bsz + b];
      dn += dns[i * Bsz + b];
      cap += cps[i * Bsz + b] * aps[i * Bsz + b];
      can += cns[i * Bsz + b] * ans_[i * Bsz + b];
    }
    l = -logsigf(dp * cap - dn * can);
  }
  for (int o = 32; o > 0; o >>= 1) l += __shfl_down(l, o);
  if ((threadIdx.x & 63) == 0) atomicAdd(acc, l);
}

__global__ void sumsq_kernel(const float4* __restrict__ x, int n4, float* __restrict__ acc) {
  int i = blockIdx.x * blockDim.x + threadIdx.x;
  int stride = gridDim.x * blockDim.x;
  float s = 0.f;
  for (; i < n4; i += stride) {
    float4 v = x[i];
    s += v.x * v.x + v.y * v.y + v.z * v.z + v.w * v.w;
  }
  for (int o = 32; o > 0; o >>= 1) s += __shfl_down(s, o);
  if ((threadIdx.x & 63) == 0) atomicAdd(acc, s);
}

__global__ void final_kernel(const float* __restrict__ accs, int Bsz, int NA, int NiRows,
                             float* __restrict__ out) {
  float rec = accs[NA] / (float)Bsz;
  float aux = 0.f;
  for (int i = 0; i < NA; ++i) aux += accs[i] / (float)Bsz;
  aux /= (float)NA;
  float embl = (sqrtf(accs[NA + 1]) + sqrtf(accs[NA + 2])) / (float)NiRows;
  out[0] = rec + 0.5f * aux + 1e-4f * embl;
}

extern "C" void kernel_launch(void* const* d_in, const int* in_sizes, int n_in,
                              void* d_out, int out_size, void* d_ws, size_t ws_size,
                              hipStream_t stream) {
  const float* user_emb = (const float*)d_in[0];
  const float* item_emb = (const float*)d_in[1];
  const int* batch = (const int*)d_in[2];
  const int* aux_edges = (const int*)d_in[3];
  const int* tgt_edges = (const int*)d_in[4];

  const int NuRows = in_sizes[0] / D;          // 100001
  const int NiRows = in_sizes[1] / D;          // 50001
  const int Bsz = in_sizes[2] / 9;             // 4096
  const int E = in_sizes[4] / 2;               // 1,000,000
  const int NA = in_sizes[3] / (2 * E);        // 2
  const int N = NuRows + NiRows;               // 150002
  const size_t rowElems = (size_t)N * D;
  const int NB = (N + SCAN_CHUNK - 1) / SCAN_CHUNK;

  // ---- workspace layout ----
  float* EMB = (float*)d_ws;
  float* A = EMB + rowElems;
  float* Ba = A + rowElems;
  float* Ca = Ba + rowElems;
  float* Bc = Ca + rowElems;
  int* deg3 = (int*)(Bc + rowElems);              // 3*N
  float* dinv5 = (float*)(deg3 + 3 * (size_t)N);  // 5*N
  int* rp3 = (int*)(dinv5 + 5 * (size_t)N);       // 3*(N+1)
  int* cur3 = rp3 + 3 * (size_t)(N + 1);          // 3*N
  int* bsum = cur3 + 3 * (size_t)N;               // 3*NB
  int* col_all = bsum + 3 * (size_t)NB;           // 3*2E
  float* cps = (float*)(col_all + 6 * (size_t)E);
  float* cns = cps + (size_t)NA * Bsz;
  float* aps = cns + (size_t)NA * Bsz;
  float* ans_ = aps + (size_t)NA * Bsz;
  float* dps = ans_ + (size_t)NA * Bsz;
  float* dns = dps + (size_t)NA * Bsz;
  float* accs = dns + (size_t)NA * Bsz;           // [NA aux][rec][sumsq_u][sumsq_i]

  const int TB = 256;
  const int g3E = (3 * E + TB - 1) / TB;
  const int gN = (N + TB - 1) / TB;
  const int gN8 = (N * 8 + TB - 1) / TB;
  const int gB = (Bsz + TB - 1) / TB;
  const int gRow4 = (int)((rowElems / 4 + TB - 1) / TB);

  hipMemcpyAsync(EMB, user_emb, (size_t)NuRows * D * sizeof(float),
                 hipMemcpyDeviceToDevice, stream);
  hipMemcpyAsync(EMB + (size_t)NuRows * D, item_emb, (size_t)NiRows * D * sizeof(float),
                 hipMemcpyDeviceToDevice, stream);

  hipMemsetAsync(deg3, 0, 3 * (size_t)N * sizeof(int), stream);
  deg_all_kernel<<<g3E, TB, 0, stream>>>((const int2*)tgt_edges, (const int2*)aux_edges,
                                         E, NuRows, deg3, N);
  dinv_all_kernel<<<gN, TB, 0, stream>>>(deg3, dinv5, N);
  scan_p1_kernel<<<3 * NB, TB, 0, stream>>>(deg3, N, NB, bsum);
  scan_p2_kernel<<<3, 64, 0, stream>>>(bsum, NB);
  scan_p3_kernel<<<3 * NB, TB, 0, stream>>>(deg3, N, NB, bsum, rp3, cur3);
  fill_all_kernel<<<g3E, TB, 0, stream>>>((const int2*)tgt_edges, (const int2*)aux_edges,
                                          E, NuRows, N, cur3, col_all);

  hipMemsetAsync(accs, 0, (size_t)(NA + 3) * sizeof(float), stream);

  const int* rpT = rp3;
  const int* colT = col_all;
  const float* dvT = dinv5;

  for (int idx = 0; idx < NA; ++idx) {
    const int* rpA = rp3 + (size_t)(1 + idx) * (N + 1);
    const int* colA = col_all + (size_t)(1 + idx) * 2 * E;
    const float* dvA = dinv5 + (size_t)(1 + idx) * N;
    const float* dvC = dinv5 + (size_t)(3 + idx) * N;

    gather_fused_kernel<<<gN8, TB, 0, stream>>>(rpA, colA, rpT, colT, dvA, dvC,
                                                (const float4*)EMB, (float4*)Ba,
                                                (float4*)Bc, N);
    gather_kernel<<<gN8, TB, 0, stream>>>(rpA, colA, dvA, (const float4*)Ba,
                                          (float4*)Ca, N);
    avg3_kernel<<<gRow4, TB, 0, stream>>>((const float4*)EMB, (const float4*)Ba,
                                          (const float4*)Ca, (float4*)A,
                                          (int)(rowElems / 4));
    score1_kernel<<<gB, TB, 0, stream>>>(A, batch, Bsz, NuRows,
                                         aps + (size_t)idx * Bsz, ans_ + (size_t)idx * Bsz);
    auxloss_kernel<<<gB, TB, 0, stream>>>(A, batch, Bsz, NuRows, idx, accs + idx);

    gather2_kernel<<<gN8, TB, 0, stream>>>(rpA, colA, rpT, colT, dvC,
                                           (const float4*)Bc, (float4*)Ca, N);
    score3_kernel<<<gB, TB, 0, stream>>>(EMB, Bc, Ca, batch, Bsz, NuRows,
                                         cps + (size_t)idx * Bsz, cns + (size_t)idx * Bsz);

    gather_kernel<<<gN8, TB, 0, stream>>>(rpT, colT, dvT, (const float4*)A,
                                          (float4*)Ba, N);
    gather_kernel<<<gN8, TB, 0, stream>>>(rpT, colT, dvT, (const float4*)Ba,
                                          (float4*)Ca, N);
    score3_kernel<<<gB, TB, 0, stream>>>(A, Ba, Ca, batch, Bsz, NuRows,
                                         dps + (size_t)idx * Bsz, dns + (size_t)idx * Bsz);
  }

  sumsq_kernel<<<2048, TB, 0, stream>>>((const float4*)user_emb,
                                        (int)((size_t)NuRows * D / 4), accs + NA + 1);
  sumsq_kernel<<<2048, TB, 0, stream>>>((const float4*)item_emb,
                                        (int)((size_t)NiRows * D / 4), accs + NA + 2);

  recloss_kernel<<<gB, TB, 0, stream>>>(cps, cns, aps, ans_, dps, dns, Bsz, NA, accs + NA);

  final_kernel<<<1, 1, 0, stream>>>(accs, Bsz, NA, NiRows, (float*)d_out);
}

// Round 4
// 1418.978 us; speedup vs baseline: 9.5676x; 1.2972x over previous
//
#include <hip/hip_runtime.h>
#include <math.h>

#define D 32
#define SCAN_CHUNK 2048   // 256 threads x 8 elems per block (node scan)
#define NBK 512           // node buckets
#define BSHIFT 9          // bucket = node >> 9
#define TILE 4096         // undirected edges per bin block

__device__ __forceinline__ float logsigf(float x) {
  return fminf(x, 0.f) - log1pf(expf(-fabsf(x)));
}

// ================= CSR build via bucket binning =================
// seg 0 = tgt, 1 = aux0, 2 = aux1. Directed entries: (dst, src).

// Phase H: bucket histogram -> bcur[seg*NBK + b] (counts)
__global__ void hist_kernel(const int2* __restrict__ tgt, const int2* __restrict__ aux,
                            int E, int Nu, int BPS, int* __restrict__ bcur) {
  __shared__ int lh[NBK];
  int seg = blockIdx.x / BPS;
  int blk = blockIdx.x - seg * BPS;
  const int2* edges = (seg == 0) ? tgt : aux + (size_t)(seg - 1) * E;
  for (int b = threadIdx.x; b < NBK; b += 256) lh[b] = 0;
  __syncthreads();
  int e0 = blk * TILE;
  for (int k = threadIdx.x; k < TILE; k += 256) {
    int e = e0 + k;
    if (e < E) {
      int2 ed = edges[e];
      atomicAdd(&lh[ed.x >> BSHIFT], 1);
      atomicAdd(&lh[(ed.y + Nu) >> BSHIFT], 1);
    }
  }
  __syncthreads();
  for (int b = threadIdx.x; b < NBK; b += 256)
    if (lh[b]) atomicAdd(&bcur[seg * NBK + b], lh[b]);
}

// Phase S: in-place exclusive scan of each seg's NBK bucket counts. grid=3, block=64
__global__ void bscan_kernel(int* __restrict__ bcur) {
  int* b = bcur + blockIdx.x * NBK;
  int lane = threadIdx.x;
  int carry = 0;
  for (int base = 0; base < NBK; base += 64) {
    int i = base + lane;
    int v = b[i];
    int s = v;
    #pragma unroll
    for (int o = 1; o < 64; o <<= 1) {
      int t = __shfl_up(s, o);
      if (lane >= o) s += t;
    }
    b[i] = carry + s - v;
    carry += __shfl(s, 63);
  }
}

// Phase B: partition directed entries into bucket order.
__global__ void bin_kernel(const int2* __restrict__ tgt, const int2* __restrict__ aux,
                           int E, int Nu, int BPS, int* __restrict__ bcur,
                           int2* __restrict__ binned) {
  __shared__ int lh[NBK];
  __shared__ int gb[NBK];
  __shared__ int lc[NBK];
  int seg = blockIdx.x / BPS;
  int blk = blockIdx.x - seg * BPS;
  const int2* edges = (seg == 0) ? tgt : aux + (size_t)(seg - 1) * E;
  int2* out = binned + (size_t)seg * 2 * E;
  for (int b = threadIdx.x; b < NBK; b += 256) lh[b] = 0;
  __syncthreads();
  int e0 = blk * TILE;
  for (int k = threadIdx.x; k < TILE; k += 256) {
    int e = e0 + k;
    if (e < E) {
      int2 ed = edges[e];
      atomicAdd(&lh[ed.x >> BSHIFT], 1);
      atomicAdd(&lh[(ed.y + Nu) >> BSHIFT], 1);
    }
  }
  __syncthreads();
  for (int b = threadIdx.x; b < NBK; b += 256) {
    gb[b] = lh[b] ? atomicAdd(&bcur[seg * NBK + b], lh[b]) : 0;
    lc[b] = 0;
  }
  __syncthreads();
  for (int k = threadIdx.x; k < TILE; k += 256) {
    int e = e0 + k;
    if (e < E) {
      int2 ed = edges[e];
      int u = ed.x, v = ed.y + Nu;
      int b1 = u >> BSHIFT, b2 = v >> BSHIFT;
      int o1 = atomicAdd(&lc[b1], 1);
      out[gb[b1] + o1] = make_int2(u, v);
      int o2 = atomicAdd(&lc[b2], 1);
      out[gb[b2] + o2] = make_int2(v, u);
    }
  }
}

// Phase C: degree from bucket-ordered entries (localized atomics)
__global__ void deg_binned_kernel(const int2* __restrict__ binned, int E2, int N,
                                  int* __restrict__ deg3) {
  int t = blockIdx.x * blockDim.x + threadIdx.x;
  if (t >= 3 * E2) return;
  int seg = t / E2;
  int j = t - seg * E2;
  atomicAdd(&deg3[(size_t)seg * N + binned[(size_t)seg * E2 + j].x], 1);
}

// Phase D: fill col from bucket-ordered entries (localized writes)
__global__ void fill_binned_kernel(const int2* __restrict__ binned, int E2, int N,
                                   int* __restrict__ cur3, int* __restrict__ col_all) {
  int t = blockIdx.x * blockDim.x + threadIdx.x;
  if (t >= 3 * E2) return;
  int seg = t / E2;
  int j = t - seg * E2;
  int2 en = binned[(size_t)seg * E2 + j];
  int pos = atomicAdd(&cur3[(size_t)seg * N + en.x], 1);
  col_all[(size_t)seg * E2 + pos] = en.y;
}

// dinv5: [0]=tgt [1]=aux0 [2]=aux1 [3]=comb0 [4]=comb1
__global__ void dinv_all_kernel(const int* __restrict__ deg3, float* __restrict__ dinv5,
                                int N) {
  int n = blockIdx.x * blockDim.x + threadIdx.x;
  if (n >= N) return;
  int dt = deg3[n], d0 = deg3[N + n], d1 = deg3[2 * N + n];
  dinv5[n]         = dt ? rsqrtf((float)dt) : 0.f;
  dinv5[N + n]     = d0 ? rsqrtf((float)d0) : 0.f;
  dinv5[2 * N + n] = d1 ? rsqrtf((float)d1) : 0.f;
  int c0 = dt + d0, c1 = dt + d1;
  dinv5[3 * N + n] = c0 ? rsqrtf((float)c0) : 0.f;
  dinv5[4 * N + n] = c1 ? rsqrtf((float)c1) : 0.f;
}

// ---- node-degree hierarchical scan (rowptr) ----
__global__ void scan_p1_kernel(const int* __restrict__ deg3, int N, int NB,
                               int* __restrict__ bsum) {
  __shared__ int red[4];
  int seg = blockIdx.x / NB;
  int blk = blockIdx.x - seg * NB;
  const int* deg = deg3 + (size_t)seg * N;
  int base = blk * SCAN_CHUNK;
  int s = 0;
  for (int k = threadIdx.x; k < SCAN_CHUNK; k += 256) {
    int i = base + k;
    s += (i < N) ? deg[i] : 0;
  }
  for (int o = 32; o > 0; o >>= 1) s += __shfl_down(s, o);
  if ((threadIdx.x & 63) == 0) red[threadIdx.x >> 6] = s;
  __syncthreads();
  if (threadIdx.x == 0) bsum[blockIdx.x] = red[0] + red[1] + red[2] + red[3];
}

__global__ void scan_p2_kernel(int* __restrict__ bsum, int NB) {
  int* b = bsum + blockIdx.x * NB;
  int lane = threadIdx.x;
  int carry = 0;
  for (int base = 0; base < NB; base += 64) {
    int i = base + lane;
    int v = (i < NB) ? b[i] : 0;
    int s = v;
    #pragma unroll
    for (int o = 1; o < 64; o <<= 1) {
      int t = __shfl_up(s, o);
      if (lane >= o) s += t;
    }
    if (i < NB) b[i] = carry + s - v;
    carry += __shfl(s, 63);
  }
}

__global__ void scan_p3_kernel(const int* __restrict__ deg3, int N, int NB,
                               const int* __restrict__ bsum, int* __restrict__ rp3,
                               int* __restrict__ cur3) {
  __shared__ int wsum[4];
  int seg = blockIdx.x / NB;
  int blk = blockIdx.x - seg * NB;
  const int* deg = deg3 + (size_t)seg * N;
  int* rowptr = rp3 + (size_t)seg * (N + 1);
  int* cursor = cur3 + (size_t)seg * N;
  int lane = threadIdx.x & 63, wid = threadIdx.x >> 6;
  int idx0 = blk * SCAN_CHUNK + threadIdx.x * 8;
  int v[8];
  int tot = 0;
  #pragma unroll
  for (int k = 0; k < 8; ++k) {
    int i = idx0 + k;
    v[k] = (i < N) ? deg[i] : 0;
    tot += v[k];
  }
  int s = tot;
  #pragma unroll
  for (int o = 1; o < 64; o <<= 1) {
    int t = __shfl_up(s, o);
    if (lane >= o) s += t;
  }
  if (lane == 63) wsum[wid] = s;
  __syncthreads();
  int woff = 0;
  for (int w = 0; w < wid; ++w) woff += wsum[w];
  int excl = bsum[blockIdx.x] + woff + (s - tot);
  #pragma unroll
  for (int k = 0; k < 8; ++k) {
    int i = idx0 + k;
    if (i < N) {
      rowptr[i] = excl;
      cursor[i] = excl;
    }
    excl += v[k];
  }
  if (N - 1 >= idx0 && N - 1 < idx0 + 8) rowptr[N] = excl;
}

// ================= propagation (pull / gather) =================

__global__ void gather_kernel(const int* __restrict__ rowptr, const int* __restrict__ col,
                              const float* __restrict__ dinv,
                              const float4* __restrict__ cur, float4* __restrict__ out,
                              int N) {
  int t = blockIdx.x * blockDim.x + threadIdx.x;
  int n = t >> 3;
  if (n >= N) return;
  int lane = t & 7;
  int s = rowptr[n], e = rowptr[n + 1];
  float4 acc = make_float4(0.f, 0.f, 0.f, 0.f);
  for (int j = s; j < e; ++j) {
    int c = col[j];
    float w = dinv[c];
    float4 x = cur[c * 8 + lane];
    acc.x += w * x.x; acc.y += w * x.y; acc.z += w * x.z; acc.w += w * x.w;
  }
  float wn = dinv[n];
  out[n * 8 + lane] = make_float4(wn * acc.x, wn * acc.y, wn * acc.z, wn * acc.w);
}

__global__ void gather2_kernel(const int* __restrict__ rpA, const int* __restrict__ colA,
                               const int* __restrict__ rpT, const int* __restrict__ colT,
                               const float* __restrict__ dinv,
                               const float4* __restrict__ cur, float4* __restrict__ out,
                               int N) {
  int t = blockIdx.x * blockDim.x + threadIdx.x;
  int n = t >> 3;
  if (n >= N) return;
  int lane = t & 7;
  float4 acc = make_float4(0.f, 0.f, 0.f, 0.f);
  int s = rpA[n], e = rpA[n + 1];
  for (int j = s; j < e; ++j) {
    int c = colA[j];
    float w = dinv[c];
    float4 x = cur[c * 8 + lane];
    acc.x += w * x.x; acc.y += w * x.y; acc.z += w * x.z; acc.w += w * x.w;
  }
  s = rpT[n]; e = rpT[n + 1];
  for (int j = s; j < e; ++j) {
    int c = colT[j];
    float w = dinv[c];
    float4 x = cur[c * 8 + lane];
    acc.x += w * x.x; acc.y += w * x.y; acc.z += w * x.z; acc.w += w * x.w;
  }
  float wn = dinv[n];
  out[n * 8 + lane] = make_float4(wn * acc.x, wn * acc.y, wn * acc.z, wn * acc.w);
}

__global__ void gather_fused_kernel(const int* __restrict__ rpA, const int* __restrict__ colA,
                                    const int* __restrict__ rpT, const int* __restrict__ colT,
                                    const float* __restrict__ dinvA,
                                    const float* __restrict__ dinvC,
                                    const float4* __restrict__ cur,
                                    float4* __restrict__ outA, float4* __restrict__ outC,
                                    int N) {
  int t = blockIdx.x * blockDim.x + threadIdx.x;
  int n = t >> 3;
  if (n >= N) return;
  int lane = t & 7;
  float4 aA = make_float4(0.f, 0.f, 0.f, 0.f);
  float4 aC = make_float4(0.f, 0.f, 0.f, 0.f);
  int s = rpA[n], e = rpA[n + 1];
  for (int j = s; j < e; ++j) {
    int c = colA[j];
    float wA = dinvA[c];
    float wC = dinvC[c];
    float4 x = cur[c * 8 + lane];
    aA.x += wA * x.x; aA.y += wA * x.y; aA.z += wA * x.z; aA.w += wA * x.w;
    aC.x += wC * x.x; aC.y += wC * x.y; aC.z += wC * x.z; aC.w += wC * x.w;
  }
  s = rpT[n]; e = rpT[n + 1];
  for (int j = s; j < e; ++j) {
    int c = colT[j];
    float wC = dinvC[c];
    float4 x = cur[c * 8 + lane];
    aC.x += wC * x.x; aC.y += wC * x.y; aC.z += wC * x.z; aC.w += wC * x.w;
  }
  float wnA = dinvA[n];
  float wnC = dinvC[n];
  outA[n * 8 + lane] = make_float4(wnA * aA.x, wnA * aA.y, wnA * aA.z, wnA * aA.w);
  outC[n * 8 + lane] = make_float4(wnC * aC.x, wnC * aC.y, wnC * aC.z, wnC * aC.w);
}

// ================= scores / losses =================

__device__ __forceinline__ float dot3_rows(const float* __restrict__ E0,
                                           const float* __restrict__ B0,
                                           const float* __restrict__ C0,
                                           int r1, int r2) {
  const float* e1 = E0 + (size_t)r1 * D;
  const float* b1 = B0 + (size_t)r1 * D;
  const float* c1 = C0 + (size_t)r1 * D;
  const float* e2 = E0 + (size_t)r2 * D;
  const float* b2 = B0 + (size_t)r2 * D;
  const float* c2 = C0 + (size_t)r2 * D;
  float s = 0.f;
#pragma unroll
  for (int k = 0; k < D; ++k)
    s += (e1[k] + b1[k] + c1[k]) * (e2[k] + b2[k] + c2[k]);
  return s * (1.f / 9.f);
}

__device__ __forceinline__ float dot1_rows(const float* __restrict__ A, int r1, int r2) {
  const float* a1 = A + (size_t)r1 * D;
  const float* a2 = A + (size_t)r2 * D;
  float s = 0.f;
#pragma unroll
  for (int k = 0; k < D; ++k) s += a1[k] * a2[k];
  return s;
}

__global__ void score3_kernel(const float* __restrict__ E0, const float* __restrict__ B0,
                              const float* __restrict__ C0, const int* __restrict__ batch,
                              int Bsz, int Nu, float* __restrict__ outp,
                              float* __restrict__ outn) {
  int b = blockIdx.x * blockDim.x + threadIdx.x;
  if (b >= Bsz) return;
  int u = batch[b * 9 + 0];
  int p = batch[b * 9 + 1] + Nu;
  int n = batch[b * 9 + 2] + Nu;
  outp[b] = fmaxf(dot3_rows(E0, B0, C0, u, p), 0.f);
  outn[b] = fmaxf(dot3_rows(E0, B0, C0, u, n), 0.f);
}

__global__ void score1_kernel(const float* __restrict__ A, const int* __restrict__ batch,
                              int Bsz, int Nu, float* __restrict__ outp,
                              float* __restrict__ outn) {
  int b = blockIdx.x * blockDim.x + threadIdx.x;
  if (b >= Bsz) return;
  int u = batch[b * 9 + 0];
  int p = batch[b * 9 + 1] + Nu;
  int n = batch[b * 9 + 2] + Nu;
  outp[b] = fmaxf(dot1_rows(A, u, p), 0.f);
  outn[b] = fmaxf(dot1_rows(A, u, n), 0.f);
}

__global__ void auxloss_kernel(const float* __restrict__ A, const int* __restrict__ batch,
                               int Bsz, int Nu, int idx, float* __restrict__ acc) {
  int b = blockIdx.x * blockDim.x + threadIdx.x;
  float l = 0.f;
  if (b < Bsz) {
    const int* r = batch + b * 9 + 3 * (1 + idx);
    int u = r[0];
    int p = r[1] + Nu;
    int n = r[2] + Nu;
    l = -logsigf(dot1_rows(A, u, p) - dot1_rows(A, u, n));
  }
  for (int o = 32; o > 0; o >>= 1) l += __shfl_down(l, o);
  if ((threadIdx.x & 63) == 0) atomicAdd(acc, l);
}

__global__ void avg3_kernel(const float4* __restrict__ e, const float4* __restrict__ b,
                            const float4* __restrict__ c, float4* __restrict__ out,
                            int n4) {
  int i = blockIdx.x * blockDim.x + threadIdx.x;
  if (i >= n4) return;
  float4 x = e[i], y = b[i], z = c[i];
  out[i] = make_float4((x.x + y.x + z.x) * (1.f / 3.f),
                       (x.y + y.y + z.y) * (1.f / 3.f),
                       (x.z + y.z + z.z) * (1.f / 3.f),
                       (x.w + y.w + z.w) * (1.f / 3.f));
}

__global__ void recloss_kernel(const float* __restrict__ cps, const float* __restrict__ cns,
                               const float* __restrict__ aps, const float* __restrict__ ans_,
                               const float* __restrict__ dps, const float* __restrict__ dns,
                               int Bsz, int NA, float* __restrict__ acc) {
  int b = blockIdx.x * blockDim.x + threadIdx.x;
  float l = 0.f;
  if (b < Bsz) {
    float dp = 0.f, dn = 0.f, cap = 0.f, can = 0.f;
    for (int i = 0; i < NA; ++i) {
      dp += dps[i * Bsz + b];
      dn += dns[i * Bsz + b];
      cap += cps[i * Bsz + b] * aps[i * Bsz + b];
      can += cns[i * Bsz + b] * ans_[i * Bsz + b];
    }
    l = -logsigf(dp * cap - dn * can);
  }
  for (int o = 32; o > 0; o >>= 1) l += __shfl_down(l, o);
  if ((threadIdx.x & 63) == 0) atomicAdd(acc, l);
}

__global__ void sumsq_kernel(const float4* __restrict__ x, int n4, float* __restrict__ acc) {
  int i = blockIdx.x * blockDim.x + threadIdx.x;
  int stride = gridDim.x * blockDim.x;
  float s = 0.f;
  for (; i < n4; i += stride) {
    float4 v = x[i];
    s += v.x * v.x + v.y * v.y + v.z * v.z + v.w * v.w;
  }
  for (int o = 32; o > 0; o >>= 1) s += __shfl_down(s, o);
  if ((threadIdx.x & 63) == 0) atomicAdd(acc, s);
}

__global__ void final_kernel(const float* __restrict__ accs, int Bsz, int NA, int NiRows,
                             float* __restrict__ out) {
  float rec = accs[NA] / (float)Bsz;
  float aux = 0.f;
  for (int i = 0; i < NA; ++i) aux += accs[i] / (float)Bsz;
  aux /= (float)NA;
  float embl = (sqrtf(accs[NA + 1]) + sqrtf(accs[NA + 2])) / (float)NiRows;
  out[0] = rec + 0.5f * aux + 1e-4f * embl;
}

extern "C" void kernel_launch(void* const* d_in, const int* in_sizes, int n_in,
                              void* d_out, int out_size, void* d_ws, size_t ws_size,
                              hipStream_t stream) {
  const float* user_emb = (const float*)d_in[0];
  const float* item_emb = (const float*)d_in[1];
  const int* batch = (const int*)d_in[2];
  const int* aux_edges = (const int*)d_in[3];
  const int* tgt_edges = (const int*)d_in[4];

  const int NuRows = in_sizes[0] / D;          // 100001
  const int NiRows = in_sizes[1] / D;          // 50001
  const int Bsz = in_sizes[2] / 9;             // 4096
  const int E = in_sizes[4] / 2;               // 1,000,000
  const int NA = in_sizes[3] / (2 * E);        // 2
  const int N = NuRows + NiRows;               // 150002
  const int E2 = 2 * E;
  const size_t rowElems = (size_t)N * D;
  const int NB = (N + SCAN_CHUNK - 1) / SCAN_CHUNK;
  const int BPS = (E + TILE - 1) / TILE;       // bin blocks per seg

  // ---- workspace layout ----
  float* EMB = (float*)d_ws;
  float* A = EMB + rowElems;
  float* Ba = A + rowElems;
  float* Ca = Ba + rowElems;
  float* Bc = Ca + rowElems;
  int* deg3 = (int*)(Bc + rowElems);              // 3*N
  float* dinv5 = (float*)(deg3 + 3 * (size_t)N);  // 5*N
  int* rp3 = (int*)(dinv5 + 5 * (size_t)N);       // 3*(N+1)
  int* cur3 = rp3 + 3 * (size_t)(N + 1);          // 3*N
  int* bsum = cur3 + 3 * (size_t)N;               // 3*NB
  int* bcur = bsum + 3 * (size_t)NB;              // 3*NBK
  int* col_all = bcur + 3 * (size_t)NBK;          // 3*2E
  float* cps = (float*)(col_all + 3 * (size_t)E2);
  float* cns = cps + (size_t)NA * Bsz;
  float* aps = cns + (size_t)NA * Bsz;
  float* ans_ = aps + (size_t)NA * Bsz;
  float* dps = ans_ + (size_t)NA * Bsz;
  float* dns = dps + (size_t)NA * Bsz;
  float* accs = dns + (size_t)NA * Bsz;           // [NA aux][rec][sumsq_u][sumsq_i]
  // binned (3*2E int2 = 48 MB) aliased onto Ba/Ca/Bc (57.6 MB); dead before gathers
  int2* binned = (int2*)Ba;

  const int TB = 256;
  const int g3E2 = (3 * E2 + TB - 1) / TB;
  const int gN = (N + TB - 1) / TB;
  const int gN8 = (N * 8 + TB - 1) / TB;
  const int gB = (Bsz + TB - 1) / TB;
  const int gRow4 = (int)((rowElems / 4 + TB - 1) / TB);

  hipMemcpyAsync(EMB, user_emb, (size_t)NuRows * D * sizeof(float),
                 hipMemcpyDeviceToDevice, stream);
  hipMemcpyAsync(EMB + (size_t)NuRows * D, item_emb, (size_t)NiRows * D * sizeof(float),
                 hipMemcpyDeviceToDevice, stream);

  // ---- binned CSR build ----
  hipMemsetAsync(bcur, 0, 3 * (size_t)NBK * sizeof(int), stream);
  hist_kernel<<<3 * BPS, TB, 0, stream>>>((const int2*)tgt_edges, (const int2*)aux_edges,
                                          E, NuRows, BPS, bcur);
  bscan_kernel<<<3, 64, 0, stream>>>(bcur);
  bin_kernel<<<3 * BPS, TB, 0, stream>>>((const int2*)tgt_edges, (const int2*)aux_edges,
                                         E, NuRows, BPS, bcur, binned);
  hipMemsetAsync(deg3, 0, 3 * (size_t)N * sizeof(int), stream);
  deg_binned_kernel<<<g3E2, TB, 0, stream>>>(binned, E2, N, deg3);
  dinv_all_kernel<<<gN, TB, 0, stream>>>(deg3, dinv5, N);
  scan_p1_kernel<<<3 * NB, TB, 0, stream>>>(deg3, N, NB, bsum);
  scan_p2_kernel<<<3, 64, 0, stream>>>(bsum, NB);
  scan_p3_kernel<<<3 * NB, TB, 0, stream>>>(deg3, N, NB, bsum, rp3, cur3);
  fill_binned_kernel<<<g3E2, TB, 0, stream>>>(binned, E2, N, cur3, col_all);

  hipMemsetAsync(accs, 0, (size_t)(NA + 3) * sizeof(float), stream);

  const int* rpT = rp3;
  const int* colT = col_all;
  const float* dvT = dinv5;

  for (int idx = 0; idx < NA; ++idx) {
    const int* rpA = rp3 + (size_t)(1 + idx) * (N + 1);
    const int* colA = col_all + (size_t)(1 + idx) * E2;
    const float* dvA = dinv5 + (size_t)(1 + idx) * N;
    const float* dvC = dinv5 + (size_t)(3 + idx) * N;

    // fused layer-1: Ba = aux L1, Bc = comb L1 (overwrites binned alias - binned is dead)
    gather_fused_kernel<<<gN8, TB, 0, stream>>>(rpA, colA, rpT, colT, dvA, dvC,
                                                (const float4*)EMB, (float4*)Ba,
                                                (float4*)Bc, N);
    gather_kernel<<<gN8, TB, 0, stream>>>(rpA, colA, dvA, (const float4*)Ba,
                                          (float4*)Ca, N);
    avg3_kernel<<<gRow4, TB, 0, stream>>>((const float4*)EMB, (const float4*)Ba,
                                          (const float4*)Ca, (float4*)A,
                                          (int)(rowElems / 4));
    score1_kernel<<<gB, TB, 0, stream>>>(A, batch, Bsz, NuRows,
                                         aps + (size_t)idx * Bsz, ans_ + (size_t)idx * Bsz);
    auxloss_kernel<<<gB, TB, 0, stream>>>(A, batch, Bsz, NuRows, idx, accs + idx);

    gather2_kernel<<<gN8, TB, 0, stream>>>(rpA, colA, rpT, colT, dvC,
                                           (const float4*)Bc, (float4*)Ca, N);
    score3_kernel<<<gB, TB, 0, stream>>>(EMB, Bc, Ca, batch, Bsz, NuRows,
                                         cps + (size_t)idx * Bsz, cns + (size_t)idx * Bsz);

    gather_kernel<<<gN8, TB, 0, stream>>>(rpT, colT, dvT, (const float4*)A,
                                          (float4*)Ba, N);
    gather_kernel<<<gN8, TB, 0, stream>>>(rpT, colT, dvT, (const float4*)Ba,
                                          (float4*)Ca, N);
    score3_kernel<<<gB, TB, 0, stream>>>(A, Ba, Ca, batch, Bsz, NuRows,
                                         dps + (size_t)idx * Bsz, dns + (size_t)idx * Bsz);
  }

  sumsq_kernel<<<2048, TB, 0, stream>>>((const float4*)user_emb,
                                        (int)((size_t)NuRows * D / 4), accs + NA + 1);
  sumsq_kernel<<<2048, TB, 0, stream>>>((const float4*)item_emb,
                                        (int)((size_t)NiRows * D / 4), accs + NA + 2);

  recloss_kernel<<<gB, TB, 0, stream>>>(cps, cns, aps, ans_, dps, dns, Bsz, NA, accs + NA);

  final_kernel<<<1, 1, 0, stream>>>(accs, Bsz, NA, NiRows, (float*)d_out);
}

// Round 5
// 1089.544 us; speedup vs baseline: 12.4605x; 1.3024x over previous
//
#include <hip/hip_runtime.h>
#include <math.h>

#define D 32
#define NBK 1024          // node buckets per segment
#define BSHIFT 8          // bucket = node >> 8  (256 nodes per bucket)
#define TILE 16384        // undirected edges per hist/bin block
#define BCAP 7680         // LDS entry capacity in bucket_csr (61.4 KB of int2)

__device__ __forceinline__ float logsigf(float x) {
  return fminf(x, 0.f) - log1pf(expf(-fabsf(x)));
}

// ================= CSR build via bucket binning =================
// seg 0 = tgt, 1 = aux0, 2 = aux1. Directed entries: (dst, src).

// Phase H: bucket histogram -> bcur[seg*NBK + b]
__global__ void hist_kernel(const int2* __restrict__ tgt, const int2* __restrict__ aux,
                            int E, int Nu, int BPS, int* __restrict__ bcur) {
  __shared__ int lh[NBK];
  int seg = blockIdx.x / BPS;
  int blk = blockIdx.x - seg * BPS;
  const int2* edges = (seg == 0) ? tgt : aux + (size_t)(seg - 1) * E;
  for (int b = threadIdx.x; b < NBK; b += 256) lh[b] = 0;
  __syncthreads();
  int e0 = blk * TILE;
  for (int k = threadIdx.x; k < TILE; k += 256) {
    int e = e0 + k;
    if (e < E) {
      int2 ed = edges[e];
      atomicAdd(&lh[ed.x >> BSHIFT], 1);
      atomicAdd(&lh[(ed.y + Nu) >> BSHIFT], 1);
    }
  }
  __syncthreads();
  for (int b = threadIdx.x; b < NBK; b += 256)
    if (lh[b]) atomicAdd(&bcur[seg * NBK + b], lh[b]);
}

// Phase S: in-place exclusive scan of each seg's NBK bucket counts. grid=3, block=64
__global__ void bscan_kernel(int* __restrict__ bcur) {
  int* b = bcur + blockIdx.x * NBK;
  int lane = threadIdx.x;
  int carry = 0;
  for (int base = 0; base < NBK; base += 64) {
    int i = base + lane;
    int v = b[i];
    int s = v;
    #pragma unroll
    for (int o = 1; o < 64; o <<= 1) {
      int t = __shfl_up(s, o);
      if (lane >= o) s += t;
    }
    b[i] = carry + s - v;
    carry += __shfl(s, 63);
  }
}

// Phase B: partition directed entries into bucket order.
// After this kernel, bcur[seg*NBK+b] holds the INCLUSIVE scan (bucket end offset).
__global__ void bin_kernel(const int2* __restrict__ tgt, const int2* __restrict__ aux,
                           int E, int Nu, int BPS, int* __restrict__ bcur,
                           int2* __restrict__ binned) {
  __shared__ int lh[NBK];
  __shared__ int gb[NBK];
  __shared__ int lc[NBK];
  int seg = blockIdx.x / BPS;
  int blk = blockIdx.x - seg * BPS;
  const int2* edges = (seg == 0) ? tgt : aux + (size_t)(seg - 1) * E;
  int2* out = binned + (size_t)seg * 2 * E;
  for (int b = threadIdx.x; b < NBK; b += 256) lh[b] = 0;
  __syncthreads();
  int e0 = blk * TILE;
  for (int k = threadIdx.x; k < TILE; k += 256) {
    int e = e0 + k;
    if (e < E) {
      int2 ed = edges[e];
      atomicAdd(&lh[ed.x >> BSHIFT], 1);
      atomicAdd(&lh[(ed.y + Nu) >> BSHIFT], 1);
    }
  }
  __syncthreads();
  for (int b = threadIdx.x; b < NBK; b += 256) {
    gb[b] = lh[b] ? atomicAdd(&bcur[seg * NBK + b], lh[b]) : 0;
    lc[b] = 0;
  }
  __syncthreads();
  for (int k = threadIdx.x; k < TILE; k += 256) {
    int e = e0 + k;
    if (e < E) {
      int2 ed = edges[e];
      int u = ed.x, v = ed.y + Nu;
      int b1 = u >> BSHIFT, b2 = v >> BSHIFT;
      int o1 = atomicAdd(&lc[b1], 1);
      out[gb[b1] + o1] = make_int2(u, v);
      int o2 = atomicAdd(&lc[b2], 1);
      out[gb[b2] + o2] = make_int2(v, u);
    }
  }
}

// Phase C: one block per (seg,bucket). LDS counting sort -> deg, rowptr, node-sorted col.
// bend = post-bin bcur (inclusive scan). Each col line written once by one block.
__global__ void bucket_csr_kernel(const int2* __restrict__ binned,
                                  const int* __restrict__ bend, int E2, int N, int NBKe,
                                  int* __restrict__ deg3, int* __restrict__ rp3,
                                  int* __restrict__ col_all) {
  __shared__ int2 ent[BCAP];
  __shared__ int cnt[256];
  __shared__ int off[256];
  __shared__ int wred[4];
  int seg = blockIdx.x / NBKe;
  int bkt = blockIdx.x - seg * NBKe;
  int node0 = bkt << BSHIFT;
  const int* bc = bend + seg * NBK;
  int start = (bkt == 0) ? 0 : bc[bkt - 1];
  int end = bc[bkt];
  int cntE = end - start;
  const int2* src = binned + (size_t)seg * E2 + start;
  bool inLds = (cntE <= BCAP);
  if (inLds)
    for (int k = threadIdx.x; k < cntE; k += 256) ent[k] = src[k];
  cnt[threadIdx.x] = 0;
  __syncthreads();
  for (int k = threadIdx.x; k < cntE; k += 256) {
    int2 en = inLds ? ent[k] : src[k];
    atomicAdd(&cnt[en.x - node0], 1);
  }
  __syncthreads();
  // exclusive scan of cnt[256]
  int lane = threadIdx.x & 63, wid = threadIdx.x >> 6;
  int v = cnt[threadIdx.x];
  int incl = v;
  #pragma unroll
  for (int o = 1; o < 64; o <<= 1) {
    int t = __shfl_up(incl, o);
    if (lane >= o) incl += t;
  }
  if (lane == 63) wred[wid] = incl;
  __syncthreads();
  int wbase = 0;
  for (int w = 0; w < wid; ++w) wbase += wred[w];
  off[threadIdx.x] = wbase + incl - v;
  // deg + rowptr
  int node = node0 + (int)threadIdx.x;
  if (node < N) {
    deg3[(size_t)seg * N + node] = v;
    rp3[(size_t)seg * (N + 1) + node] = start + wbase + incl - v;
  }
  if (bkt == 0 && threadIdx.x == 0) rp3[(size_t)seg * (N + 1) + N] = E2;
  __syncthreads();
  cnt[threadIdx.x] = 0;
  __syncthreads();
  int* col = col_all + (size_t)seg * E2 + start;
  for (int k = threadIdx.x; k < cntE; k += 256) {
    int2 en = inLds ? ent[k] : src[k];
    int lb = en.x - node0;
    int pos = atomicAdd(&cnt[lb], 1);
    col[off[lb] + pos] = en.y;
  }
}

// dinv5: [0]=tgt [1]=aux0 [2]=aux1 [3]=comb0 [4]=comb1
__global__ void dinv_all_kernel(const int* __restrict__ deg3, float* __restrict__ dinv5,
                                int N) {
  int n = blockIdx.x * blockDim.x + threadIdx.x;
  if (n >= N) return;
  int dt = deg3[n], d0 = deg3[N + n], d1 = deg3[2 * N + n];
  dinv5[n]         = dt ? rsqrtf((float)dt) : 0.f;
  dinv5[N + n]     = d0 ? rsqrtf((float)d0) : 0.f;
  dinv5[2 * N + n] = d1 ? rsqrtf((float)d1) : 0.f;
  int c0 = dt + d0, c1 = dt + d1;
  dinv5[3 * N + n] = c0 ? rsqrtf((float)c0) : 0.f;
  dinv5[4 * N + n] = c1 ? rsqrtf((float)c1) : 0.f;
}

// ================= dense propagation (pull / gather) =================

__global__ void gather_kernel(const int* __restrict__ rowptr, const int* __restrict__ col,
                              const float* __restrict__ dinv,
                              const float4* __restrict__ cur, float4* __restrict__ out,
                              int N) {
  int t = blockIdx.x * blockDim.x + threadIdx.x;
  int n = t >> 3;
  if (n >= N) return;
  int lane = t & 7;
  int s = rowptr[n], e = rowptr[n + 1];
  float4 acc = make_float4(0.f, 0.f, 0.f, 0.f);
  for (int j = s; j < e; ++j) {
    int c = col[j];
    float w = dinv[c];
    float4 x = cur[c * 8 + lane];
    acc.x += w * x.x; acc.y += w * x.y; acc.z += w * x.z; acc.w += w * x.w;
  }
  float wn = dinv[n];
  out[n * 8 + lane] = make_float4(wn * acc.x, wn * acc.y, wn * acc.z, wn * acc.w);
}

// aux L2 + avg folded: A = (EMB + Ba + dinv[n]*gather(Ba)) / 3
__global__ void gather_avg_kernel(const int* __restrict__ rowptr, const int* __restrict__ col,
                                  const float* __restrict__ dinv,
                                  const float4* __restrict__ cur,
                                  const float4* __restrict__ emb,
                                  float4* __restrict__ outA, int N) {
  int t = blockIdx.x * blockDim.x + threadIdx.x;
  int n = t >> 3;
  if (n >= N) return;
  int lane = t & 7;
  int s = rowptr[n], e = rowptr[n + 1];
  float4 acc = make_float4(0.f, 0.f, 0.f, 0.f);
  for (int j = s; j < e; ++j) {
    int c = col[j];
    float w = dinv[c];
    float4 x = cur[c * 8 + lane];
    acc.x += w * x.x; acc.y += w * x.y; acc.z += w * x.z; acc.w += w * x.w;
  }
  float wn = dinv[n];
  float4 e0 = emb[n * 8 + lane];
  float4 b0 = cur[n * 8 + lane];
  outA[n * 8 + lane] = make_float4((e0.x + b0.x + wn * acc.x) * (1.f / 3.f),
                                   (e0.y + b0.y + wn * acc.y) * (1.f / 3.f),
                                   (e0.z + b0.z + wn * acc.z) * (1.f / 3.f),
                                   (e0.w + b0.w + wn * acc.w) * (1.f / 3.f));
}

// fused layer-1: aux graph (dinvA) -> outA, comb graph (dinvC) -> outC; shares aux row reads
__global__ void gather_fused_kernel(const int* __restrict__ rpA, const int* __restrict__ colA,
                                    const int* __restrict__ rpT, const int* __restrict__ colT,
                                    const float* __restrict__ dinvA,
                                    const float* __restrict__ dinvC,
                                    const float4* __restrict__ cur,
                                    float4* __restrict__ outA, float4* __restrict__ outC,
                                    int N) {
  int t = blockIdx.x * blockDim.x + threadIdx.x;
  int n = t >> 3;
  if (n >= N) return;
  int lane = t & 7;
  float4 aA = make_float4(0.f, 0.f, 0.f, 0.f);
  float4 aC = make_float4(0.f, 0.f, 0.f, 0.f);
  int s = rpA[n], e = rpA[n + 1];
  for (int j = s; j < e; ++j) {
    int c = colA[j];
    float wA = dinvA[c];
    float wC = dinvC[c];
    float4 x = cur[c * 8 + lane];
    aA.x += wA * x.x; aA.y += wA * x.y; aA.z += wA * x.z; aA.w += wA * x.w;
    aC.x += wC * x.x; aC.y += wC * x.y; aC.z += wC * x.z; aC.w += wC * x.w;
  }
  s = rpT[n]; e = rpT[n + 1];
  for (int j = s; j < e; ++j) {
    int c = colT[j];
    float wC = dinvC[c];
    float4 x = cur[c * 8 + lane];
    aC.x += wC * x.x; aC.y += wC * x.y; aC.z += wC * x.z; aC.w += wC * x.w;
  }
  float wnA = dinvA[n];
  float wnC = dinvC[n];
  outA[n * 8 + lane] = make_float4(wnA * aA.x, wnA * aA.y, wnA * aA.z, wnA * aA.w);
  outC[n * 8 + lane] = make_float4(wnC * aC.x, wnC * aC.y, wnC * aC.z, wnC * aC.w);
}

// ================= sparse L2 + score =================
// For row r: final[r][d] = (base[r][d] + L1[r][d] + dinv[r]*sum_{adj} dinv[c]*L1[c][d]) / 3
// Adjacency = colA (+ colT if non-null). One 32-lane group per batch element; lane = dim.

__device__ __forceinline__ float final_dim(const int* __restrict__ rpA,
                                           const int* __restrict__ colA,
                                           const int* __restrict__ rpT,
                                           const int* __restrict__ colT,
                                           const float* __restrict__ dinv,
                                           const float* __restrict__ base,
                                           const float* __restrict__ L1,
                                           int r, int d) {
  float acc = 0.f;
  int s = rpA[r], e = rpA[r + 1];
  for (int j = s; j < e; ++j) {
    int c = colA[j];
    acc += dinv[c] * L1[(size_t)c * D + d];
  }
  if (colT != nullptr) {
    s = rpT[r]; e = rpT[r + 1];
    for (int j = s; j < e; ++j) {
      int c = colT[j];
      acc += dinv[c] * L1[(size_t)c * D + d];
    }
  }
  return (base[(size_t)r * D + d] + L1[(size_t)r * D + d] + dinv[r] * acc) * (1.f / 3.f);
}

__global__ void score_sparse_kernel(const int* __restrict__ rpA, const int* __restrict__ colA,
                                    const int* __restrict__ rpT, const int* __restrict__ colT,
                                    const float* __restrict__ dinv,
                                    const float* __restrict__ base,
                                    const float* __restrict__ L1,
                                    const int* __restrict__ batch, int Bsz, int Nu,
                                    float* __restrict__ outp, float* __restrict__ outn) {
  int t = blockIdx.x * blockDim.x + threadIdx.x;
  int b = t >> 5;
  int d = t & 31;
  if (b >= Bsz) return;
  int u = batch[b * 9 + 0];
  int p = batch[b * 9 + 1] + Nu;
  int n = batch[b * 9 + 2] + Nu;
  float uv = final_dim(rpA, colA, rpT, colT, dinv, base, L1, u, d);
  float pv = final_dim(rpA, colA, rpT, colT, dinv, base, L1, p, d);
  float nv = final_dim(rpA, colA, rpT, colT, dinv, base, L1, n, d);
  float sp = uv * pv, sn = uv * nv;
  #pragma unroll
  for (int o = 16; o > 0; o >>= 1) {
    sp += __shfl_down(sp, o, 32);
    sn += __shfl_down(sn, o, 32);
  }
  if (d == 0) {
    outp[b] = fmaxf(sp, 0.f);
    outn[b] = fmaxf(sn, 0.f);
  }
}

// ================= batch scores / losses on materialized A =================

__device__ __forceinline__ float dot1_rows(const float* __restrict__ A, int r1, int r2) {
  const float* a1 = A + (size_t)r1 * D;
  const float* a2 = A + (size_t)r2 * D;
  float s = 0.f;
#pragma unroll
  for (int k = 0; k < D; ++k) s += a1[k] * a2[k];
  return s;
}

__global__ void score1_kernel(const float* __restrict__ A, const int* __restrict__ batch,
                              int Bsz, int Nu, float* __restrict__ outp,
                              float* __restrict__ outn) {
  int b = blockIdx.x * blockDim.x + threadIdx.x;
  if (b >= Bsz) return;
  int u = batch[b * 9 + 0];
  int p = batch[b * 9 + 1] + Nu;
  int n = batch[b * 9 + 2] + Nu;
  outp[b] = fmaxf(dot1_rows(A, u, p), 0.f);
  outn[b] = fmaxf(dot1_rows(A, u, n), 0.f);
}

__global__ void auxloss_kernel(const float* __restrict__ A, const int* __restrict__ batch,
                               int Bsz, int Nu, int idx, float* __restrict__ acc) {
  int b = blockIdx.x * blockDim.x + threadIdx.x;
  float l = 0.f;
  if (b < Bsz) {
    const int* r = batch + b * 9 + 3 * (1 + idx);
    int u = r[0];
    int p = r[1] + Nu;
    int n = r[2] + Nu;
    l = -logsigf(dot1_rows(A, u, p) - dot1_rows(A, u, n));
  }
  for (int o = 32; o > 0; o >>= 1) l += __shfl_down(l, o);
  if ((threadIdx.x & 63) == 0) atomicAdd(acc, l);
}

__global__ void recloss_kernel(const float* __restrict__ cps, const float* __restrict__ cns,
                               const float* __restrict__ aps, const float* __restrict__ ans_,
                               const float* __restrict__ dps, const float* __restrict__ dns,
                               int Bsz, int NA, float* __restrict__ acc) {
  int b = blockIdx.x * blockDim.x + threadIdx.x;
  float l = 0.f;
  if (b < Bsz) {
    float dp = 0.f, dn = 0.f, cap = 0.f, can = 0.f;
    for (int i = 0; i < NA; ++i) {
      dp += dps[i * Bsz + b];
      dn += dns[i * Bsz + b];
      cap += cps[i * Bsz + b] * aps[i * Bsz + b];
      can += cns[i * Bsz + b] * ans_[i * Bsz + b];
    }
    l = -logsigf(dp * cap - dn * can);
  }
  for (int o = 32; o > 0; o >>= 1) l += __shfl_down(l, o);
  if ((threadIdx.x & 63) == 0) atomicAdd(acc, l);
}

__global__ void sumsq_kernel(const float4* __restrict__ x, int n4, float* __restrict__ acc) {
  int i = blockIdx.x * blockDim.x + threadIdx.x;
  int stride = gridDim.x * blockDim.x;
  float s = 0.f;
  for (; i < n4; i += stride) {
    float4 v = x[i];
    s += v.x * v.x + v.y * v.y + v.z * v.z + v.w * v.w;
  }
  for (int o = 32; o > 0; o >>= 1) s += __shfl_down(s, o);
  if ((threadIdx.x & 63) == 0) atomicAdd(acc, s);
}

__global__ void final_kernel(const float* __restrict__ accs, int Bsz, int NA, int NiRows,
                             float* __restrict__ out) {
  float rec = accs[NA] / (float)Bsz;
  float aux = 0.f;
  for (int i = 0; i < NA; ++i) aux += accs[i] / (float)Bsz;
  aux /= (float)NA;
  float embl = (sqrtf(accs[NA + 1]) + sqrtf(accs[NA + 2])) / (float)NiRows;
  out[0] = rec + 0.5f * aux + 1e-4f * embl;
}

extern "C" void kernel_launch(void* const* d_in, const int* in_sizes, int n_in,
                              void* d_out, int out_size, void* d_ws, size_t ws_size,
                              hipStream_t stream) {
  const float* user_emb = (const float*)d_in[0];
  const float* item_emb = (const float*)d_in[1];
  const int* batch = (const int*)d_in[2];
  const int* aux_edges = (const int*)d_in[3];
  const int* tgt_edges = (const int*)d_in[4];

  const int NuRows = in_sizes[0] / D;          // 100001
  const int NiRows = in_sizes[1] / D;          // 50001
  const int Bsz = in_sizes[2] / 9;             // 4096
  const int E = in_sizes[4] / 2;               // 1,000,000
  const int NA = in_sizes[3] / (2 * E);        // 2
  const int N = NuRows + NiRows;               // 150002
  const int E2 = 2 * E;
  const size_t rowElems = (size_t)N * D;
  const int BPS = (E + TILE - 1) / TILE;
  const int NBKe = (N + (1 << BSHIFT) - 1) >> BSHIFT;

  // ---- workspace layout ----
  float* EMB = (float*)d_ws;
  float* A = EMB + rowElems;
  float* Ba = A + rowElems;
  float* Bc = Ba + rowElems;
  int* deg3 = (int*)(Bc + rowElems);              // 3*N
  float* dinv5 = (float*)(deg3 + 3 * (size_t)N);  // 5*N
  int* rp3 = (int*)(dinv5 + 5 * (size_t)N);       // 3*(N+1)
  int* bcur = rp3 + 3 * (size_t)(N + 1);          // 3*NBK
  int* col_all = bcur + 3 * (size_t)NBK;          // 3*2E
  float* cps = (float*)(col_all + 3 * (size_t)E2);
  float* cns = cps + (size_t)NA * Bsz;
  float* aps = cns + (size_t)NA * Bsz;
  float* ans_ = aps + (size_t)NA * Bsz;
  float* dps = ans_ + (size_t)NA * Bsz;
  float* dns = dps + (size_t)NA * Bsz;
  float* accs = dns + (size_t)NA * Bsz;           // [NA aux][rec][sumsq_u][sumsq_i]
  // binned (3*2E int2 = 48 MB) aliased onto A/Ba/Bc (57.6 MB); dead before gathers
  int2* binned = (int2*)A;

  const int TB = 256;
  const int gN = (N + TB - 1) / TB;
  const int gN8 = (N * 8 + TB - 1) / TB;
  const int gB = (Bsz + TB - 1) / TB;
  const int gB32 = (Bsz * 32 + TB - 1) / TB;

  hipMemcpyAsync(EMB, user_emb, (size_t)NuRows * D * sizeof(float),
                 hipMemcpyDeviceToDevice, stream);
  hipMemcpyAsync(EMB + (size_t)NuRows * D, item_emb, (size_t)NiRows * D * sizeof(float),
                 hipMemcpyDeviceToDevice, stream);

  // ---- binned CSR build ----
  hipMemsetAsync(bcur, 0, 3 * (size_t)NBK * sizeof(int), stream);
  hist_kernel<<<3 * BPS, TB, 0, stream>>>((const int2*)tgt_edges, (const int2*)aux_edges,
                                          E, NuRows, BPS, bcur);
  bscan_kernel<<<3, 64, 0, stream>>>(bcur);
  bin_kernel<<<3 * BPS, TB, 0, stream>>>((const int2*)tgt_edges, (const int2*)aux_edges,
                                         E, NuRows, BPS, bcur, binned);
  bucket_csr_kernel<<<3 * NBKe, TB, 0, stream>>>(binned, bcur, E2, N, NBKe,
                                                 deg3, rp3, col_all);
  dinv_all_kernel<<<gN, TB, 0, stream>>>(deg3, dinv5, N);

  hipMemsetAsync(accs, 0, (size_t)(NA + 3) * sizeof(float), stream);

  const int* rpT = rp3;
  const int* colT = col_all;
  const float* dvT = dinv5;

  for (int idx = 0; idx < NA; ++idx) {
    const int* rpA = rp3 + (size_t)(1 + idx) * (N + 1);
    const int* colA = col_all + (size_t)(1 + idx) * E2;
    const float* dvA = dinv5 + (size_t)(1 + idx) * N;
    const float* dvC = dinv5 + (size_t)(3 + idx) * N;

    // dense fused layer-1: Ba = aux L1, Bc = comb L1 (overwrites binned alias - dead)
    gather_fused_kernel<<<gN8, TB, 0, stream>>>(rpA, colA, rpT, colT, dvA, dvC,
                                                (const float4*)EMB, (float4*)Ba,
                                                (float4*)Bc, N);
    // dense aux L2 + avg: A = (EMB + Ba + gather(Ba))/3
    gather_avg_kernel<<<gN8, TB, 0, stream>>>(rpA, colA, dvA, (const float4*)Ba,
                                              (const float4*)EMB, (float4*)A, N);
    score1_kernel<<<gB, TB, 0, stream>>>(A, batch, Bsz, NuRows,
                                         aps + (size_t)idx * Bsz, ans_ + (size_t)idx * Bsz);
    auxloss_kernel<<<gB, TB, 0, stream>>>(A, batch, Bsz, NuRows, idx, accs + idx);

    // sparse comb L2 + ce scores (batch rows only)
    score_sparse_kernel<<<gB32, TB, 0, stream>>>(rpA, colA, rpT, colT, dvC, EMB, Bc,
                                                 batch, Bsz, NuRows,
                                                 cps + (size_t)idx * Bsz,
                                                 cns + (size_t)idx * Bsz);

    // dense de layer-1: Ba = gather(A over tgt)
    gather_kernel<<<gN8, TB, 0, stream>>>(rpT, colT, dvT, (const float4*)A,
                                          (float4*)Ba, N);
    // sparse de L2 + scores
    score_sparse_kernel<<<gB32, TB, 0, stream>>>(rpT, colT, nullptr, nullptr, dvT, A, Ba,
                                                 batch, Bsz, NuRows,
                                                 dps + (size_t)idx * Bsz,
                                                 dns + (size_t)idx * Bsz);
  }

  sumsq_kernel<<<2048, TB, 0, stream>>>((const float4*)user_emb,
                                        (int)((size_t)NuRows * D / 4), accs + NA + 1);
  sumsq_kernel<<<2048, TB, 0, stream>>>((const float4*)item_emb,
                                        (int)((size_t)NiRows * D / 4), accs + NA + 2);

  recloss_kernel<<<gB, TB, 0, stream>>>(cps, cns, aps, ans_, dps, dns, Bsz, NA, accs + NA);

  final_kernel<<<1, 1, 0, stream>>>(accs, Bsz, NA, NiRows, (float*)d_out);
}

// Round 6
// 956.452 us; speedup vs baseline: 14.1943x; 1.1392x over previous
//
#include <hip/hip_runtime.h>
#include <math.h>

#define D 32
#define NBK 1024          // bucket slots per segment
#define BSHIFT 8          // bucket = node >> 8  (256 nodes per bucket)
#define TILE_H 16384      // undirected edges per hist block
#define TILE_BIN 2048     // undirected edges per bin block (stage 4096 ints)
#define BCAP 7680         // LDS packed-entry capacity in bucket_csr

__device__ __forceinline__ float logsigf(float x) {
  return fminf(x, 0.f) - log1pf(expf(-fabsf(x)));
}

// ================= CSR build via bucket binning =================
// seg 0 = tgt, 1 = aux0, 2 = aux1. Directed entry packed: (dst_local<<18)|src
// (dst_local = dst & 255 within bucket, src < 2^18).

__global__ void hist_kernel(const int2* __restrict__ tgt, const int2* __restrict__ aux,
                            int E, int Nu, int BPS, int* __restrict__ bcur) {
  __shared__ int lh[NBK];
  int seg = blockIdx.x / BPS;
  int blk = blockIdx.x - seg * BPS;
  const int2* edges = (seg == 0) ? tgt : aux + (size_t)(seg - 1) * E;
  for (int b = threadIdx.x; b < NBK; b += 256) lh[b] = 0;
  __syncthreads();
  int e0 = blk * TILE_H;
  for (int k = threadIdx.x; k < TILE_H; k += 256) {
    int e = e0 + k;
    if (e < E) {
      int2 ed = edges[e];
      atomicAdd(&lh[ed.x >> BSHIFT], 1);
      atomicAdd(&lh[(ed.y + Nu) >> BSHIFT], 1);
    }
  }
  __syncthreads();
  for (int b = threadIdx.x; b < NBK; b += 256)
    if (lh[b]) atomicAdd(&bcur[seg * NBK + b], lh[b]);
}

// exclusive scan of each seg's NBK bucket counts. grid=3, block=64
__global__ void bscan_kernel(int* __restrict__ bcur) {
  int* b = bcur + blockIdx.x * NBK;
  int lane = threadIdx.x;
  int carry = 0;
  for (int base = 0; base < NBK; base += 64) {
    int i = base + lane;
    int v = b[i];
    int s = v;
    #pragma unroll
    for (int o = 1; o < 64; o <<= 1) {
      int t = __shfl_up(s, o);
      if (lane >= o) s += t;
    }
    b[i] = carry + s - v;
    carry += __shfl(s, 63);
  }
}

// LDS-staged bin: partition packed directed entries into bucket order.
// After this, bcur[seg*NBK+b] = inclusive end offset per bucket.
__global__ void bin_kernel(const int2* __restrict__ tgt, const int2* __restrict__ aux,
                           int E, int Nu, int BPS, int* __restrict__ bcur,
                           int* __restrict__ binned) {
  __shared__ int stage[2 * TILE_BIN];
  __shared__ int lh[NBK];
  __shared__ int loff[NBK];
  __shared__ int gb[NBK];
  __shared__ int lc[NBK];
  __shared__ int wred[4];
  __shared__ int stot;
  int seg = blockIdx.x / BPS;
  int blk = blockIdx.x - seg * BPS;
  const int2* edges = (seg == 0) ? tgt : aux + (size_t)(seg - 1) * E;
  int* out = binned + (size_t)seg * 2 * E;
  int tid = threadIdx.x;
  for (int b = tid; b < NBK; b += 256) lh[b] = 0;
  __syncthreads();
  int e0 = blk * TILE_BIN;
  // pass 1: count
  for (int k = tid; k < TILE_BIN; k += 256) {
    int e = e0 + k;
    if (e < E) {
      int2 ed = edges[e];
      atomicAdd(&lh[ed.x >> BSHIFT], 1);
      atomicAdd(&lh[(ed.y + Nu) >> BSHIFT], 1);
    }
  }
  __syncthreads();
  // block exclusive scan of lh[1024], 4 per thread
  int lane = tid & 63, wid = tid >> 6;
  int b4 = tid * 4;
  int v0 = lh[b4], v1 = lh[b4 + 1], v2 = lh[b4 + 2], v3 = lh[b4 + 3];
  int tsum = v0 + v1 + v2 + v3;
  int incl = tsum;
  #pragma unroll
  for (int o = 1; o < 64; o <<= 1) {
    int t = __shfl_up(incl, o);
    if (lane >= o) incl += t;
  }
  if (lane == 63) wred[wid] = incl;
  __syncthreads();
  int wbase = 0;
  for (int w = 0; w < wid; ++w) wbase += wred[w];
  int excl = wbase + incl - tsum;
  loff[b4] = excl;
  loff[b4 + 1] = excl + v0;
  loff[b4 + 2] = excl + v0 + v1;
  loff[b4 + 3] = excl + v0 + v1 + v2;
  if (tid == 255) stot = excl + tsum;
  // reserve global space, zero cursors
  #pragma unroll
  for (int j = 0; j < 4; ++j) {
    int b = b4 + j;
    int c = lh[b];
    gb[b] = c ? atomicAdd(&bcur[seg * NBK + b], c) : 0;
    lc[b] = 0;
  }
  __syncthreads();
  // pass 2: scatter packed entries into stage (bucket-grouped)
  for (int k = tid; k < TILE_BIN; k += 256) {
    int e = e0 + k;
    if (e < E) {
      int2 ed = edges[e];
      int u = ed.x, v = ed.y + Nu;
      int b1 = u >> BSHIFT, b2 = v >> BSHIFT;
      int p1 = atomicAdd(&lc[b1], 1);
      stage[loff[b1] + p1] = ((u & 255) << 18) | v;
      int p2 = atomicAdd(&lc[b2], 1);
      stage[loff[b2] + p2] = ((v & 255) << 18) | u;
    }
  }
  __syncthreads();
  // flush: contiguous runs per bucket; bucket found by upper_bound on loff
  int tot = stot;
  for (int k = tid; k < tot; k += 256) {
    int lo = 0, hi = NBK;
    while (lo < hi) {
      int mid = (lo + hi) >> 1;
      if (loff[mid] <= k) lo = mid + 1; else hi = mid;
    }
    int b = lo - 1;
    out[gb[b] + (k - loff[b])] = stage[k];
  }
}

// one block per (seg,bucket): LDS counting sort -> deg, rowptr, node-sorted col
__global__ void bucket_csr_kernel(const int* __restrict__ binned,
                                  const int* __restrict__ bend, int E2, int N, int NBKe,
                                  int* __restrict__ deg3, int* __restrict__ rp3,
                                  int* __restrict__ col_all) {
  __shared__ int ent[BCAP];
  __shared__ int cnt[256];
  __shared__ int off[256];
  __shared__ int wred[4];
  int seg = blockIdx.x / NBKe;
  int bkt = blockIdx.x - seg * NBKe;
  int node0 = bkt << BSHIFT;
  const int* bc = bend + seg * NBK;
  int start = (bkt == 0) ? 0 : bc[bkt - 1];
  int end = bc[bkt];
  int cntE = end - start;
  const int* src = binned + (size_t)seg * E2 + start;
  bool inLds = (cntE <= BCAP);
  if (inLds)
    for (int k = threadIdx.x; k < cntE; k += 256) ent[k] = src[k];
  cnt[threadIdx.x] = 0;
  __syncthreads();
  for (int k = threadIdx.x; k < cntE; k += 256) {
    int en = inLds ? ent[k] : src[k];
    atomicAdd(&cnt[en >> 18], 1);
  }
  __syncthreads();
  int lane = threadIdx.x & 63, wid = threadIdx.x >> 6;
  int v = cnt[threadIdx.x];
  int incl = v;
  #pragma unroll
  for (int o = 1; o < 64; o <<= 1) {
    int t = __shfl_up(incl, o);
    if (lane >= o) incl += t;
  }
  if (lane == 63) wred[wid] = incl;
  __syncthreads();
  int wbase = 0;
  for (int w = 0; w < wid; ++w) wbase += wred[w];
  off[threadIdx.x] = wbase + incl - v;
  int node = node0 + (int)threadIdx.x;
  if (node < N) {
    deg3[(size_t)seg * N + node] = v;
    rp3[(size_t)seg * (N + 1) + node] = start + wbase + incl - v;
  }
  if (bkt == 0 && threadIdx.x == 0) rp3[(size_t)seg * (N + 1) + N] = E2;
  __syncthreads();
  cnt[threadIdx.x] = 0;
  __syncthreads();
  int* col = col_all + (size_t)seg * E2 + start;
  for (int k = threadIdx.x; k < cntE; k += 256) {
    int en = inLds ? ent[k] : src[k];
    int lb = en >> 18;
    int pos = atomicAdd(&cnt[lb], 1);
    col[off[lb] + pos] = en & 0x3FFFF;
  }
}

// dinv5: [0]=tgt [1]=aux0 [2]=aux1 [3]=comb0 [4]=comb1
__global__ void dinv_all_kernel(const int* __restrict__ deg3, float* __restrict__ dinv5,
                                int N) {
  int n = blockIdx.x * blockDim.x + threadIdx.x;
  if (n >= N) return;
  int dt = deg3[n], d0 = deg3[N + n], d1 = deg3[2 * N + n];
  dinv5[n]         = dt ? rsqrtf((float)dt) : 0.f;
  dinv5[N + n]     = d0 ? rsqrtf((float)d0) : 0.f;
  dinv5[2 * N + n] = d1 ? rsqrtf((float)d1) : 0.f;
  int c0 = dt + d0, c1 = dt + d1;
  dinv5[3 * N + n] = c0 ? rsqrtf((float)c0) : 0.f;
  dinv5[4 * N + n] = c1 ? rsqrtf((float)c1) : 0.f;
}

// ================= dense propagation (pull / gather) =================

__global__ void gather_kernel(const int* __restrict__ rowptr, const int* __restrict__ col,
                              const float* __restrict__ dinv,
                              const float4* __restrict__ cur, float4* __restrict__ out,
                              int N) {
  int t = blockIdx.x * blockDim.x + threadIdx.x;
  int n = t >> 3;
  if (n >= N) return;
  int lane = t & 7;
  int s = rowptr[n], e = rowptr[n + 1];
  float4 acc = make_float4(0.f, 0.f, 0.f, 0.f);
  for (int j = s; j < e; ++j) {
    int c = col[j];
    float w = dinv[c];
    float4 x = cur[c * 8 + lane];
    acc.x += w * x.x; acc.y += w * x.y; acc.z += w * x.z; acc.w += w * x.w;
  }
  float wn = dinv[n];
  out[n * 8 + lane] = make_float4(wn * acc.x, wn * acc.y, wn * acc.z, wn * acc.w);
}

// aux L2 + avg folded: A = (EMB + Ba + dinv[n]*gather(Ba)) / 3
__global__ void gather_avg_kernel(const int* __restrict__ rowptr, const int* __restrict__ col,
                                  const float* __restrict__ dinv,
                                  const float4* __restrict__ cur,
                                  const float4* __restrict__ emb,
                                  float4* __restrict__ outA, int N) {
  int t = blockIdx.x * blockDim.x + threadIdx.x;
  int n = t >> 3;
  if (n >= N) return;
  int lane = t & 7;
  int s = rowptr[n], e = rowptr[n + 1];
  float4 acc = make_float4(0.f, 0.f, 0.f, 0.f);
  for (int j = s; j < e; ++j) {
    int c = col[j];
    float w = dinv[c];
    float4 x = cur[c * 8 + lane];
    acc.x += w * x.x; acc.y += w * x.y; acc.z += w * x.z; acc.w += w * x.w;
  }
  float wn = dinv[n];
  float4 e0 = emb[n * 8 + lane];
  float4 b0 = cur[n * 8 + lane];
  outA[n * 8 + lane] = make_float4((e0.x + b0.x + wn * acc.x) * (1.f / 3.f),
                                   (e0.y + b0.y + wn * acc.y) * (1.f / 3.f),
                                   (e0.z + b0.z + wn * acc.z) * (1.f / 3.f),
                                   (e0.w + b0.w + wn * acc.w) * (1.f / 3.f));
}

// fused layer-1: aux graph (dinvA) -> outA, comb graph (dinvC) -> outC
__global__ void gather_fused_kernel(const int* __restrict__ rpA, const int* __restrict__ colA,
                                    const int* __restrict__ rpT, const int* __restrict__ colT,
                                    const float* __restrict__ dinvA,
                                    const float* __restrict__ dinvC,
                                    const float4* __restrict__ cur,
                                    float4* __restrict__ outA, float4* __restrict__ outC,
                                    int N) {
  int t = blockIdx.x * blockDim.x + threadIdx.x;
  int n = t >> 3;
  if (n >= N) return;
  int lane = t & 7;
  float4 aA = make_float4(0.f, 0.f, 0.f, 0.f);
  float4 aC = make_float4(0.f, 0.f, 0.f, 0.f);
  int s = rpA[n], e = rpA[n + 1];
  for (int j = s; j < e; ++j) {
    int c = colA[j];
    float wA = dinvA[c];
    float wC = dinvC[c];
    float4 x = cur[c * 8 + lane];
    aA.x += wA * x.x; aA.y += wA * x.y; aA.z += wA * x.z; aA.w += wA * x.w;
    aC.x += wC * x.x; aC.y += wC * x.y; aC.z += wC * x.z; aC.w += wC * x.w;
  }
  s = rpT[n]; e = rpT[n + 1];
  for (int j = s; j < e; ++j) {
    int c = colT[j];
    float wC = dinvC[c];
    float4 x = cur[c * 8 + lane];
    aC.x += wC * x.x; aC.y += wC * x.y; aC.z += wC * x.z; aC.w += wC * x.w;
  }
  float wnA = dinvA[n];
  float wnC = dinvC[n];
  outA[n * 8 + lane] = make_float4(wnA * aA.x, wnA * aA.y, wnA * aA.z, wnA * aA.w);
  outC[n * 8 + lane] = make_float4(wnC * aC.x, wnC * aC.y, wnC * aC.z, wnC * aC.w);
}

// ================= sparse L2 + score =================

__device__ __forceinline__ float final_dim(const int* __restrict__ rpA,
                                           const int* __restrict__ colA,
                                           const int* __restrict__ rpT,
                                           const int* __restrict__ colT,
                                           const float* __restrict__ dinv,
                                           const float* __restrict__ base,
                                           const float* __restrict__ L1,
                                           int r, int d) {
  float acc = 0.f;
  int s = rpA[r], e = rpA[r + 1];
  for (int j = s; j < e; ++j) {
    int c = colA[j];
    acc += dinv[c] * L1[(size_t)c * D + d];
  }
  if (colT != nullptr) {
    s = rpT[r]; e = rpT[r + 1];
    for (int j = s; j < e; ++j) {
      int c = colT[j];
      acc += dinv[c] * L1[(size_t)c * D + d];
    }
  }
  return (base[(size_t)r * D + d] + L1[(size_t)r * D + d] + dinv[r] * acc) * (1.f / 3.f);
}

__global__ void score_sparse_kernel(const int* __restrict__ rpA, const int* __restrict__ colA,
                                    const int* __restrict__ rpT, const int* __restrict__ colT,
                                    const float* __restrict__ dinv,
                                    const float* __restrict__ base,
                                    const float* __restrict__ L1,
                                    const int* __restrict__ batch, int Bsz, int Nu,
                                    float* __restrict__ outp, float* __restrict__ outn) {
  int t = blockIdx.x * blockDim.x + threadIdx.x;
  int b = t >> 5;
  int d = t & 31;
  if (b >= Bsz) return;
  int u = batch[b * 9 + 0];
  int p = batch[b * 9 + 1] + Nu;
  int n = batch[b * 9 + 2] + Nu;
  float uv = final_dim(rpA, colA, rpT, colT, dinv, base, L1, u, d);
  float pv = final_dim(rpA, colA, rpT, colT, dinv, base, L1, p, d);
  float nv = final_dim(rpA, colA, rpT, colT, dinv, base, L1, n, d);
  float sp = uv * pv, sn = uv * nv;
  #pragma unroll
  for (int o = 16; o > 0; o >>= 1) {
    sp += __shfl_down(sp, o, 32);
    sn += __shfl_down(sn, o, 32);
  }
  if (d == 0) {
    outp[b] = fmaxf(sp, 0.f);
    outn[b] = fmaxf(sn, 0.f);
  }
}

// ================= batch scores / losses on materialized A =================

__device__ __forceinline__ float dot1_rows(const float* __restrict__ A, int r1, int r2) {
  const float* a1 = A + (size_t)r1 * D;
  const float* a2 = A + (size_t)r2 * D;
  float s = 0.f;
#pragma unroll
  for (int k = 0; k < D; ++k) s += a1[k] * a2[k];
  return s;
}

// merged: aps/ans (relu'd) + aux BPR loss (non-relu'd, different rows)
__global__ void score_aux_kernel(const float* __restrict__ A, const int* __restrict__ batch,
                                 int Bsz, int Nu, int idx, float* __restrict__ outp,
                                 float* __restrict__ outn, float* __restrict__ acc) {
  int b = blockIdx.x * blockDim.x + threadIdx.x;
  float l = 0.f;
  if (b < Bsz) {
    int u = batch[b * 9 + 0];
    int p = batch[b * 9 + 1] + Nu;
    int n = batch[b * 9 + 2] + Nu;
    outp[b] = fmaxf(dot1_rows(A, u, p), 0.f);
    outn[b] = fmaxf(dot1_rows(A, u, n), 0.f);
    const int* r = batch + b * 9 + 3 * (1 + idx);
    int au = r[0];
    int ap = r[1] + Nu;
    int an = r[2] + Nu;
    l = -logsigf(dot1_rows(A, au, ap) - dot1_rows(A, au, an));
  }
  for (int o = 32; o > 0; o >>= 1) l += __shfl_down(l, o);
  if ((threadIdx.x & 63) == 0) atomicAdd(acc, l);
}

__global__ void recloss_kernel(const float* __restrict__ cps, const float* __restrict__ cns,
                               const float* __restrict__ aps, const float* __restrict__ ans_,
                               const float* __restrict__ dps, const float* __restrict__ dns,
                               int Bsz, int NA, float* __restrict__ acc) {
  int b = blockIdx.x * blockDim.x + threadIdx.x;
  float l = 0.f;
  if (b < Bsz) {
    float dp = 0.f, dn = 0.f, cap = 0.f, can = 0.f;
    for (int i = 0; i < NA; ++i) {
      dp += dps[i * Bsz + b];
      dn += dns[i * Bsz + b];
      cap += cps[i * Bsz + b] * aps[i * Bsz + b];
      can += cns[i * Bsz + b] * ans_[i * Bsz + b];
    }
    l = -logsigf(dp * cap - dn * can);
  }
  for (int o = 32; o > 0; o >>= 1) l += __shfl_down(l, o);
  if ((threadIdx.x & 63) == 0) atomicAdd(acc, l);
}

// both Frobenius sums in one launch, block-reduced (few atomics)
__global__ void sumsq2_kernel(const float4* __restrict__ xu, int n4u,
                              const float4* __restrict__ xi, int n4i,
                              float* __restrict__ accU, float* __restrict__ accI) {
  __shared__ float redU[4], redI[4];
  int tid = threadIdx.x;
  int gid = blockIdx.x * blockDim.x + tid;
  int stride = gridDim.x * blockDim.x;
  float su = 0.f, si = 0.f;
  for (int i = gid; i < n4u; i += stride) {
    float4 v = xu[i];
    su += v.x * v.x + v.y * v.y + v.z * v.z + v.w * v.w;
  }
  for (int i = gid; i < n4i; i += stride) {
    float4 v = xi[i];
    si += v.x * v.x + v.y * v.y + v.z * v.z + v.w * v.w;
  }
  for (int o = 32; o > 0; o >>= 1) {
    su += __shfl_down(su, o);
    si += __shfl_down(si, o);
  }
  if ((tid & 63) == 0) { redU[tid >> 6] = su; redI[tid >> 6] = si; }
  __syncthreads();
  if (tid == 0) {
    atomicAdd(accU, redU[0] + redU[1] + redU[2] + redU[3]);
    atomicAdd(accI, redI[0] + redI[1] + redI[2] + redI[3]);
  }
}

__global__ void final_kernel(const float* __restrict__ accs, int Bsz, int NA, int NiRows,
                             float* __restrict__ out) {
  float rec = accs[NA] / (float)Bsz;
  float aux = 0.f;
  for (int i = 0; i < NA; ++i) aux += accs[i] / (float)Bsz;
  aux /= (float)NA;
  float embl = (sqrtf(accs[NA + 1]) + sqrtf(accs[NA + 2])) / (float)NiRows;
  out[0] = rec + 0.5f * aux + 1e-4f * embl;
}

extern "C" void kernel_launch(void* const* d_in, const int* in_sizes, int n_in,
                              void* d_out, int out_size, void* d_ws, size_t ws_size,
                              hipStream_t stream) {
  const float* user_emb = (const float*)d_in[0];
  const float* item_emb = (const float*)d_in[1];
  const int* batch = (const int*)d_in[2];
  const int* aux_edges = (const int*)d_in[3];
  const int* tgt_edges = (const int*)d_in[4];

  const int NuRows = in_sizes[0] / D;          // 100001
  const int NiRows = in_sizes[1] / D;          // 50001
  const int Bsz = in_sizes[2] / 9;             // 4096
  const int E = in_sizes[4] / 2;               // 1,000,000
  const int NA = in_sizes[3] / (2 * E);        // 2
  const int N = NuRows + NiRows;               // 150002 < 2^18 (pack invariant)
  const int E2 = 2 * E;
  const size_t rowElems = (size_t)N * D;
  const int BPS_H = (E + TILE_H - 1) / TILE_H;
  const int BPS_B = (E + TILE_BIN - 1) / TILE_BIN;
  const int NBKe = (N + (1 << BSHIFT) - 1) >> BSHIFT;

  // ---- workspace layout ----
  float* EMB = (float*)d_ws;
  float* A = EMB + rowElems;
  float* Ba = A + rowElems;
  float* Bc = Ba + rowElems;
  int* deg3 = (int*)(Bc + rowElems);              // 3*N
  float* dinv5 = (float*)(deg3 + 3 * (size_t)N);  // 5*N
  int* rp3 = (int*)(dinv5 + 5 * (size_t)N);       // 3*(N+1)
  int* bcur = rp3 + 3 * (size_t)(N + 1);          // 3*NBK
  int* col_all = bcur + 3 * (size_t)NBK;          // 3*2E
  float* cps = (float*)(col_all + 3 * (size_t)E2);
  float* cns = cps + (size_t)NA * Bsz;
  float* aps = cns + (size_t)NA * Bsz;
  float* ans_ = aps + (size_t)NA * Bsz;
  float* dps = ans_ + (size_t)NA * Bsz;
  float* dns = dps + (size_t)NA * Bsz;
  float* accs = dns + (size_t)NA * Bsz;           // [NA aux][rec][sumsq_u][sumsq_i]
  // binned (3*2E packed ints = 24 MB) aliased onto A/Ba (38.4 MB); dead before gathers
  int* binned = (int*)A;

  const int TB = 256;
  const int gN = (N + TB - 1) / TB;
  const int gN8 = (N * 8 + TB - 1) / TB;
  const int gB = (Bsz + TB - 1) / TB;
  const int gB32 = (Bsz * 32 + TB - 1) / TB;

  hipMemcpyAsync(EMB, user_emb, (size_t)NuRows * D * sizeof(float),
                 hipMemcpyDeviceToDevice, stream);
  hipMemcpyAsync(EMB + (size_t)NuRows * D, item_emb, (size_t)NiRows * D * sizeof(float),
                 hipMemcpyDeviceToDevice, stream);

  // ---- binned CSR build ----
  hipMemsetAsync(bcur, 0, 3 * (size_t)NBK * sizeof(int), stream);
  hist_kernel<<<3 * BPS_H, TB, 0, stream>>>((const int2*)tgt_edges, (const int2*)aux_edges,
                                            E, NuRows, BPS_H, bcur);
  bscan_kernel<<<3, 64, 0, stream>>>(bcur);
  bin_kernel<<<3 * BPS_B, TB, 0, stream>>>((const int2*)tgt_edges, (const int2*)aux_edges,
                                           E, NuRows, BPS_B, bcur, binned);
  bucket_csr_kernel<<<3 * NBKe, TB, 0, stream>>>(binned, bcur, E2, N, NBKe,
                                                 deg3, rp3, col_all);
  dinv_all_kernel<<<gN, TB, 0, stream>>>(deg3, dinv5, N);

  hipMemsetAsync(accs, 0, (size_t)(NA + 3) * sizeof(float), stream);

  const int* rpT = rp3;
  const int* colT = col_all;
  const float* dvT = dinv5;

  for (int idx = 0; idx < NA; ++idx) {
    const int* rpA = rp3 + (size_t)(1 + idx) * (N + 1);
    const int* colA = col_all + (size_t)(1 + idx) * E2;
    const float* dvA = dinv5 + (size_t)(1 + idx) * N;
    const float* dvC = dinv5 + (size_t)(3 + idx) * N;

    // dense fused layer-1: Ba = aux L1, Bc = comb L1 (binned alias dead now)
    gather_fused_kernel<<<gN8, TB, 0, stream>>>(rpA, colA, rpT, colT, dvA, dvC,
                                                (const float4*)EMB, (float4*)Ba,
                                                (float4*)Bc, N);
    // dense aux L2 + avg: A = (EMB + Ba + gather(Ba))/3
    gather_avg_kernel<<<gN8, TB, 0, stream>>>(rpA, colA, dvA, (const float4*)Ba,
                                              (const float4*)EMB, (float4*)A, N);
    score_aux_kernel<<<gB, TB, 0, stream>>>(A, batch, Bsz, NuRows, idx,
                                            aps + (size_t)idx * Bsz,
                                            ans_ + (size_t)idx * Bsz, accs + idx);

    // sparse comb L2 + ce scores
    score_sparse_kernel<<<gB32, TB, 0, stream>>>(rpA, colA, rpT, colT, dvC, EMB, Bc,
                                                 batch, Bsz, NuRows,
                                                 cps + (size_t)idx * Bsz,
                                                 cns + (size_t)idx * Bsz);

    // dense de layer-1: Ba = gather(A over tgt)   (Ba dead after gather_avg)
    gather_kernel<<<gN8, TB, 0, stream>>>(rpT, colT, dvT, (const float4*)A,
                                          (float4*)Ba, N);
    // sparse de L2 + scores
    score_sparse_kernel<<<gB32, TB, 0, stream>>>(rpT, colT, nullptr, nullptr, dvT, A, Ba,
                                                 batch, Bsz, NuRows,
                                                 dps + (size_t)idx * Bsz,
                                                 dns + (size_t)idx * Bsz);
  }

  sumsq2_kernel<<<104, TB, 0, stream>>>((const float4*)user_emb,
                                        (int)((size_t)NuRows * D / 4),
                                        (const float4*)item_emb,
                                        (int)((size_t)NiRows * D / 4),
                                        accs + NA + 1, accs + NA + 2);

  recloss_kernel<<<gB, TB, 0, stream>>>(cps, cns, aps, ans_, dps, dns, Bsz, NA, accs + NA);

  final_kernel<<<1, 1, 0, stream>>>(accs, Bsz, NA, NiRows, (float*)d_out);
}

// Round 7
// 730.395 us; speedup vs baseline: 18.5875x; 1.3095x over previous
//
#include <hip/hip_runtime.h>
#include <math.h>

#define D 32
#define ROWU 16           // uints per bf16 row (32 bf16 = 64 B)
#define NBK 1024          // bucket slots per segment
#define BSHIFT 8          // bucket = node >> 8  (256 nodes per bucket)
#define TILE_H 16384      // undirected edges per hist block
#define TILE_BIN 2048     // undirected edges per bin block (8 per thread)
#define BCAP 7680         // LDS packed-entry capacity in bucket_csr

typedef unsigned int u32;
typedef unsigned short u16;

__device__ __forceinline__ float logsigf(float x) {
  return fminf(x, 0.f) - log1pf(expf(-fabsf(x)));
}

// ---- bf16 helpers (storage bf16, math fp32) ----
__device__ __forceinline__ float lo16(u32 u) { return __uint_as_float(u << 16); }
__device__ __forceinline__ float hi16(u32 u) { return __uint_as_float(u & 0xFFFF0000u); }
__device__ __forceinline__ u32 pk2(float a, float b) {  // RNE pack
  u32 ua = __float_as_uint(a), ub = __float_as_uint(b);
  u32 ra = (ua + 0x7FFFu + ((ua >> 16) & 1u)) >> 16;
  u32 rb = (ub + 0x7FFFu + ((ub >> 16) & 1u)) >> 16;
  return (ra & 0xFFFFu) | (rb << 16);
}
__device__ __forceinline__ float bfat(const u16* __restrict__ p, size_t off) {
  return __uint_as_float(((u32)p[off]) << 16);
}
__device__ __forceinline__ void accum8(float* a, float w, uint4 x) {
  a[0] += w * lo16(x.x); a[1] += w * hi16(x.x);
  a[2] += w * lo16(x.y); a[3] += w * hi16(x.y);
  a[4] += w * lo16(x.z); a[5] += w * hi16(x.z);
  a[6] += w * lo16(x.w); a[7] += w * hi16(x.w);
}
__device__ __forceinline__ uint4 pack8(const float* a, float w) {
  return make_uint4(pk2(w * a[0], w * a[1]), pk2(w * a[2], w * a[3]),
                    pk2(w * a[4], w * a[5]), pk2(w * a[6], w * a[7]));
}

// ================= CSR build via bucket binning =================
// seg 0 = tgt, 1 = aux0, 2 = aux1. Directed entry packed: (dst_local<<18)|src.

__global__ void hist_kernel(const int2* __restrict__ tgt, const int2* __restrict__ aux,
                            int E, int Nu, int BPS, int* __restrict__ bcur) {
  __shared__ int lh[NBK];
  int seg = blockIdx.x / BPS;
  int blk = blockIdx.x - seg * BPS;
  const int2* edges = (seg == 0) ? tgt : aux + (size_t)(seg - 1) * E;
  for (int b = threadIdx.x; b < NBK; b += 256) lh[b] = 0;
  __syncthreads();
  int e0 = blk * TILE_H;
  for (int k = threadIdx.x; k < TILE_H; k += 256) {
    int e = e0 + k;
    if (e < E) {
      int2 ed = edges[e];
      atomicAdd(&lh[ed.x >> BSHIFT], 1);
      atomicAdd(&lh[(ed.y + Nu) >> BSHIFT], 1);
    }
  }
  __syncthreads();
  for (int b = threadIdx.x; b < NBK; b += 256)
    if (lh[b]) atomicAdd(&bcur[seg * NBK + b], lh[b]);
}

__global__ void bscan_kernel(int* __restrict__ bcur) {
  int* b = bcur + blockIdx.x * NBK;
  int lane = threadIdx.x;
  int carry = 0;
  for (int base = 0; base < NBK; base += 64) {
    int i = base + lane;
    int v = b[i];
    int s = v;
    #pragma unroll
    for (int o = 1; o < 64; o <<= 1) {
      int t = __shfl_up(s, o);
      if (lane >= o) s += t;
    }
    b[i] = carry + s - v;
    carry += __shfl(s, 63);
  }
}

// bin: pass1 counts AND captures per-entry rank (atomic return) in registers;
// pass2 writes stage with no LDS atomics; flush via binary search on loff.
__global__ void bin_kernel(const int2* __restrict__ tgt, const int2* __restrict__ aux,
                           int E, int Nu, int BPS, int* __restrict__ bcur,
                           int* __restrict__ binned) {
  __shared__ int stage[2 * TILE_BIN];
  __shared__ int lh[NBK];
  __shared__ int loff[NBK];
  __shared__ int gb[NBK];
  __shared__ int wred[4];
  __shared__ int stot;
  int seg = blockIdx.x / BPS;
  int blk = blockIdx.x - seg * BPS;
  const int2* edges = (seg == 0) ? tgt : aux + (size_t)(seg - 1) * E;
  int* out = binned + (size_t)seg * 2 * E;
  int tid = threadIdx.x;
  for (int b = tid; b < NBK; b += 256) lh[b] = 0;
  __syncthreads();
  int e0 = blk * TILE_BIN;
  int pkv[16];
  int pb[16];
  int pr[16];
  #pragma unroll
  for (int it = 0; it < 8; ++it) {
    int e = e0 + tid + it * 256;
    bool ok = e < E;
    int2 ed = ok ? edges[e] : make_int2(0, -Nu);
    int u = ed.x, v = ed.y + Nu;
    int b1 = u >> BSHIFT, b2 = v >> BSHIFT;
    pkv[2 * it] = ((u & 255) << 18) | v;
    pb[2 * it] = b1;
    pr[2 * it] = ok ? atomicAdd(&lh[b1], 1) : 0;
    pkv[2 * it + 1] = ((v & 255) << 18) | u;
    pb[2 * it + 1] = b2;
    pr[2 * it + 1] = ok ? atomicAdd(&lh[b2], 1) : 0;
  }
  __syncthreads();
  // block exclusive scan of lh[1024], 4 per thread
  int lane = tid & 63, wid = tid >> 6;
  int b4 = tid * 4;
  int v0 = lh[b4], v1 = lh[b4 + 1], v2 = lh[b4 + 2], v3 = lh[b4 + 3];
  int tsum = v0 + v1 + v2 + v3;
  int incl = tsum;
  #pragma unroll
  for (int o = 1; o < 64; o <<= 1) {
    int t = __shfl_up(incl, o);
    if (lane >= o) incl += t;
  }
  if (lane == 63) wred[wid] = incl;
  __syncthreads();
  int wbase = 0;
  for (int w = 0; w < wid; ++w) wbase += wred[w];
  int excl = wbase + incl - tsum;
  loff[b4] = excl;
  loff[b4 + 1] = excl + v0;
  loff[b4 + 2] = excl + v0 + v1;
  loff[b4 + 3] = excl + v0 + v1 + v2;
  if (tid == 255) stot = excl + tsum;
  #pragma unroll
  for (int j = 0; j < 4; ++j) {
    int b = b4 + j;
    int c = lh[b];
    gb[b] = c ? atomicAdd(&bcur[seg * NBK + b], c) : 0;
  }
  __syncthreads();
  #pragma unroll
  for (int it = 0; it < 16; ++it) {
    int e = e0 + tid + (it >> 1) * 256;
    if (e < E) stage[loff[pb[it]] + pr[it]] = pkv[it];
  }
  __syncthreads();
  int tot = stot;
  for (int k = tid; k < tot; k += 256) {
    int lo = 0, hi = NBK;
    while (lo < hi) {
      int mid = (lo + hi) >> 1;
      if (loff[mid] <= k) lo = mid + 1; else hi = mid;
    }
    int b = lo - 1;
    out[gb[b] + (k - loff[b])] = stage[k];
  }
}

__global__ void bucket_csr_kernel(const int* __restrict__ binned,
                                  const int* __restrict__ bend, int E2, int N, int NBKe,
                                  int* __restrict__ deg3, int* __restrict__ rp3,
                                  int* __restrict__ col_all) {
  __shared__ int ent[BCAP];
  __shared__ int cnt[256];
  __shared__ int off[256];
  __shared__ int wred[4];
  int seg = blockIdx.x / NBKe;
  int bkt = blockIdx.x - seg * NBKe;
  int node0 = bkt << BSHIFT;
  const int* bc = bend + seg * NBK;
  int start = (bkt == 0) ? 0 : bc[bkt - 1];
  int end = bc[bkt];
  int cntE = end - start;
  const int* src = binned + (size_t)seg * E2 + start;
  bool inLds = (cntE <= BCAP);
  if (inLds)
    for (int k = threadIdx.x; k < cntE; k += 256) ent[k] = src[k];
  cnt[threadIdx.x] = 0;
  __syncthreads();
  for (int k = threadIdx.x; k < cntE; k += 256) {
    int en = inLds ? ent[k] : src[k];
    atomicAdd(&cnt[en >> 18], 1);
  }
  __syncthreads();
  int lane = threadIdx.x & 63, wid = threadIdx.x >> 6;
  int v = cnt[threadIdx.x];
  int incl = v;
  #pragma unroll
  for (int o = 1; o < 64; o <<= 1) {
    int t = __shfl_up(incl, o);
    if (lane >= o) incl += t;
  }
  if (lane == 63) wred[wid] = incl;
  __syncthreads();
  int wbase = 0;
  for (int w = 0; w < wid; ++w) wbase += wred[w];
  off[threadIdx.x] = wbase + incl - v;
  int node = node0 + (int)threadIdx.x;
  if (node < N) {
    deg3[(size_t)seg * N + node] = v;
    rp3[(size_t)seg * (N + 1) + node] = start + wbase + incl - v;
  }
  if (bkt == 0 && threadIdx.x == 0) rp3[(size_t)seg * (N + 1) + N] = E2;
  __syncthreads();
  cnt[threadIdx.x] = 0;
  __syncthreads();
  int* col = col_all + (size_t)seg * E2 + start;
  for (int k = threadIdx.x; k < cntE; k += 256) {
    int en = inLds ? ent[k] : src[k];
    int lb = en >> 18;
    int pos = atomicAdd(&cnt[lb], 1);
    col[off[lb] + pos] = en & 0x3FFFF;
  }
}

__global__ void dinv_all_kernel(const int* __restrict__ deg3, float* __restrict__ dinv5,
                                int N) {
  int n = blockIdx.x * blockDim.x + threadIdx.x;
  if (n >= N) return;
  int dt = deg3[n], d0 = deg3[N + n], d1 = deg3[2 * N + n];
  dinv5[n]         = dt ? rsqrtf((float)dt) : 0.f;
  dinv5[N + n]     = d0 ? rsqrtf((float)d0) : 0.f;
  dinv5[2 * N + n] = d1 ? rsqrtf((float)d1) : 0.f;
  int c0 = dt + d0, c1 = dt + d1;
  dinv5[3 * N + n] = c0 ? rsqrtf((float)c0) : 0.f;
  dinv5[4 * N + n] = c1 ? rsqrtf((float)c1) : 0.f;
}

// fp32 inputs -> bf16 EMB (concat user, item)
__global__ void cvt_emb_kernel(const float2* __restrict__ ue, long nu2,
                               const float2* __restrict__ ie, long ni2,
                               u32* __restrict__ emb) {
  long i = (long)blockIdx.x * blockDim.x + threadIdx.x;
  if (i >= nu2 + ni2) return;
  float2 v = (i < nu2) ? ue[i] : ie[i - nu2];
  emb[i] = pk2(v.x, v.y);
}

// ================= dense propagation (bf16 rows, 4 lanes/node) =================

__global__ void gather_fused_kernel(const int* __restrict__ rp3, const int* __restrict__ col_all,
                                    const float* __restrict__ dinv5,
                                    const uint4* __restrict__ emb,
                                    uint4* __restrict__ BaAll, uint4* __restrict__ BcAll,
                                    int N, int E2) {
  int idx = blockIdx.y;
  const int* rpA = rp3 + (size_t)(1 + idx) * (N + 1);
  const int* colA = col_all + (size_t)(1 + idx) * E2;
  const int* rpT = rp3;
  const int* colT = col_all;
  const float* dvA = dinv5 + (size_t)(1 + idx) * N;
  const float* dvC = dinv5 + (size_t)(3 + idx) * N;
  uint4* outA = BaAll + (size_t)idx * N * 4;
  uint4* outC = BcAll + (size_t)idx * N * 4;
  int t = blockIdx.x * blockDim.x + threadIdx.x;
  int n = t >> 2;
  if (n >= N) return;
  int lane = t & 3;
  float aA[8] = {0, 0, 0, 0, 0, 0, 0, 0};
  float aC[8] = {0, 0, 0, 0, 0, 0, 0, 0};
  int s = rpA[n], e = rpA[n + 1];
  for (int j = s; j < e; ++j) {
    int c = colA[j];
    float wA = dvA[c], wC = dvC[c];
    uint4 x = emb[(size_t)c * 4 + lane];
    accum8(aA, wA, x);
    accum8(aC, wC, x);
  }
  s = rpT[n]; e = rpT[n + 1];
  for (int j = s; j < e; ++j) {
    int c = colT[j];
    float wC = dvC[c];
    uint4 x = emb[(size_t)c * 4 + lane];
    accum8(aC, wC, x);
  }
  outA[(size_t)n * 4 + lane] = pack8(aA, dvA[n]);
  outC[(size_t)n * 4 + lane] = pack8(aC, dvC[n]);
}

// aux L2 + avg: A(idx) = (EMB + Ba + dinv*gather(Ba))/3
__global__ void gather_avg_kernel(const int* __restrict__ rp3, const int* __restrict__ col_all,
                                  const float* __restrict__ dinv5,
                                  const uint4* __restrict__ emb,
                                  const uint4* __restrict__ BaAll, uint4* __restrict__ AAll,
                                  int N, int E2) {
  int idx = blockIdx.y;
  const int* rp = rp3 + (size_t)(1 + idx) * (N + 1);
  const int* col = col_all + (size_t)(1 + idx) * E2;
  const float* dv = dinv5 + (size_t)(1 + idx) * N;
  const uint4* cur = BaAll + (size_t)idx * N * 4;
  uint4* outA = AAll + (size_t)idx * N * 4;
  int t = blockIdx.x * blockDim.x + threadIdx.x;
  int n = t >> 2;
  if (n >= N) return;
  int lane = t & 3;
  float acc[8] = {0, 0, 0, 0, 0, 0, 0, 0};
  int s = rp[n], e = rp[n + 1];
  for (int j = s; j < e; ++j) {
    int c = col[j];
    float w = dv[c];
    uint4 x = cur[(size_t)c * 4 + lane];
    accum8(acc, w, x);
  }
  float wn = dv[n];
  uint4 e4 = emb[(size_t)n * 4 + lane];
  uint4 b4 = cur[(size_t)n * 4 + lane];
  float r[8];
  r[0] = (lo16(e4.x) + lo16(b4.x) + wn * acc[0]) * (1.f / 3.f);
  r[1] = (hi16(e4.x) + hi16(b4.x) + wn * acc[1]) * (1.f / 3.f);
  r[2] = (lo16(e4.y) + lo16(b4.y) + wn * acc[2]) * (1.f / 3.f);
  r[3] = (hi16(e4.y) + hi16(b4.y) + wn * acc[3]) * (1.f / 3.f);
  r[4] = (lo16(e4.z) + lo16(b4.z) + wn * acc[4]) * (1.f / 3.f);
  r[5] = (hi16(e4.z) + hi16(b4.z) + wn * acc[5]) * (1.f / 3.f);
  r[6] = (lo16(e4.w) + lo16(b4.w) + wn * acc[6]) * (1.f / 3.f);
  r[7] = (hi16(e4.w) + hi16(b4.w) + wn * acc[7]) * (1.f / 3.f);
  outA[(size_t)n * 4 + lane] = pack8(r, 1.f);
}

// de layer-1: Ba(idx) = dinv_tgt-gather of A(idx) over tgt graph
__global__ void de_gather_kernel(const int* __restrict__ rp3, const int* __restrict__ col_all,
                                 const float* __restrict__ dinv5,
                                 const uint4* __restrict__ AAll, uint4* __restrict__ BaAll,
                                 int N, int E2) {
  int idx = blockIdx.y;
  const uint4* cur = AAll + (size_t)idx * N * 4;
  uint4* out = BaAll + (size_t)idx * N * 4;
  int t = blockIdx.x * blockDim.x + threadIdx.x;
  int n = t >> 2;
  if (n >= N) return;
  int lane = t & 3;
  float acc[8] = {0, 0, 0, 0, 0, 0, 0, 0};
  int s = rp3[n], e = rp3[n + 1];
  for (int j = s; j < e; ++j) {
    int c = col_all[j];
    float w = dinv5[c];
    uint4 x = cur[(size_t)c * 4 + lane];
    accum8(acc, w, x);
  }
  out[(size_t)n * 4 + lane] = pack8(acc, dinv5[n]);
}

// ================= sparse L2 + score (bf16 rows) =================

__device__ __forceinline__ float fdim2(const int* __restrict__ rpA, const int* __restrict__ colA,
                                       const int* __restrict__ rpT, const int* __restrict__ colT,
                                       const float* __restrict__ dv,
                                       const u16* __restrict__ base, const u16* __restrict__ L1,
                                       int r, int d) {
  float acc = 0.f;
  for (int j = rpA[r]; j < rpA[r + 1]; ++j) {
    int c = colA[j];
    acc += dv[c] * bfat(L1, (size_t)c * D + d);
  }
  if (colT != nullptr) {
    for (int j = rpT[r]; j < rpT[r + 1]; ++j) {
      int c = colT[j];
      acc += dv[c] * bfat(L1, (size_t)c * D + d);
    }
  }
  return (bfat(base, (size_t)r * D + d) + bfat(L1, (size_t)r * D + d) + dv[r] * acc) * (1.f / 3.f);
}

__global__ void ce_sparse_kernel(const int* __restrict__ rp3, const int* __restrict__ col_all,
                                 const float* __restrict__ dinv5,
                                 const u32* __restrict__ EMBu, const u32* __restrict__ BcAll,
                                 const int* __restrict__ batch, int Bsz, int Nu, int N, int E2,
                                 float* __restrict__ cps, float* __restrict__ cns) {
  int idx = blockIdx.y;
  const int* rpA = rp3 + (size_t)(1 + idx) * (N + 1);
  const int* colA = col_all + (size_t)(1 + idx) * E2;
  const float* dv = dinv5 + (size_t)(3 + idx) * N;
  const u16* base = (const u16*)EMBu;
  const u16* L1 = (const u16*)(BcAll + (size_t)idx * N * ROWU);
  float* outp = cps + (size_t)idx * Bsz;
  float* outn = cns + (size_t)idx * Bsz;
  int t = blockIdx.x * blockDim.x + threadIdx.x;
  int b = t >> 5, d = t & 31;
  if (b >= Bsz) return;
  int u = batch[b * 9 + 0];
  int p = batch[b * 9 + 1] + Nu;
  int n = batch[b * 9 + 2] + Nu;
  float uv = fdim2(rpA, colA, rp3, col_all, dv, base, L1, u, d);
  float pv = fdim2(rpA, colA, rp3, col_all, dv, base, L1, p, d);
  float nv = fdim2(rpA, colA, rp3, col_all, dv, base, L1, n, d);
  float sp = uv * pv, sn = uv * nv;
  #pragma unroll
  for (int o = 16; o > 0; o >>= 1) {
    sp += __shfl_down(sp, o, 32);
    sn += __shfl_down(sn, o, 32);
  }
  if (d == 0) {
    outp[b] = fmaxf(sp, 0.f);
    outn[b] = fmaxf(sn, 0.f);
  }
}

__global__ void de_sparse_kernel(const int* __restrict__ rp3, const int* __restrict__ col_all,
                                 const float* __restrict__ dinv5,
                                 const u32* __restrict__ AAll, const u32* __restrict__ BaAll,
                                 const int* __restrict__ batch, int Bsz, int Nu, int N, int E2,
                                 float* __restrict__ dps, float* __restrict__ dns) {
  int idx = blockIdx.y;
  const u16* base = (const u16*)(AAll + (size_t)idx * N * ROWU);
  const u16* L1 = (const u16*)(BaAll + (size_t)idx * N * ROWU);
  float* outp = dps + (size_t)idx * Bsz;
  float* outn = dns + (size_t)idx * Bsz;
  int t = blockIdx.x * blockDim.x + threadIdx.x;
  int b = t >> 5, d = t & 31;
  if (b >= Bsz) return;
  int u = batch[b * 9 + 0];
  int p = batch[b * 9 + 1] + Nu;
  int n = batch[b * 9 + 2] + Nu;
  float uv = fdim2(rp3, col_all, nullptr, nullptr, dinv5, base, L1, u, d);
  float pv = fdim2(rp3, col_all, nullptr, nullptr, dinv5, base, L1, p, d);
  float nv = fdim2(rp3, col_all, nullptr, nullptr, dinv5, base, L1, n, d);
  float sp = uv * pv, sn = uv * nv;
  #pragma unroll
  for (int o = 16; o > 0; o >>= 1) {
    sp += __shfl_down(sp, o, 32);
    sn += __shfl_down(sn, o, 32);
  }
  if (d == 0) {
    outp[b] = fmaxf(sp, 0.f);
    outn[b] = fmaxf(sn, 0.f);
  }
}

// ================= batch scores / losses on materialized A (bf16) =================

__device__ __forceinline__ float dotrow(const u32* __restrict__ a, const u32* __restrict__ b) {
  float s = 0.f;
  #pragma unroll
  for (int k = 0; k < ROWU; ++k) {
    u32 x = a[k], y = b[k];
    s += lo16(x) * lo16(y) + hi16(x) * hi16(y);
  }
  return s;
}

__global__ void score_aux_kernel(const u32* __restrict__ AAll, const int* __restrict__ batch,
                                 int Bsz, int Nu, int N, float* __restrict__ aps,
                                 float* __restrict__ ans_, float* __restrict__ accs) {
  int idx = blockIdx.y;
  const u32* A = AAll + (size_t)idx * N * ROWU;
  float* outp = aps + (size_t)idx * Bsz;
  float* outn = ans_ + (size_t)idx * Bsz;
  int b = blockIdx.x * blockDim.x + threadIdx.x;
  float l = 0.f;
  if (b < Bsz) {
    int u = batch[b * 9 + 0];
    int p = batch[b * 9 + 1] + Nu;
    int n = batch[b * 9 + 2] + Nu;
    const u32* ur = A + (size_t)u * ROWU;
    outp[b] = fmaxf(dotrow(ur, A + (size_t)p * ROWU), 0.f);
    outn[b] = fmaxf(dotrow(ur, A + (size_t)n * ROWU), 0.f);
    const int* r = batch + b * 9 + 3 * (1 + idx);
    const u32* aur = A + (size_t)r[0] * ROWU;
    float ps = dotrow(aur, A + (size_t)(r[1] + Nu) * ROWU);
    float ns = dotrow(aur, A + (size_t)(r[2] + Nu) * ROWU);
    l = -logsigf(ps - ns);
  }
  for (int o = 32; o > 0; o >>= 1) l += __shfl_down(l, o);
  if ((threadIdx.x & 63) == 0) atomicAdd(&accs[idx], l);
}

__global__ void recloss_kernel(const float* __restrict__ cps, const float* __restrict__ cns,
                               const float* __restrict__ aps, const float* __restrict__ ans_,
                               const float* __restrict__ dps, const float* __restrict__ dns,
                               int Bsz, int NA, float* __restrict__ acc) {
  int b = blockIdx.x * blockDim.x + threadIdx.x;
  float l = 0.f;
  if (b < Bsz) {
    float dp = 0.f, dn = 0.f, cap = 0.f, can = 0.f;
    for (int i = 0; i < NA; ++i) {
      dp += dps[i * Bsz + b];
      dn += dns[i * Bsz + b];
      cap += cps[i * Bsz + b] * aps[i * Bsz + b];
      can += cns[i * Bsz + b] * ans_[i * Bsz + b];
    }
    l = -logsigf(dp * cap - dn * can);
  }
  for (int o = 32; o > 0; o >>= 1) l += __shfl_down(l, o);
  if ((threadIdx.x & 63) == 0) atomicAdd(acc, l);
}

__global__ void sumsq2_kernel(const float4* __restrict__ xu, int n4u,
                              const float4* __restrict__ xi, int n4i,
                              float* __restrict__ accU, float* __restrict__ accI) {
  __shared__ float redU[4], redI[4];
  int tid = threadIdx.x;
  int gid = blockIdx.x * blockDim.x + tid;
  int stride = gridDim.x * blockDim.x;
  float su = 0.f, si = 0.f;
  for (int i = gid; i < n4u; i += stride) {
    float4 v = xu[i];
    su += v.x * v.x + v.y * v.y + v.z * v.z + v.w * v.w;
  }
  for (int i = gid; i < n4i; i += stride) {
    float4 v = xi[i];
    si += v.x * v.x + v.y * v.y + v.z * v.z + v.w * v.w;
  }
  for (int o = 32; o > 0; o >>= 1) {
    su += __shfl_down(su, o);
    si += __shfl_down(si, o);
  }
  if ((tid & 63) == 0) { redU[tid >> 6] = su; redI[tid >> 6] = si; }
  __syncthreads();
  if (tid == 0) {
    atomicAdd(accU, redU[0] + redU[1] + redU[2] + redU[3]);
    atomicAdd(accI, redI[0] + redI[1] + redI[2] + redI[3]);
  }
}

__global__ void final_kernel(const float* __restrict__ accs, int Bsz, int NA, int NiRows,
                             float* __restrict__ out) {
  float rec = accs[NA] / (float)Bsz;
  float aux = 0.f;
  for (int i = 0; i < NA; ++i) aux += accs[i] / (float)Bsz;
  aux /= (float)NA;
  float embl = (sqrtf(accs[NA + 1]) + sqrtf(accs[NA + 2])) / (float)NiRows;
  out[0] = rec + 0.5f * aux + 1e-4f * embl;
}

extern "C" void kernel_launch(void* const* d_in, const int* in_sizes, int n_in,
                              void* d_out, int out_size, void* d_ws, size_t ws_size,
                              hipStream_t stream) {
  const float* user_emb = (const float*)d_in[0];
  const float* item_emb = (const float*)d_in[1];
  const int* batch = (const int*)d_in[2];
  const int* aux_edges = (const int*)d_in[3];
  const int* tgt_edges = (const int*)d_in[4];

  const int NuRows = in_sizes[0] / D;          // 100001
  const int NiRows = in_sizes[1] / D;          // 50001
  const int Bsz = in_sizes[2] / 9;             // 4096
  const int E = in_sizes[4] / 2;               // 1,000,000
  const int NA = in_sizes[3] / (2 * E);        // 2
  const int N = NuRows + NiRows;               // 150002 < 2^18 (pack invariant)
  const int E2 = 2 * E;
  const size_t rowH = (size_t)N * ROWU;        // uints per bf16 node buffer
  const int BPS_H = (E + TILE_H - 1) / TILE_H;
  const int BPS_B = (E + TILE_BIN - 1) / TILE_BIN;
  const int NBKe = (N + (1 << BSHIFT) - 1) >> BSHIFT;

  // ---- workspace layout ----
  u32* EMBu = (u32*)d_ws;                 // rowH
  u32* AAll = EMBu + rowH;                // 2*rowH
  u32* BaAll = AAll + 2 * rowH;           // 2*rowH
  u32* BcAll = BaAll + 2 * rowH;          // 2*rowH
  int* deg3 = (int*)(BcAll + 2 * rowH);           // 3*N
  float* dinv5 = (float*)(deg3 + 3 * (size_t)N);  // 5*N
  int* rp3 = (int*)(dinv5 + 5 * (size_t)N);       // 3*(N+1)
  int* bcur = rp3 + 3 * (size_t)(N + 1);          // 3*NBK
  int* col_all = bcur + 3 * (size_t)NBK;          // 3*2E
  float* cps = (float*)(col_all + 3 * (size_t)E2);
  float* cns = cps + (size_t)NA * Bsz;
  float* aps = cns + (size_t)NA * Bsz;
  float* ans_ = aps + (size_t)NA * Bsz;
  float* dps = ans_ + (size_t)NA * Bsz;
  float* dns = dps + (size_t)NA * Bsz;
  float* accs = dns + (size_t)NA * Bsz;           // [NA aux][rec][sumsq_u][sumsq_i]
  // binned (3*2E ints = 24 MB) aliased onto AAll+BaAll (38.4 MB); dead before gathers
  int* binned = (int*)AAll;

  const int TB = 256;
  const int gN = (N + TB - 1) / TB;
  const int gN4 = (N * 4 + TB - 1) / TB;
  const int gB = (Bsz + TB - 1) / TB;
  const int gB32 = (Bsz * 32 + TB - 1) / TB;
  const long nu2 = (long)NuRows * ROWU;
  const long ni2 = (long)NiRows * ROWU;
  const int gCvt = (int)((nu2 + ni2 + TB - 1) / TB);

  cvt_emb_kernel<<<gCvt, TB, 0, stream>>>((const float2*)user_emb, nu2,
                                          (const float2*)item_emb, ni2, EMBu);

  // ---- binned CSR build ----
  hipMemsetAsync(bcur, 0, 3 * (size_t)NBK * sizeof(int), stream);
  hist_kernel<<<3 * BPS_H, TB, 0, stream>>>((const int2*)tgt_edges, (const int2*)aux_edges,
                                            E, NuRows, BPS_H, bcur);
  bscan_kernel<<<3, 64, 0, stream>>>(bcur);
  bin_kernel<<<3 * BPS_B, TB, 0, stream>>>((const int2*)tgt_edges, (const int2*)aux_edges,
                                           E, NuRows, BPS_B, bcur, binned);
  bucket_csr_kernel<<<3 * NBKe, TB, 0, stream>>>(binned, bcur, E2, N, NBKe,
                                                 deg3, rp3, col_all);
  dinv_all_kernel<<<gN, TB, 0, stream>>>(deg3, dinv5, N);

  hipMemsetAsync(accs, 0, (size_t)(NA + 3) * sizeof(float), stream);

  dim3 gridG(gN4, NA), gridB(gB, NA), gridS(gB32, NA);

  gather_fused_kernel<<<gridG, TB, 0, stream>>>(rp3, col_all, dinv5, (const uint4*)EMBu,
                                                (uint4*)BaAll, (uint4*)BcAll, N, E2);
  gather_avg_kernel<<<gridG, TB, 0, stream>>>(rp3, col_all, dinv5, (const uint4*)EMBu,
                                              (const uint4*)BaAll, (uint4*)AAll, N, E2);
  score_aux_kernel<<<gridB, TB, 0, stream>>>(AAll, batch, Bsz, NuRows, N, aps, ans_, accs);
  ce_sparse_kernel<<<gridS, TB, 0, stream>>>(rp3, col_all, dinv5, EMBu, BcAll,
                                             batch, Bsz, NuRows, N, E2, cps, cns);
  de_gather_kernel<<<gridG, TB, 0, stream>>>(rp3, col_all, dinv5, (const uint4*)AAll,
                                             (uint4*)BaAll, N, E2);
  de_sparse_kernel<<<gridS, TB, 0, stream>>>(rp3, col_all, dinv5, AAll, BaAll,
                                             batch, Bsz, NuRows, N, E2, dps, dns);

  sumsq2_kernel<<<104, TB, 0, stream>>>((const float4*)user_emb,
                                        (int)((size_t)NuRows * D / 4),
                                        (const float4*)item_emb,
                                        (int)((size_t)NiRows * D / 4),
                                        accs + NA + 1, accs + NA + 2);
  recloss_kernel<<<gB, TB, 0, stream>>>(cps, cns, aps, ans_, dps, dns, Bsz, NA, accs + NA);
  final_kernel<<<1, 1, 0, stream>>>(accs, Bsz, NA, NiRows, (float*)d_out);
}

// Round 8
// 683.315 us; speedup vs baseline: 19.8682x; 1.0689x over previous
//
#include <hip/hip_runtime.h>
#include <math.h>

#define D 32
#define ROWU 16           // uints per bf16 row (32 bf16 = 64 B)
#define NBK 1024          // bucket slots per segment
#define BSHIFT 8          // bucket = node >> 8  (256 nodes per bucket)
#define TILE_H 16384      // undirected edges per hist block
#define TILE_BIN 2048     // undirected edges per bin block (8 per thread)
#define BCAP 7680         // LDS packed-entry capacity in bucket_csr

typedef unsigned int u32;
typedef unsigned short u16;

__device__ __forceinline__ float logsigf(float x) {
  return fminf(x, 0.f) - log1pf(expf(-fabsf(x)));
}

// ---- bf16 helpers (storage bf16, math fp32) ----
__device__ __forceinline__ float lo16(u32 u) { return __uint_as_float(u << 16); }
__device__ __forceinline__ float hi16(u32 u) { return __uint_as_float(u & 0xFFFF0000u); }
__device__ __forceinline__ u32 pk2(float a, float b) {  // RNE pack
  u32 ua = __float_as_uint(a), ub = __float_as_uint(b);
  u32 ra = (ua + 0x7FFFu + ((ua >> 16) & 1u)) >> 16;
  u32 rb = (ub + 0x7FFFu + ((ub >> 16) & 1u)) >> 16;
  return (ra & 0xFFFFu) | (rb << 16);
}
__device__ __forceinline__ float bfat(const u16* __restrict__ p, size_t off) {
  return __uint_as_float(((u32)p[off]) << 16);
}
__device__ __forceinline__ void accum8(float* a, float w, uint4 x) {
  a[0] += w * lo16(x.x); a[1] += w * hi16(x.x);
  a[2] += w * lo16(x.y); a[3] += w * hi16(x.y);
  a[4] += w * lo16(x.z); a[5] += w * hi16(x.z);
  a[6] += w * lo16(x.w); a[7] += w * hi16(x.w);
}
__device__ __forceinline__ uint4 pack8(const float* a, float w) {
  return make_uint4(pk2(w * a[0], w * a[1]), pk2(w * a[2], w * a[3]),
                    pk2(w * a[4], w * a[5]), pk2(w * a[6], w * a[7]));
}

// ================= CSR build via bucket binning =================
// seg 0 = tgt, 1 = aux0, 2 = aux1. Directed entry packed: (dst_local<<18)|src.

__global__ void hist_kernel(const int2* __restrict__ tgt, const int2* __restrict__ aux,
                            int E, int Nu, int BPS, int* __restrict__ bcur) {
  __shared__ int lh[NBK];
  int seg = blockIdx.x / BPS;
  int blk = blockIdx.x - seg * BPS;
  const int2* edges = (seg == 0) ? tgt : aux + (size_t)(seg - 1) * E;
  for (int b = threadIdx.x; b < NBK; b += 256) lh[b] = 0;
  __syncthreads();
  int e0 = blk * TILE_H;
  for (int k = threadIdx.x; k < TILE_H; k += 256) {
    int e = e0 + k;
    if (e < E) {
      int2 ed = edges[e];
      atomicAdd(&lh[ed.x >> BSHIFT], 1);
      atomicAdd(&lh[(ed.y + Nu) >> BSHIFT], 1);
    }
  }
  __syncthreads();
  for (int b = threadIdx.x; b < NBK; b += 256)
    if (lh[b]) atomicAdd(&bcur[seg * NBK + b], lh[b]);
}

__global__ void bscan_kernel(int* __restrict__ bcur) {
  int* b = bcur + blockIdx.x * NBK;
  int lane = threadIdx.x;
  int carry = 0;
  for (int base = 0; base < NBK; base += 64) {
    int i = base + lane;
    int v = b[i];
    int s = v;
    #pragma unroll
    for (int o = 1; o < 64; o <<= 1) {
      int t = __shfl_up(s, o);
      if (lane >= o) s += t;
    }
    b[i] = carry + s - v;
    carry += __shfl(s, 63);
  }
}

__global__ void bin_kernel(const int2* __restrict__ tgt, const int2* __restrict__ aux,
                           int E, int Nu, int BPS, int* __restrict__ bcur,
                           int* __restrict__ binned) {
  __shared__ int stage[2 * TILE_BIN];
  __shared__ int lh[NBK];
  __shared__ int loff[NBK];
  __shared__ int gb[NBK];
  __shared__ int wred[4];
  __shared__ int stot;
  int seg = blockIdx.x / BPS;
  int blk = blockIdx.x - seg * BPS;
  const int2* edges = (seg == 0) ? tgt : aux + (size_t)(seg - 1) * E;
  int* out = binned + (size_t)seg * 2 * E;
  int tid = threadIdx.x;
  for (int b = tid; b < NBK; b += 256) lh[b] = 0;
  __syncthreads();
  int e0 = blk * TILE_BIN;
  int pkv[16];
  int pb[16];
  int pr[16];
  #pragma unroll
  for (int it = 0; it < 8; ++it) {
    int e = e0 + tid + it * 256;
    bool ok = e < E;
    int2 ed = ok ? edges[e] : make_int2(0, -Nu);
    int u = ed.x, v = ed.y + Nu;
    int b1 = u >> BSHIFT, b2 = v >> BSHIFT;
    pkv[2 * it] = ((u & 255) << 18) | v;
    pb[2 * it] = b1;
    pr[2 * it] = ok ? atomicAdd(&lh[b1], 1) : 0;
    pkv[2 * it + 1] = ((v & 255) << 18) | u;
    pb[2 * it + 1] = b2;
    pr[2 * it + 1] = ok ? atomicAdd(&lh[b2], 1) : 0;
  }
  __syncthreads();
  int lane = tid & 63, wid = tid >> 6;
  int b4 = tid * 4;
  int v0 = lh[b4], v1 = lh[b4 + 1], v2 = lh[b4 + 2], v3 = lh[b4 + 3];
  int tsum = v0 + v1 + v2 + v3;
  int incl = tsum;
  #pragma unroll
  for (int o = 1; o < 64; o <<= 1) {
    int t = __shfl_up(incl, o);
    if (lane >= o) incl += t;
  }
  if (lane == 63) wred[wid] = incl;
  __syncthreads();
  int wbase = 0;
  for (int w = 0; w < wid; ++w) wbase += wred[w];
  int excl = wbase + incl - tsum;
  loff[b4] = excl;
  loff[b4 + 1] = excl + v0;
  loff[b4 + 2] = excl + v0 + v1;
  loff[b4 + 3] = excl + v0 + v1 + v2;
  if (tid == 255) stot = excl + tsum;
  #pragma unroll
  for (int j = 0; j < 4; ++j) {
    int b = b4 + j;
    int c = lh[b];
    gb[b] = c ? atomicAdd(&bcur[seg * NBK + b], c) : 0;
  }
  __syncthreads();
  #pragma unroll
  for (int it = 0; it < 16; ++it) {
    int e = e0 + tid + (it >> 1) * 256;
    if (e < E) stage[loff[pb[it]] + pr[it]] = pkv[it];
  }
  __syncthreads();
  int tot = stot;
  for (int k = tid; k < tot; k += 256) {
    int lo = 0, hi = NBK;
    while (lo < hi) {
      int mid = (lo + hi) >> 1;
      if (loff[mid] <= k) lo = mid + 1; else hi = mid;
    }
    int b = lo - 1;
    out[gb[b] + (k - loff[b])] = stage[k];
  }
}

__global__ void bucket_csr_kernel(const int* __restrict__ binned,
                                  const int* __restrict__ bend, int E2, int N, int NBKe,
                                  int* __restrict__ deg3, int* __restrict__ rp3,
                                  int* __restrict__ col_all) {
  __shared__ int ent[BCAP];
  __shared__ int cnt[256];
  __shared__ int off[256];
  __shared__ int wred[4];
  int seg = blockIdx.x / NBKe;
  int bkt = blockIdx.x - seg * NBKe;
  int node0 = bkt << BSHIFT;
  const int* bc = bend + seg * NBK;
  int start = (bkt == 0) ? 0 : bc[bkt - 1];
  int end = bc[bkt];
  int cntE = end - start;
  const int* src = binned + (size_t)seg * E2 + start;
  bool inLds = (cntE <= BCAP);
  if (inLds)
    for (int k = threadIdx.x; k < cntE; k += 256) ent[k] = src[k];
  cnt[threadIdx.x] = 0;
  __syncthreads();
  for (int k = threadIdx.x; k < cntE; k += 256) {
    int en = inLds ? ent[k] : src[k];
    atomicAdd(&cnt[en >> 18], 1);
  }
  __syncthreads();
  int lane = threadIdx.x & 63, wid = threadIdx.x >> 6;
  int v = cnt[threadIdx.x];
  int incl = v;
  #pragma unroll
  for (int o = 1; o < 64; o <<= 1) {
    int t = __shfl_up(incl, o);
    if (lane >= o) incl += t;
  }
  if (lane == 63) wred[wid] = incl;
  __syncthreads();
  int wbase = 0;
  for (int w = 0; w < wid; ++w) wbase += wred[w];
  off[threadIdx.x] = wbase + incl - v;
  int node = node0 + (int)threadIdx.x;
  if (node < N) {
    deg3[(size_t)seg * N + node] = v;
    rp3[(size_t)seg * (N + 1) + node] = start + wbase + incl - v;
  }
  if (bkt == 0 && threadIdx.x == 0) rp3[(size_t)seg * (N + 1) + N] = E2;
  __syncthreads();
  cnt[threadIdx.x] = 0;
  __syncthreads();
  int* col = col_all + (size_t)seg * E2 + start;
  for (int k = threadIdx.x; k < cntE; k += 256) {
    int en = inLds ? ent[k] : src[k];
    int lb = en >> 18;
    int pos = atomicAdd(&cnt[lb], 1);
    col[off[lb] + pos] = en & 0x3FFFF;
  }
}

__global__ void dinv_all_kernel(const int* __restrict__ deg3, float* __restrict__ dinv5,
                                int N) {
  int n = blockIdx.x * blockDim.x + threadIdx.x;
  if (n >= N) return;
  int dt = deg3[n], d0 = deg3[N + n], d1 = deg3[2 * N + n];
  dinv5[n]         = dt ? rsqrtf((float)dt) : 0.f;
  dinv5[N + n]     = d0 ? rsqrtf((float)d0) : 0.f;
  dinv5[2 * N + n] = d1 ? rsqrtf((float)d1) : 0.f;
  int c0 = dt + d0, c1 = dt + d1;
  dinv5[3 * N + n] = c0 ? rsqrtf((float)c0) : 0.f;
  dinv5[4 * N + n] = c1 ? rsqrtf((float)c1) : 0.f;
}

__global__ void cvt_emb_kernel(const float2* __restrict__ ue, long nu2,
                               const float2* __restrict__ ie, long ni2,
                               u32* __restrict__ emb) {
  long i = (long)blockIdx.x * blockDim.x + threadIdx.x;
  if (i >= nu2 + ni2) return;
  float2 v = (i < nu2) ? ue[i] : ie[i - nu2];
  emb[i] = pk2(v.x, v.y);
}

// ================= dense propagation (bf16 rows, 4 lanes/node) =================

// layer-1 for BOTH idx: Ba0/Ba1 = aux L1, Bc0/Bc1 = comb L1. tgt rows read ONCE.
__global__ void gather_fused_all_kernel(const int* __restrict__ rp3,
                                        const int* __restrict__ col_all,
                                        const float* __restrict__ dinv5,
                                        const uint4* __restrict__ emb,
                                        uint4* __restrict__ BaAll, uint4* __restrict__ BcAll,
                                        int N, int E2) {
  const int* rpA0 = rp3 + (size_t)1 * (N + 1);
  const int* rpA1 = rp3 + (size_t)2 * (N + 1);
  const int* colA0 = col_all + (size_t)1 * E2;
  const int* colA1 = col_all + (size_t)2 * E2;
  const float* dvA0 = dinv5 + (size_t)1 * N;
  const float* dvA1 = dinv5 + (size_t)2 * N;
  const float* dvC0 = dinv5 + (size_t)3 * N;
  const float* dvC1 = dinv5 + (size_t)4 * N;
  int t = blockIdx.x * blockDim.x + threadIdx.x;
  int n = t >> 2;
  if (n >= N) return;
  int lane = t & 3;
  float aA0[8] = {0, 0, 0, 0, 0, 0, 0, 0};
  float aA1[8] = {0, 0, 0, 0, 0, 0, 0, 0};
  float aC0[8] = {0, 0, 0, 0, 0, 0, 0, 0};
  float aC1[8] = {0, 0, 0, 0, 0, 0, 0, 0};
  // aux0 edges -> Ba0, Bc0 (2-edge unroll)
  int s = rpA0[n], e = rpA0[n + 1];
  int j = s;
  for (; j + 1 < e; j += 2) {
    int c0 = colA0[j], c1 = colA0[j + 1];
    float wa0 = dvA0[c0], wc0 = dvC0[c0];
    float wa1 = dvA0[c1], wc1 = dvC0[c1];
    uint4 x0 = emb[(size_t)c0 * 4 + lane];
    uint4 x1 = emb[(size_t)c1 * 4 + lane];
    accum8(aA0, wa0, x0); accum8(aC0, wc0, x0);
    accum8(aA0, wa1, x1); accum8(aC0, wc1, x1);
  }
  if (j < e) {
    int c = colA0[j];
    float wa = dvA0[c], wc = dvC0[c];
    uint4 x = emb[(size_t)c * 4 + lane];
    accum8(aA0, wa, x); accum8(aC0, wc, x);
  }
  // aux1 edges -> Ba1, Bc1
  s = rpA1[n]; e = rpA1[n + 1];
  j = s;
  for (; j + 1 < e; j += 2) {
    int c0 = colA1[j], c1 = colA1[j + 1];
    float wa0 = dvA1[c0], wc0 = dvC1[c0];
    float wa1 = dvA1[c1], wc1 = dvC1[c1];
    uint4 x0 = emb[(size_t)c0 * 4 + lane];
    uint4 x1 = emb[(size_t)c1 * 4 + lane];
    accum8(aA1, wa0, x0); accum8(aC1, wc0, x0);
    accum8(aA1, wa1, x1); accum8(aC1, wc1, x1);
  }
  if (j < e) {
    int c = colA1[j];
    float wa = dvA1[c], wc = dvC1[c];
    uint4 x = emb[(size_t)c * 4 + lane];
    accum8(aA1, wa, x); accum8(aC1, wc, x);
  }
  // tgt edges -> Bc0, Bc1 (rows read once for both idx)
  s = rp3[n]; e = rp3[n + 1];
  j = s;
  for (; j + 1 < e; j += 2) {
    int c0 = col_all[j], c1 = col_all[j + 1];
    float w00 = dvC0[c0], w10 = dvC1[c0];
    float w01 = dvC0[c1], w11 = dvC1[c1];
    uint4 x0 = emb[(size_t)c0 * 4 + lane];
    uint4 x1 = emb[(size_t)c1 * 4 + lane];
    accum8(aC0, w00, x0); accum8(aC1, w10, x0);
    accum8(aC0, w01, x1); accum8(aC1, w11, x1);
  }
  if (j < e) {
    int c = col_all[j];
    float w0 = dvC0[c], w1 = dvC1[c];
    uint4 x = emb[(size_t)c * 4 + lane];
    accum8(aC0, w0, x); accum8(aC1, w1, x);
  }
  size_t o = (size_t)n * 4 + lane;
  size_t rowN4 = (size_t)N * 4;
  BaAll[o] = pack8(aA0, dvA0[n]);
  BaAll[rowN4 + o] = pack8(aA1, dvA1[n]);
  BcAll[o] = pack8(aC0, dvC0[n]);
  BcAll[rowN4 + o] = pack8(aC1, dvC1[n]);
}

// aux L2 + avg: A(idx) = (EMB + Ba + dinv*gather(Ba))/3
__global__ void gather_avg_kernel(const int* __restrict__ rp3, const int* __restrict__ col_all,
                                  const float* __restrict__ dinv5,
                                  const uint4* __restrict__ emb,
                                  const uint4* __restrict__ BaAll, uint4* __restrict__ AAll,
                                  int N, int E2) {
  int idx = blockIdx.y;
  const int* rp = rp3 + (size_t)(1 + idx) * (N + 1);
  const int* col = col_all + (size_t)(1 + idx) * E2;
  const float* dv = dinv5 + (size_t)(1 + idx) * N;
  const uint4* cur = BaAll + (size_t)idx * N * 4;
  uint4* outA = AAll + (size_t)idx * N * 4;
  int t = blockIdx.x * blockDim.x + threadIdx.x;
  int n = t >> 2;
  if (n >= N) return;
  int lane = t & 3;
  float acc[8] = {0, 0, 0, 0, 0, 0, 0, 0};
  int s = rp[n], e = rp[n + 1];
  int j = s;
  for (; j + 1 < e; j += 2) {
    int c0 = col[j], c1 = col[j + 1];
    float w0 = dv[c0], w1 = dv[c1];
    uint4 x0 = cur[(size_t)c0 * 4 + lane];
    uint4 x1 = cur[(size_t)c1 * 4 + lane];
    accum8(acc, w0, x0);
    accum8(acc, w1, x1);
  }
  if (j < e) {
    int c = col[j];
    float w = dv[c];
    uint4 x = cur[(size_t)c * 4 + lane];
    accum8(acc, w, x);
  }
  float wn = dv[n];
  uint4 e4 = emb[(size_t)n * 4 + lane];
  uint4 b4 = cur[(size_t)n * 4 + lane];
  float r[8];
  r[0] = (lo16(e4.x) + lo16(b4.x) + wn * acc[0]) * (1.f / 3.f);
  r[1] = (hi16(e4.x) + hi16(b4.x) + wn * acc[1]) * (1.f / 3.f);
  r[2] = (lo16(e4.y) + lo16(b4.y) + wn * acc[2]) * (1.f / 3.f);
  r[3] = (hi16(e4.y) + hi16(b4.y) + wn * acc[3]) * (1.f / 3.f);
  r[4] = (lo16(e4.z) + lo16(b4.z) + wn * acc[4]) * (1.f / 3.f);
  r[5] = (hi16(e4.z) + hi16(b4.z) + wn * acc[5]) * (1.f / 3.f);
  r[6] = (lo16(e4.w) + lo16(b4.w) + wn * acc[6]) * (1.f / 3.f);
  r[7] = (hi16(e4.w) + hi16(b4.w) + wn * acc[7]) * (1.f / 3.f);
  outA[(size_t)n * 4 + lane] = pack8(r, 1.f);
}

// de layer-1: Ba(idx) = dinv_tgt-gather of A(idx) over tgt graph
__global__ void de_gather_kernel(const int* __restrict__ rp3, const int* __restrict__ col_all,
                                 const float* __restrict__ dinv5,
                                 const uint4* __restrict__ AAll, uint4* __restrict__ BaAll,
                                 int N, int E2) {
  int idx = blockIdx.y;
  const uint4* cur = AAll + (size_t)idx * N * 4;
  uint4* out = BaAll + (size_t)idx * N * 4;
  int t = blockIdx.x * blockDim.x + threadIdx.x;
  int n = t >> 2;
  if (n >= N) return;
  int lane = t & 3;
  float acc[8] = {0, 0, 0, 0, 0, 0, 0, 0};
  int s = rp3[n], e = rp3[n + 1];
  int j = s;
  for (; j + 1 < e; j += 2) {
    int c0 = col_all[j], c1 = col_all[j + 1];
    float w0 = dinv5[c0], w1 = dinv5[c1];
    uint4 x0 = cur[(size_t)c0 * 4 + lane];
    uint4 x1 = cur[(size_t)c1 * 4 + lane];
    accum8(acc, w0, x0);
    accum8(acc, w1, x1);
  }
  if (j < e) {
    int c = col_all[j];
    float w = dinv5[c];
    uint4 x = cur[(size_t)c * 4 + lane];
    accum8(acc, w, x);
  }
  out[(size_t)n * 4 + lane] = pack8(acc, dinv5[n]);
}

// ================= sparse L2 + score (bf16 rows) =================

__device__ __forceinline__ float fdim2(const int* __restrict__ rpA, const int* __restrict__ colA,
                                       const int* __restrict__ rpT, const int* __restrict__ colT,
                                       const float* __restrict__ dv,
                                       const u16* __restrict__ base, const u16* __restrict__ L1,
                                       int r, int d) {
  float acc = 0.f;
  for (int j = rpA[r]; j < rpA[r + 1]; ++j) {
    int c = colA[j];
    acc += dv[c] * bfat(L1, (size_t)c * D + d);
  }
  if (colT != nullptr) {
    for (int j = rpT[r]; j < rpT[r + 1]; ++j) {
      int c = colT[j];
      acc += dv[c] * bfat(L1, (size_t)c * D + d);
    }
  }
  return (bfat(base, (size_t)r * D + d) + bfat(L1, (size_t)r * D + d) + dv[r] * acc) * (1.f / 3.f);
}

__global__ void ce_sparse_kernel(const int* __restrict__ rp3, const int* __restrict__ col_all,
                                 const float* __restrict__ dinv5,
                                 const u32* __restrict__ EMBu, const u32* __restrict__ BcAll,
                                 const int* __restrict__ batch, int Bsz, int Nu, int N, int E2,
                                 float* __restrict__ cps, float* __restrict__ cns) {
  int idx = blockIdx.y;
  const int* rpA = rp3 + (size_t)(1 + idx) * (N + 1);
  const int* colA = col_all + (size_t)(1 + idx) * E2;
  const float* dv = dinv5 + (size_t)(3 + idx) * N;
  const u16* base = (const u16*)EMBu;
  const u16* L1 = (const u16*)(BcAll + (size_t)idx * N * ROWU);
  float* outp = cps + (size_t)idx * Bsz;
  float* outn = cns + (size_t)idx * Bsz;
  int t = blockIdx.x * blockDim.x + threadIdx.x;
  int b = t >> 5, d = t & 31;
  if (b >= Bsz) return;
  int u = batch[b * 9 + 0];
  int p = batch[b * 9 + 1] + Nu;
  int n = batch[b * 9 + 2] + Nu;
  float uv = fdim2(rpA, colA, rp3, col_all, dv, base, L1, u, d);
  float pv = fdim2(rpA, colA, rp3, col_all, dv, base, L1, p, d);
  float nv = fdim2(rpA, colA, rp3, col_all, dv, base, L1, n, d);
  float sp = uv * pv, sn = uv * nv;
  #pragma unroll
  for (int o = 16; o > 0; o >>= 1) {
    sp += __shfl_down(sp, o, 32);
    sn += __shfl_down(sn, o, 32);
  }
  if (d == 0) {
    outp[b] = fmaxf(sp, 0.f);
    outn[b] = fmaxf(sn, 0.f);
  }
}

__global__ void de_sparse_kernel(const int* __restrict__ rp3, const int* __restrict__ col_all,
                                 const float* __restrict__ dinv5,
                                 const u32* __restrict__ AAll, const u32* __restrict__ BaAll,
                                 const int* __restrict__ batch, int Bsz, int Nu, int N, int E2,
                                 float* __restrict__ dps, float* __restrict__ dns) {
  int idx = blockIdx.y;
  const u16* base = (const u16*)(AAll + (size_t)idx * N * ROWU);
  const u16* L1 = (const u16*)(BaAll + (size_t)idx * N * ROWU);
  float* outp = dps + (size_t)idx * Bsz;
  float* outn = dns + (size_t)idx * Bsz;
  int t = blockIdx.x * blockDim.x + threadIdx.x;
  int b = t >> 5, d = t & 31;
  if (b >= Bsz) return;
  int u = batch[b * 9 + 0];
  int p = batch[b * 9 + 1] + Nu;
  int n = batch[b * 9 + 2] + Nu;
  float uv = fdim2(rp3, col_all, nullptr, nullptr, dinv5, base, L1, u, d);
  float pv = fdim2(rp3, col_all, nullptr, nullptr, dinv5, base, L1, p, d);
  float nv = fdim2(rp3, col_all, nullptr, nullptr, dinv5, base, L1, n, d);
  float sp = uv * pv, sn = uv * nv;
  #pragma unroll
  for (int o = 16; o > 0; o >>= 1) {
    sp += __shfl_down(sp, o, 32);
    sn += __shfl_down(sn, o, 32);
  }
  if (d == 0) {
    outp[b] = fmaxf(sp, 0.f);
    outn[b] = fmaxf(sn, 0.f);
  }
}

// ================= batch scores / losses on materialized A (bf16) =================

__device__ __forceinline__ float dotrow(const u32* __restrict__ a, const u32* __restrict__ b) {
  float s = 0.f;
  #pragma unroll
  for (int k = 0; k < ROWU; ++k) {
    u32 x = a[k], y = b[k];
    s += lo16(x) * lo16(y) + hi16(x) * hi16(y);
  }
  return s;
}

__global__ void score_aux_kernel(const u32* __restrict__ AAll, const int* __restrict__ batch,
                                 int Bsz, int Nu, int N, float* __restrict__ aps,
                                 float* __restrict__ ans_, float* __restrict__ accs) {
  int idx = blockIdx.y;
  const u32* A = AAll + (size_t)idx * N * ROWU;
  float* outp = aps + (size_t)idx * Bsz;
  float* outn = ans_ + (size_t)idx * Bsz;
  int b = blockIdx.x * blockDim.x + threadIdx.x;
  float l = 0.f;
  if (b < Bsz) {
    int u = batch[b * 9 + 0];
    int p = batch[b * 9 + 1] + Nu;
    int n = batch[b * 9 + 2] + Nu;
    const u32* ur = A + (size_t)u * ROWU;
    outp[b] = fmaxf(dotrow(ur, A + (size_t)p * ROWU), 0.f);
    outn[b] = fmaxf(dotrow(ur, A + (size_t)n * ROWU), 0.f);
    const int* r = batch + b * 9 + 3 * (1 + idx);
    const u32* aur = A + (size_t)r[0] * ROWU;
    float ps = dotrow(aur, A + (size_t)(r[1] + Nu) * ROWU);
    float ns = dotrow(aur, A + (size_t)(r[2] + Nu) * ROWU);
    l = -logsigf(ps - ns);
  }
  for (int o = 32; o > 0; o >>= 1) l += __shfl_down(l, o);
  if ((threadIdx.x & 63) == 0) atomicAdd(&accs[idx], l);
}

__global__ void recloss_kernel(const float* __restrict__ cps, const float* __restrict__ cns,
                               const float* __restrict__ aps, const float* __restrict__ ans_,
                               const float* __restrict__ dps, const float* __restrict__ dns,
                               int Bsz, int NA, float* __restrict__ acc) {
  int b = blockIdx.x * blockDim.x + threadIdx.x;
  float l = 0.f;
  if (b < Bsz) {
    float dp = 0.f, dn = 0.f, cap = 0.f, can = 0.f;
    for (int i = 0; i < NA; ++i) {
      dp += dps[i * Bsz + b];
      dn += dns[i * Bsz + b];
      cap += cps[i * Bsz + b] * aps[i * Bsz + b];
      can += cns[i * Bsz + b] * ans_[i * Bsz + b];
    }
    l = -logsigf(dp * cap - dn * can);
  }
  for (int o = 32; o > 0; o >>= 1) l += __shfl_down(l, o);
  if ((threadIdx.x & 63) == 0) atomicAdd(acc, l);
}

__global__ void sumsq2_kernel(const float4* __restrict__ xu, int n4u,
                              const float4* __restrict__ xi, int n4i,
                              float* __restrict__ accU, float* __restrict__ accI) {
  __shared__ float redU[4], redI[4];
  int tid = threadIdx.x;
  int gid = blockIdx.x * blockDim.x + tid;
  int stride = gridDim.x * blockDim.x;
  float su = 0.f, si = 0.f;
  for (int i = gid; i < n4u; i += stride) {
    float4 v = xu[i];
    su += v.x * v.x + v.y * v.y + v.z * v.z + v.w * v.w;
  }
  for (int i = gid; i < n4i; i += stride) {
    float4 v = xi[i];
    si += v.x * v.x + v.y * v.y + v.z * v.z + v.w * v.w;
  }
  for (int o = 32; o > 0; o >>= 1) {
    su += __shfl_down(su, o);
    si += __shfl_down(si, o);
  }
  if ((tid & 63) == 0) { redU[tid >> 6] = su; redI[tid >> 6] = si; }
  __syncthreads();
  if (tid == 0) {
    atomicAdd(accU, redU[0] + redU[1] + redU[2] + redU[3]);
    atomicAdd(accI, redI[0] + redI[1] + redI[2] + redI[3]);
  }
}

__global__ void final_kernel(const float* __restrict__ accs, int Bsz, int NA, int NiRows,
                             float* __restrict__ out) {
  float rec = accs[NA] / (float)Bsz;
  float aux = 0.f;
  for (int i = 0; i < NA; ++i) aux += accs[i] / (float)Bsz;
  aux /= (float)NA;
  float embl = (sqrtf(accs[NA + 1]) + sqrtf(accs[NA + 2])) / (float)NiRows;
  out[0] = rec + 0.5f * aux + 1e-4f * embl;
}

extern "C" void kernel_launch(void* const* d_in, const int* in_sizes, int n_in,
                              void* d_out, int out_size, void* d_ws, size_t ws_size,
                              hipStream_t stream) {
  const float* user_emb = (const float*)d_in[0];
  const float* item_emb = (const float*)d_in[1];
  const int* batch = (const int*)d_in[2];
  const int* aux_edges = (const int*)d_in[3];
  const int* tgt_edges = (const int*)d_in[4];

  const int NuRows = in_sizes[0] / D;          // 100001
  const int NiRows = in_sizes[1] / D;          // 50001
  const int Bsz = in_sizes[2] / 9;             // 4096
  const int E = in_sizes[4] / 2;               // 1,000,000
  const int NA = in_sizes[3] / (2 * E);        // 2
  const int N = NuRows + NiRows;               // 150002 < 2^18 (pack invariant)
  const int E2 = 2 * E;
  const size_t rowH = (size_t)N * ROWU;
  const int BPS_H = (E + TILE_H - 1) / TILE_H;
  const int BPS_B = (E + TILE_BIN - 1) / TILE_BIN;
  const int NBKe = (N + (1 << BSHIFT) - 1) >> BSHIFT;

  // ---- workspace layout ----
  u32* EMBu = (u32*)d_ws;                 // rowH
  u32* AAll = EMBu + rowH;                // 2*rowH
  u32* BaAll = AAll + 2 * rowH;           // 2*rowH
  u32* BcAll = BaAll + 2 * rowH;          // 2*rowH
  int* deg3 = (int*)(BcAll + 2 * rowH);           // 3*N
  float* dinv5 = (float*)(deg3 + 3 * (size_t)N);  // 5*N
  int* rp3 = (int*)(dinv5 + 5 * (size_t)N);       // 3*(N+1)
  int* bcur = rp3 + 3 * (size_t)(N + 1);          // 3*NBK
  int* col_all = bcur + 3 * (size_t)NBK;          // 3*2E
  float* cps = (float*)(col_all + 3 * (size_t)E2);
  float* cns = cps + (size_t)NA * Bsz;
  float* aps = cns + (size_t)NA * Bsz;
  float* ans_ = aps + (size_t)NA * Bsz;
  float* dps = ans_ + (size_t)NA * Bsz;
  float* dns = dps + (size_t)NA * Bsz;
  float* accs = dns + (size_t)NA * Bsz;           // [NA aux][rec][sumsq_u][sumsq_i]
  int* binned = (int*)AAll;  // 24 MB alias; dead before gathers

  const int TB = 256;
  const int gN = (N + TB - 1) / TB;
  const int gN4 = (N * 4 + TB - 1) / TB;
  const int gB = (Bsz + TB - 1) / TB;
  const int gB32 = (Bsz * 32 + TB - 1) / TB;
  const long nu2 = (long)NuRows * ROWU;
  const long ni2 = (long)NiRows * ROWU;
  const int gCvt = (int)((nu2 + ni2 + TB - 1) / TB);

  cvt_emb_kernel<<<gCvt, TB, 0, stream>>>((const float2*)user_emb, nu2,
                                          (const float2*)item_emb, ni2, EMBu);

  // ---- binned CSR build ----
  hipMemsetAsync(bcur, 0, 3 * (size_t)NBK * sizeof(int), stream);
  hist_kernel<<<3 * BPS_H, TB, 0, stream>>>((const int2*)tgt_edges, (const int2*)aux_edges,
                                            E, NuRows, BPS_H, bcur);
  bscan_kernel<<<3, 64, 0, stream>>>(bcur);
  bin_kernel<<<3 * BPS_B, TB, 0, stream>>>((const int2*)tgt_edges, (const int2*)aux_edges,
                                           E, NuRows, BPS_B, bcur, binned);
  bucket_csr_kernel<<<3 * NBKe, TB, 0, stream>>>(binned, bcur, E2, N, NBKe,
                                                 deg3, rp3, col_all);
  dinv_all_kernel<<<gN, TB, 0, stream>>>(deg3, dinv5, N);

  hipMemsetAsync(accs, 0, (size_t)(NA + 3) * sizeof(float), stream);

  dim3 gridG(gN4, NA), gridB(gB, NA), gridS(gB32, NA);

  gather_fused_all_kernel<<<gN4, TB, 0, stream>>>(rp3, col_all, dinv5, (const uint4*)EMBu,
                                                  (uint4*)BaAll, (uint4*)BcAll, N, E2);
  gather_avg_kernel<<<gridG, TB, 0, stream>>>(rp3, col_all, dinv5, (const uint4*)EMBu,
                                              (const uint4*)BaAll, (uint4*)AAll, N, E2);
  score_aux_kernel<<<gridB, TB, 0, stream>>>(AAll, batch, Bsz, NuRows, N, aps, ans_, accs);
  ce_sparse_kernel<<<gridS, TB, 0, stream>>>(rp3, col_all, dinv5, EMBu, BcAll,
                                             batch, Bsz, NuRows, N, E2, cps, cns);
  de_gather_kernel<<<gridG, TB, 0, stream>>>(rp3, col_all, dinv5, (const uint4*)AAll,
                                             (uint4*)BaAll, N, E2);
  de_sparse_kernel<<<gridS, TB, 0, stream>>>(rp3, col_all, dinv5, AAll, BaAll,
                                             batch, Bsz, NuRows, N, E2, dps, dns);

  sumsq2_kernel<<<104, TB, 0, stream>>>((const float4*)user_emb,
                                        (int)((size_t)NuRows * D / 4),
                                        (const float4*)item_emb,
                                        (int)((size_t)NiRows * D / 4),
                                        accs + NA + 1, accs + NA + 2);
  recloss_kernel<<<gB, TB, 0, stream>>>(cps, cns, aps, ans_, dps, dns, Bsz, NA, accs + NA);
  final_kernel<<<1, 1, 0, stream>>>(accs, Bsz, NA, NiRows, (float*)d_out);
}

// Round 9
// 651.115 us; speedup vs baseline: 20.8507x; 1.0495x over previous
//
#include <hip/hip_runtime.h>
#include <math.h>

#define D 32
#define ROWU 16           // uints per bf16 row (32 bf16 = 64 B)
#define NBK 1024          // bucket slots per segment
#define BSHIFT 8          // bucket = node >> 8  (256 nodes per bucket)
#define TILE_H 16384      // undirected edges per hist block
#define TILE_BIN 2048     // undirected edges per bin block (8 per thread)
#define BCAP 7680         // LDS packed-entry capacity in bucket_csr

typedef unsigned int u32;
typedef unsigned short u16;

__device__ __forceinline__ float logsigf(float x) {
  return fminf(x, 0.f) - log1pf(expf(-fabsf(x)));
}

// ---- bf16 helpers (storage bf16, math fp32) ----
__device__ __forceinline__ float lo16(u32 u) { return __uint_as_float(u << 16); }
__device__ __forceinline__ float hi16(u32 u) { return __uint_as_float(u & 0xFFFF0000u); }
__device__ __forceinline__ u32 pk2(float a, float b) {  // RNE pack
  u32 ua = __float_as_uint(a), ub = __float_as_uint(b);
  u32 ra = (ua + 0x7FFFu + ((ua >> 16) & 1u)) >> 16;
  u32 rb = (ub + 0x7FFFu + ((ub >> 16) & 1u)) >> 16;
  return (ra & 0xFFFFu) | (rb << 16);
}
__device__ __forceinline__ float bfat(const u16* __restrict__ p, size_t off) {
  return __uint_as_float(((u32)p[off]) << 16);
}
__device__ __forceinline__ void accum8(float* a, float w, uint4 x) {
  a[0] += w * lo16(x.x); a[1] += w * hi16(x.x);
  a[2] += w * lo16(x.y); a[3] += w * hi16(x.y);
  a[4] += w * lo16(x.z); a[5] += w * hi16(x.z);
  a[6] += w * lo16(x.w); a[7] += w * hi16(x.w);
}
__device__ __forceinline__ uint4 pack8(const float* a, float w) {
  return make_uint4(pk2(w * a[0], w * a[1]), pk2(w * a[2], w * a[3]),
                    pk2(w * a[4], w * a[5]), pk2(w * a[6], w * a[7]));
}

// ================= CSR build via bucket binning =================
// seg 0 = tgt, 1 = aux0, 2 = aux1. Directed entry packed: (dst_local<<18)|src.

__global__ void hist_kernel(const int2* __restrict__ tgt, const int2* __restrict__ aux,
                            int E, int Nu, int BPS, int* __restrict__ bcur) {
  __shared__ int lh[NBK];
  int seg = blockIdx.x / BPS;
  int blk = blockIdx.x - seg * BPS;
  const int2* edges = (seg == 0) ? tgt : aux + (size_t)(seg - 1) * E;
  for (int b = threadIdx.x; b < NBK; b += 256) lh[b] = 0;
  __syncthreads();
  int e0 = blk * TILE_H;
  for (int k = threadIdx.x; k < TILE_H; k += 256) {
    int e = e0 + k;
    if (e < E) {
      int2 ed = edges[e];
      atomicAdd(&lh[ed.x >> BSHIFT], 1);
      atomicAdd(&lh[(ed.y + Nu) >> BSHIFT], 1);
    }
  }
  __syncthreads();
  for (int b = threadIdx.x; b < NBK; b += 256)
    if (lh[b]) atomicAdd(&bcur[seg * NBK + b], lh[b]);
}

__global__ void bscan_kernel(int* __restrict__ bcur) {
  int* b = bcur + blockIdx.x * NBK;
  int lane = threadIdx.x;
  int carry = 0;
  for (int base = 0; base < NBK; base += 64) {
    int i = base + lane;
    int v = b[i];
    int s = v;
    #pragma unroll
    for (int o = 1; o < 64; o <<= 1) {
      int t = __shfl_up(s, o);
      if (lane >= o) s += t;
    }
    b[i] = carry + s - v;
    carry += __shfl(s, 63);
  }
}

__global__ void bin_kernel(const int2* __restrict__ tgt, const int2* __restrict__ aux,
                           int E, int Nu, int BPS, int* __restrict__ bcur,
                           int* __restrict__ binned) {
  __shared__ int stage[2 * TILE_BIN];
  __shared__ int lh[NBK];
  __shared__ int loff[NBK];
  __shared__ int gb[NBK];
  __shared__ int wred[4];
  __shared__ int stot;
  int seg = blockIdx.x / BPS;
  int blk = blockIdx.x - seg * BPS;
  const int2* edges = (seg == 0) ? tgt : aux + (size_t)(seg - 1) * E;
  int* out = binned + (size_t)seg * 2 * E;
  int tid = threadIdx.x;
  for (int b = tid; b < NBK; b += 256) lh[b] = 0;
  __syncthreads();
  int e0 = blk * TILE_BIN;
  int pkv[16];
  int pb[16];
  int pr[16];
  #pragma unroll
  for (int it = 0; it < 8; ++it) {
    int e = e0 + tid + it * 256;
    bool ok = e < E;
    int2 ed = ok ? edges[e] : make_int2(0, -Nu);
    int u = ed.x, v = ed.y + Nu;
    int b1 = u >> BSHIFT, b2 = v >> BSHIFT;
    pkv[2 * it] = ((u & 255) << 18) | v;
    pb[2 * it] = b1;
    pr[2 * it] = ok ? atomicAdd(&lh[b1], 1) : 0;
    pkv[2 * it + 1] = ((v & 255) << 18) | u;
    pb[2 * it + 1] = b2;
    pr[2 * it + 1] = ok ? atomicAdd(&lh[b2], 1) : 0;
  }
  __syncthreads();
  int lane = tid & 63, wid = tid >> 6;
  int b4 = tid * 4;
  int v0 = lh[b4], v1 = lh[b4 + 1], v2 = lh[b4 + 2], v3 = lh[b4 + 3];
  int tsum = v0 + v1 + v2 + v3;
  int incl = tsum;
  #pragma unroll
  for (int o = 1; o < 64; o <<= 1) {
    int t = __shfl_up(incl, o);
    if (lane >= o) incl += t;
  }
  if (lane == 63) wred[wid] = incl;
  __syncthreads();
  int wbase = 0;
  for (int w = 0; w < wid; ++w) wbase += wred[w];
  int excl = wbase + incl - tsum;
  loff[b4] = excl;
  loff[b4 + 1] = excl + v0;
  loff[b4 + 2] = excl + v0 + v1;
  loff[b4 + 3] = excl + v0 + v1 + v2;
  if (tid == 255) stot = excl + tsum;
  #pragma unroll
  for (int j = 0; j < 4; ++j) {
    int b = b4 + j;
    int c = lh[b];
    gb[b] = c ? atomicAdd(&bcur[seg * NBK + b], c) : 0;
  }
  __syncthreads();
  #pragma unroll
  for (int it = 0; it < 16; ++it) {
    int e = e0 + tid + (it >> 1) * 256;
    if (e < E) stage[loff[pb[it]] + pr[it]] = pkv[it];
  }
  __syncthreads();
  int tot = stot;
  for (int k = tid; k < tot; k += 256) {
    int lo = 0, hi = NBK;
    while (lo < hi) {
      int mid = (lo + hi) >> 1;
      if (loff[mid] <= k) lo = mid + 1; else hi = mid;
    }
    int b = lo - 1;
    out[gb[b] + (k - loff[b])] = stage[k];
  }
}

__global__ void bucket_csr_kernel(const int* __restrict__ binned,
                                  const int* __restrict__ bend, int E2, int N, int NBKe,
                                  int* __restrict__ deg3, int* __restrict__ rp3,
                                  int* __restrict__ col_all) {
  __shared__ int ent[BCAP];
  __shared__ int cnt[256];
  __shared__ int off[256];
  __shared__ int wred[4];
  int seg = blockIdx.x / NBKe;
  int bkt = blockIdx.x - seg * NBKe;
  int node0 = bkt << BSHIFT;
  const int* bc = bend + seg * NBK;
  int start = (bkt == 0) ? 0 : bc[bkt - 1];
  int end = bc[bkt];
  int cntE = end - start;
  const int* src = binned + (size_t)seg * E2 + start;
  bool inLds = (cntE <= BCAP);
  if (inLds)
    for (int k = threadIdx.x; k < cntE; k += 256) ent[k] = src[k];
  cnt[threadIdx.x] = 0;
  __syncthreads();
  for (int k = threadIdx.x; k < cntE; k += 256) {
    int en = inLds ? ent[k] : src[k];
    atomicAdd(&cnt[en >> 18], 1);
  }
  __syncthreads();
  int lane = threadIdx.x & 63, wid = threadIdx.x >> 6;
  int v = cnt[threadIdx.x];
  int incl = v;
  #pragma unroll
  for (int o = 1; o < 64; o <<= 1) {
    int t = __shfl_up(incl, o);
    if (lane >= o) incl += t;
  }
  if (lane == 63) wred[wid] = incl;
  __syncthreads();
  int wbase = 0;
  for (int w = 0; w < wid; ++w) wbase += wred[w];
  off[threadIdx.x] = wbase + incl - v;
  int node = node0 + (int)threadIdx.x;
  if (node < N) {
    deg3[(size_t)seg * N + node] = v;
    rp3[(size_t)seg * (N + 1) + node] = start + wbase + incl - v;
  }
  if (bkt == 0 && threadIdx.x == 0) rp3[(size_t)seg * (N + 1) + N] = E2;
  __syncthreads();
  cnt[threadIdx.x] = 0;
  __syncthreads();
  int* col = col_all + (size_t)seg * E2 + start;
  for (int k = threadIdx.x; k < cntE; k += 256) {
    int en = inLds ? ent[k] : src[k];
    int lb = en >> 18;
    int pos = atomicAdd(&cnt[lb], 1);
    col[off[lb] + pos] = en & 0x3FFFF;
  }
}

__global__ void dinv_all_kernel(const int* __restrict__ deg3, float* __restrict__ dinv5,
                                int N) {
  int n = blockIdx.x * blockDim.x + threadIdx.x;
  if (n >= N) return;
  int dt = deg3[n], d0 = deg3[N + n], d1 = deg3[2 * N + n];
  dinv5[n]         = dt ? rsqrtf((float)dt) : 0.f;
  dinv5[N + n]     = d0 ? rsqrtf((float)d0) : 0.f;
  dinv5[2 * N + n] = d1 ? rsqrtf((float)d1) : 0.f;
  int c0 = dt + d0, c1 = dt + d1;
  dinv5[3 * N + n] = c0 ? rsqrtf((float)c0) : 0.f;
  dinv5[4 * N + n] = c1 ? rsqrtf((float)c1) : 0.f;
}

__global__ void cvt_emb_kernel(const float2* __restrict__ ue, long nu2,
                               const float2* __restrict__ ie, long ni2,
                               u32* __restrict__ emb) {
  long i = (long)blockIdx.x * blockDim.x + threadIdx.x;
  if (i >= nu2 + ni2) return;
  float2 v = (i < nu2) ? ue[i] : ie[i - nu2];
  emb[i] = pk2(v.x, v.y);
}

// ================= dense propagation (bf16 rows) =================

// layer-1 for BOTH idx: Ba0/Ba1 (planar) = aux L1, Bc0/Bc1 (planar) = comb L1.
// tgt rows read ONCE. 4 lanes/node.
__global__ void gather_fused_all_kernel(const int* __restrict__ rp3,
                                        const int* __restrict__ col_all,
                                        const float* __restrict__ dinv5,
                                        const uint4* __restrict__ emb,
                                        uint4* __restrict__ BaAll, uint4* __restrict__ BcAll,
                                        int N, int E2) {
  const int* rpA0 = rp3 + (size_t)1 * (N + 1);
  const int* rpA1 = rp3 + (size_t)2 * (N + 1);
  const int* colA0 = col_all + (size_t)1 * E2;
  const int* colA1 = col_all + (size_t)2 * E2;
  const float* dvA0 = dinv5 + (size_t)1 * N;
  const float* dvA1 = dinv5 + (size_t)2 * N;
  const float* dvC0 = dinv5 + (size_t)3 * N;
  const float* dvC1 = dinv5 + (size_t)4 * N;
  int t = blockIdx.x * blockDim.x + threadIdx.x;
  int n = t >> 2;
  if (n >= N) return;
  int lane = t & 3;
  float aA0[8] = {0, 0, 0, 0, 0, 0, 0, 0};
  float aA1[8] = {0, 0, 0, 0, 0, 0, 0, 0};
  float aC0[8] = {0, 0, 0, 0, 0, 0, 0, 0};
  float aC1[8] = {0, 0, 0, 0, 0, 0, 0, 0};
  int s = rpA0[n], e = rpA0[n + 1];
  int j = s;
  for (; j + 1 < e; j += 2) {
    int c0 = colA0[j], c1 = colA0[j + 1];
    float wa0 = dvA0[c0], wc0 = dvC0[c0];
    float wa1 = dvA0[c1], wc1 = dvC0[c1];
    uint4 x0 = emb[(size_t)c0 * 4 + lane];
    uint4 x1 = emb[(size_t)c1 * 4 + lane];
    accum8(aA0, wa0, x0); accum8(aC0, wc0, x0);
    accum8(aA0, wa1, x1); accum8(aC0, wc1, x1);
  }
  if (j < e) {
    int c = colA0[j];
    float wa = dvA0[c], wc = dvC0[c];
    uint4 x = emb[(size_t)c * 4 + lane];
    accum8(aA0, wa, x); accum8(aC0, wc, x);
  }
  s = rpA1[n]; e = rpA1[n + 1];
  j = s;
  for (; j + 1 < e; j += 2) {
    int c0 = colA1[j], c1 = colA1[j + 1];
    float wa0 = dvA1[c0], wc0 = dvC1[c0];
    float wa1 = dvA1[c1], wc1 = dvC1[c1];
    uint4 x0 = emb[(size_t)c0 * 4 + lane];
    uint4 x1 = emb[(size_t)c1 * 4 + lane];
    accum8(aA1, wa0, x0); accum8(aC1, wc0, x0);
    accum8(aA1, wa1, x1); accum8(aC1, wc1, x1);
  }
  if (j < e) {
    int c = colA1[j];
    float wa = dvA1[c], wc = dvC1[c];
    uint4 x = emb[(size_t)c * 4 + lane];
    accum8(aA1, wa, x); accum8(aC1, wc, x);
  }
  s = rp3[n]; e = rp3[n + 1];
  j = s;
  for (; j + 1 < e; j += 2) {
    int c0 = col_all[j], c1 = col_all[j + 1];
    float w00 = dvC0[c0], w10 = dvC1[c0];
    float w01 = dvC0[c1], w11 = dvC1[c1];
    uint4 x0 = emb[(size_t)c0 * 4 + lane];
    uint4 x1 = emb[(size_t)c1 * 4 + lane];
    accum8(aC0, w00, x0); accum8(aC1, w10, x0);
    accum8(aC0, w01, x1); accum8(aC1, w11, x1);
  }
  if (j < e) {
    int c = col_all[j];
    float w0 = dvC0[c], w1 = dvC1[c];
    uint4 x = emb[(size_t)c * 4 + lane];
    accum8(aC0, w0, x); accum8(aC1, w1, x);
  }
  size_t o = (size_t)n * 4 + lane;
  size_t rowN4 = (size_t)N * 4;
  BaAll[o] = pack8(aA0, dvA0[n]);
  BaAll[rowN4 + o] = pack8(aA1, dvA1[n]);
  BcAll[o] = pack8(aC0, dvC0[n]);
  BcAll[rowN4 + o] = pack8(aC1, dvC1[n]);
}

// aux L2 + avg: A(idx) = (EMB + Ba + dinv*gather(Ba))/3.
// A written INTERLEAVED: node n row = [idx0 64B][idx1 64B]. 4-edge unroll.
__global__ void gather_avg_kernel(const int* __restrict__ rp3, const int* __restrict__ col_all,
                                  const float* __restrict__ dinv5,
                                  const uint4* __restrict__ emb,
                                  const uint4* __restrict__ BaAll, uint4* __restrict__ AI,
                                  int N, int E2) {
  int idx = blockIdx.y;
  const int* rp = rp3 + (size_t)(1 + idx) * (N + 1);
  const int* col = col_all + (size_t)(1 + idx) * E2;
  const float* dv = dinv5 + (size_t)(1 + idx) * N;
  const uint4* cur = BaAll + (size_t)idx * N * 4;
  int t = blockIdx.x * blockDim.x + threadIdx.x;
  int n = t >> 2;
  if (n >= N) return;
  int lane = t & 3;
  float acc[8] = {0, 0, 0, 0, 0, 0, 0, 0};
  int s = rp[n], e = rp[n + 1];
  int j = s;
  for (; j + 3 < e; j += 4) {
    int c0 = col[j], c1 = col[j + 1], c2 = col[j + 2], c3 = col[j + 3];
    float w0 = dv[c0], w1 = dv[c1], w2 = dv[c2], w3 = dv[c3];
    uint4 x0 = cur[(size_t)c0 * 4 + lane];
    uint4 x1 = cur[(size_t)c1 * 4 + lane];
    uint4 x2 = cur[(size_t)c2 * 4 + lane];
    uint4 x3 = cur[(size_t)c3 * 4 + lane];
    accum8(acc, w0, x0);
    accum8(acc, w1, x1);
    accum8(acc, w2, x2);
    accum8(acc, w3, x3);
  }
  for (; j < e; ++j) {
    int c = col[j];
    float w = dv[c];
    uint4 x = cur[(size_t)c * 4 + lane];
    accum8(acc, w, x);
  }
  float wn = dv[n];
  uint4 e4 = emb[(size_t)n * 4 + lane];
  uint4 b4 = cur[(size_t)n * 4 + lane];
  float r[8];
  r[0] = (lo16(e4.x) + lo16(b4.x) + wn * acc[0]) * (1.f / 3.f);
  r[1] = (hi16(e4.x) + hi16(b4.x) + wn * acc[1]) * (1.f / 3.f);
  r[2] = (lo16(e4.y) + lo16(b4.y) + wn * acc[2]) * (1.f / 3.f);
  r[3] = (hi16(e4.y) + hi16(b4.y) + wn * acc[3]) * (1.f / 3.f);
  r[4] = (lo16(e4.z) + lo16(b4.z) + wn * acc[4]) * (1.f / 3.f);
  r[5] = (hi16(e4.z) + hi16(b4.z) + wn * acc[5]) * (1.f / 3.f);
  r[6] = (lo16(e4.w) + lo16(b4.w) + wn * acc[6]) * (1.f / 3.f);
  r[7] = (hi16(e4.w) + hi16(b4.w) + wn * acc[7]) * (1.f / 3.f);
  AI[(size_t)n * 8 + idx * 4 + lane] = pack8(r, 1.f);
}

// de layer-1 for BOTH idx in ONE tgt pass: 8 lanes/node, lane/4 = idx half.
// Reads interleaved A (128 B/row shared), writes interleaved De.
__global__ void de_gather_kernel(const int* __restrict__ rp3, const int* __restrict__ col_all,
                                 const float* __restrict__ dinv5,
                                 const uint4* __restrict__ AI, uint4* __restrict__ DeI,
                                 int N) {
  int t = blockIdx.x * blockDim.x + threadIdx.x;
  int n = t >> 3;
  if (n >= N) return;
  int lane = t & 7;
  float acc[8] = {0, 0, 0, 0, 0, 0, 0, 0};
  int s = rp3[n], e = rp3[n + 1];
  int j = s;
  for (; j + 1 < e; j += 2) {
    int c0 = col_all[j], c1 = col_all[j + 1];
    float w0 = dinv5[c0], w1 = dinv5[c1];
    uint4 x0 = AI[(size_t)c0 * 8 + lane];
    uint4 x1 = AI[(size_t)c1 * 8 + lane];
    accum8(acc, w0, x0);
    accum8(acc, w1, x1);
  }
  if (j < e) {
    int c = col_all[j];
    float w = dinv5[c];
    uint4 x = AI[(size_t)c * 8 + lane];
    accum8(acc, w, x);
  }
  DeI[(size_t)n * 8 + lane] = pack8(acc, dinv5[n]);
}

// ================= sparse L2 + score (bf16 rows) =================

// planar rows (stride 32 u16)
__device__ __forceinline__ float fdim2(const int* __restrict__ rpA, const int* __restrict__ colA,
                                       const int* __restrict__ rpT, const int* __restrict__ colT,
                                       const float* __restrict__ dv,
                                       const u16* __restrict__ base, const u16* __restrict__ L1,
                                       int r, int d) {
  float acc = 0.f;
  for (int j = rpA[r]; j < rpA[r + 1]; ++j) {
    int c = colA[j];
    acc += dv[c] * bfat(L1, (size_t)c * D + d);
  }
  for (int j = rpT[r]; j < rpT[r + 1]; ++j) {
    int c = colT[j];
    acc += dv[c] * bfat(L1, (size_t)c * D + d);
  }
  return (bfat(base, (size_t)r * D + d) + bfat(L1, (size_t)r * D + d) + dv[r] * acc) * (1.f / 3.f);
}

// interleaved rows (stride 64 u16, idx half offset folded into d)
__device__ __forceinline__ float fdim1i(const int* __restrict__ rp, const int* __restrict__ col,
                                        const float* __restrict__ dv,
                                        const u16* __restrict__ base, const u16* __restrict__ L1,
                                        int r, int di) {
  float acc = 0.f;
  for (int j = rp[r]; j < rp[r + 1]; ++j) {
    int c = col[j];
    acc += dv[c] * bfat(L1, (size_t)c * 64 + di);
  }
  return (bfat(base, (size_t)r * 64 + di) + bfat(L1, (size_t)r * 64 + di) + dv[r] * acc) * (1.f / 3.f);
}

__global__ void ce_sparse_kernel(const int* __restrict__ rp3, const int* __restrict__ col_all,
                                 const float* __restrict__ dinv5,
                                 const u32* __restrict__ EMBu, const u32* __restrict__ BcAll,
                                 const int* __restrict__ batch, int Bsz, int Nu, int N, int E2,
                                 float* __restrict__ cps, float* __restrict__ cns) {
  int idx = blockIdx.y;
  const int* rpA = rp3 + (size_t)(1 + idx) * (N + 1);
  const int* colA = col_all + (size_t)(1 + idx) * E2;
  const float* dv = dinv5 + (size_t)(3 + idx) * N;
  const u16* base = (const u16*)EMBu;
  const u16* L1 = (const u16*)(BcAll + (size_t)idx * N * ROWU);
  float* outp = cps + (size_t)idx * Bsz;
  float* outn = cns + (size_t)idx * Bsz;
  int t = blockIdx.x * blockDim.x + threadIdx.x;
  int b = t >> 5, d = t & 31;
  if (b >= Bsz) return;
  int u = batch[b * 9 + 0];
  int p = batch[b * 9 + 1] + Nu;
  int n = batch[b * 9 + 2] + Nu;
  float uv = fdim2(rpA, colA, rp3, col_all, dv, base, L1, u, d);
  float pv = fdim2(rpA, colA, rp3, col_all, dv, base, L1, p, d);
  float nv = fdim2(rpA, colA, rp3, col_all, dv, base, L1, n, d);
  float sp = uv * pv, sn = uv * nv;
  #pragma unroll
  for (int o = 16; o > 0; o >>= 1) {
    sp += __shfl_down(sp, o, 32);
    sn += __shfl_down(sn, o, 32);
  }
  if (d == 0) {
    outp[b] = fmaxf(sp, 0.f);
    outn[b] = fmaxf(sn, 0.f);
  }
}

__global__ void de_sparse_kernel(const int* __restrict__ rp3, const int* __restrict__ col_all,
                                 const float* __restrict__ dinv5,
                                 const u32* __restrict__ AI, const u32* __restrict__ DeI,
                                 const int* __restrict__ batch, int Bsz, int Nu, int N,
                                 float* __restrict__ dps, float* __restrict__ dns) {
  int idx = blockIdx.y;
  const u16* base = (const u16*)AI;
  const u16* L1 = (const u16*)DeI;
  float* outp = dps + (size_t)idx * Bsz;
  float* outn = dns + (size_t)idx * Bsz;
  int t = blockIdx.x * blockDim.x + threadIdx.x;
  int b = t >> 5, d = t & 31;
  if (b >= Bsz) return;
  int di = idx * 32 + d;
  int u = batch[b * 9 + 0];
  int p = batch[b * 9 + 1] + Nu;
  int n = batch[b * 9 + 2] + Nu;
  float uv = fdim1i(rp3, col_all, dinv5, base, L1, u, di);
  float pv = fdim1i(rp3, col_all, dinv5, base, L1, p, di);
  float nv = fdim1i(rp3, col_all, dinv5, base, L1, n, di);
  float sp = uv * pv, sn = uv * nv;
  #pragma unroll
  for (int o = 16; o > 0; o >>= 1) {
    sp += __shfl_down(sp, o, 32);
    sn += __shfl_down(sn, o, 32);
  }
  if (d == 0) {
    outp[b] = fmaxf(sp, 0.f);
    outn[b] = fmaxf(sn, 0.f);
  }
}

// ================= batch scores / losses on interleaved A (bf16) =================

__device__ __forceinline__ float dotrow(const u32* __restrict__ a, const u32* __restrict__ b) {
  float s = 0.f;
  #pragma unroll
  for (int k = 0; k < ROWU; ++k) {
    u32 x = a[k], y = b[k];
    s += lo16(x) * lo16(y) + hi16(x) * hi16(y);
  }
  return s;
}

__global__ void score_aux_kernel(const u32* __restrict__ AI, const int* __restrict__ batch,
                                 int Bsz, int Nu, int N, float* __restrict__ aps,
                                 float* __restrict__ ans_, float* __restrict__ accs) {
  int idx = blockIdx.y;
  const u32* A = AI + (size_t)idx * ROWU;  // interleaved: row r at r*32 + idx*16
  float* outp = aps + (size_t)idx * Bsz;
  float* outn = ans_ + (size_t)idx * Bsz;
  int b = blockIdx.x * blockDim.x + threadIdx.x;
  float l = 0.f;
  if (b < Bsz) {
    int u = batch[b * 9 + 0];
    int p = batch[b * 9 + 1] + Nu;
    int n = batch[b * 9 + 2] + Nu;
    const u32* ur = A + (size_t)u * 32;
    outp[b] = fmaxf(dotrow(ur, A + (size_t)p * 32), 0.f);
    outn[b] = fmaxf(dotrow(ur, A + (size_t)n * 32), 0.f);
    const int* r = batch + b * 9 + 3 * (1 + idx);
    const u32* aur = A + (size_t)r[0] * 32;
    float ps = dotrow(aur, A + (size_t)(r[1] + Nu) * 32);
    float ns = dotrow(aur, A + (size_t)(r[2] + Nu) * 32);
    l = -logsigf(ps - ns);
  }
  for (int o = 32; o > 0; o >>= 1) l += __shfl_down(l, o);
  if ((threadIdx.x & 63) == 0) atomicAdd(&accs[idx], l);
}

__global__ void recloss_kernel(const float* __restrict__ cps, const float* __restrict__ cns,
                               const float* __restrict__ aps, const float* __restrict__ ans_,
                               const float* __restrict__ dps, const float* __restrict__ dns,
                               int Bsz, int NA, float* __restrict__ acc) {
  int b = blockIdx.x * blockDim.x + threadIdx.x;
  float l = 0.f;
  if (b < Bsz) {
    float dp = 0.f, dn = 0.f, cap = 0.f, can = 0.f;
    for (int i = 0; i < NA; ++i) {
      dp += dps[i * Bsz + b];
      dn += dns[i * Bsz + b];
      cap += cps[i * Bsz + b] * aps[i * Bsz + b];
      can += cns[i * Bsz + b] * ans_[i * Bsz + b];
    }
    l = -logsigf(dp * cap - dn * can);
  }
  for (int o = 32; o > 0; o >>= 1) l += __shfl_down(l, o);
  if ((threadIdx.x & 63) == 0) atomicAdd(acc, l);
}

__global__ void sumsq2_kernel(const float4* __restrict__ xu, int n4u,
                              const float4* __restrict__ xi, int n4i,
                              float* __restrict__ accU, float* __restrict__ accI) {
  __shared__ float redU[4], redI[4];
  int tid = threadIdx.x;
  int gid = blockIdx.x * blockDim.x + tid;
  int stride = gridDim.x * blockDim.x;
  float su = 0.f, si = 0.f;
  for (int i = gid; i < n4u; i += stride) {
    float4 v = xu[i];
    su += v.x * v.x + v.y * v.y + v.z * v.z + v.w * v.w;
  }
  for (int i = gid; i < n4i; i += stride) {
    float4 v = xi[i];
    si += v.x * v.x + v.y * v.y + v.z * v.z + v.w * v.w;
  }
  for (int o = 32; o > 0; o >>= 1) {
    su += __shfl_down(su, o);
    si += __shfl_down(si, o);
  }
  if ((tid & 63) == 0) { redU[tid >> 6] = su; redI[tid >> 6] = si; }
  __syncthreads();
  if (tid == 0) {
    atomicAdd(accU, redU[0] + redU[1] + redU[2] + redU[3]);
    atomicAdd(accI, redI[0] + redI[1] + redI[2] + redI[3]);
  }
}

__global__ void final_kernel(const float* __restrict__ accs, int Bsz, int NA, int NiRows,
                             float* __restrict__ out) {
  float rec = accs[NA] / (float)Bsz;
  float aux = 0.f;
  for (int i = 0; i < NA; ++i) aux += accs[i] / (float)Bsz;
  aux /= (float)NA;
  float embl = (sqrtf(accs[NA + 1]) + sqrtf(accs[NA + 2])) / (float)NiRows;
  out[0] = rec + 0.5f * aux + 1e-4f * embl;
}

extern "C" void kernel_launch(void* const* d_in, const int* in_sizes, int n_in,
                              void* d_out, int out_size, void* d_ws, size_t ws_size,
                              hipStream_t stream) {
  const float* user_emb = (const float*)d_in[0];
  const float* item_emb = (const float*)d_in[1];
  const int* batch = (const int*)d_in[2];
  const int* aux_edges = (const int*)d_in[3];
  const int* tgt_edges = (const int*)d_in[4];

  const int NuRows = in_sizes[0] / D;          // 100001
  const int NiRows = in_sizes[1] / D;          // 50001
  const int Bsz = in_sizes[2] / 9;             // 4096
  const int E = in_sizes[4] / 2;               // 1,000,000
  const int NA = in_sizes[3] / (2 * E);        // 2
  const int N = NuRows + NiRows;               // 150002 < 2^18 (pack invariant)
  const int E2 = 2 * E;
  const size_t rowH = (size_t)N * ROWU;
  const int BPS_H = (E + TILE_H - 1) / TILE_H;
  const int BPS_B = (E + TILE_BIN - 1) / TILE_BIN;
  const int NBKe = (N + (1 << BSHIFT) - 1) >> BSHIFT;

  // ---- workspace layout ----
  u32* EMBu = (u32*)d_ws;                 // rowH (planar)
  u32* AI = EMBu + rowH;                  // 2*rowH (INTERLEAVED per node)
  u32* BaAll = AI + 2 * rowH;             // 2*rowH (planar aux L1; later interleaved De)
  u32* BcAll = BaAll + 2 * rowH;          // 2*rowH (planar comb L1)
  int* deg3 = (int*)(BcAll + 2 * rowH);           // 3*N
  float* dinv5 = (float*)(deg3 + 3 * (size_t)N);  // 5*N
  int* rp3 = (int*)(dinv5 + 5 * (size_t)N);       // 3*(N+1)
  int* bcur = rp3 + 3 * (size_t)(N + 1);          // 3*NBK
  int* col_all = bcur + 3 * (size_t)NBK;          // 3*2E
  float* cps = (float*)(col_all + 3 * (size_t)E2);
  float* cns = cps + (size_t)NA * Bsz;
  float* aps = cns + (size_t)NA * Bsz;
  float* ans_ = aps + (size_t)NA * Bsz;
  float* dps = ans_ + (size_t)NA * Bsz;
  float* dns = dps + (size_t)NA * Bsz;
  float* accs = dns + (size_t)NA * Bsz;           // [NA aux][rec][sumsq_u][sumsq_i]
  int* binned = (int*)AI;  // 24 MB alias spanning AI+BaAll; dead before gathers

  const int TB = 256;
  const int gN = (N + TB - 1) / TB;
  const int gN4 = (N * 4 + TB - 1) / TB;
  const int gN8 = (N * 8 + TB - 1) / TB;
  const int gB = (Bsz + TB - 1) / TB;
  const int gB32 = (Bsz * 32 + TB - 1) / TB;
  const long nu2 = (long)NuRows * ROWU;
  const long ni2 = (long)NiRows * ROWU;
  const int gCvt = (int)((nu2 + ni2 + TB - 1) / TB);

  cvt_emb_kernel<<<gCvt, TB, 0, stream>>>((const float2*)user_emb, nu2,
                                          (const float2*)item_emb, ni2, EMBu);

  // ---- binned CSR build ----
  hipMemsetAsync(bcur, 0, 3 * (size_t)NBK * sizeof(int), stream);
  hist_kernel<<<3 * BPS_H, TB, 0, stream>>>((const int2*)tgt_edges, (const int2*)aux_edges,
                                            E, NuRows, BPS_H, bcur);
  bscan_kernel<<<3, 64, 0, stream>>>(bcur);
  bin_kernel<<<3 * BPS_B, TB, 0, stream>>>((const int2*)tgt_edges, (const int2*)aux_edges,
                                           E, NuRows, BPS_B, bcur, binned);
  bucket_csr_kernel<<<3 * NBKe, TB, 0, stream>>>(binned, bcur, E2, N, NBKe,
                                                 deg3, rp3, col_all);
  dinv_all_kernel<<<gN, TB, 0, stream>>>(deg3, dinv5, N);

  hipMemsetAsync(accs, 0, (size_t)(NA + 3) * sizeof(float), stream);

  dim3 gridG(gN4, NA), gridB(gB, NA), gridS(gB32, NA);

  gather_fused_all_kernel<<<gN4, TB, 0, stream>>>(rp3, col_all, dinv5, (const uint4*)EMBu,
                                                  (uint4*)BaAll, (uint4*)BcAll, N, E2);
  gather_avg_kernel<<<gridG, TB, 0, stream>>>(rp3, col_all, dinv5, (const uint4*)EMBu,
                                              (const uint4*)BaAll, (uint4*)AI, N, E2);
  score_aux_kernel<<<gridB, TB, 0, stream>>>(AI, batch, Bsz, NuRows, N, aps, ans_, accs);
  ce_sparse_kernel<<<gridS, TB, 0, stream>>>(rp3, col_all, dinv5, EMBu, BcAll,
                                             batch, Bsz, NuRows, N, E2, cps, cns);
  // single tgt pass for both idx; writes interleaved De into (dead) BaAll
  de_gather_kernel<<<gN8, TB, 0, stream>>>(rp3, col_all, dinv5, (const uint4*)AI,
                                           (uint4*)BaAll, N);
  de_sparse_kernel<<<gridS, TB, 0, stream>>>(rp3, col_all, dinv5, AI, BaAll,
                                             batch, Bsz, NuRows, N, dps, dns);

  sumsq2_kernel<<<104, TB, 0, stream>>>((const float4*)user_emb,
                                        (int)((size_t)NuRows * D / 4),
                                        (const float4*)item_emb,
                                        (int)((size_t)NiRows * D / 4),
                                        accs + NA + 1, accs + NA + 2);
  recloss_kernel<<<gB, TB, 0, stream>>>(cps, cns, aps, ans_, dps, dns, Bsz, NA, accs + NA);
  final_kernel<<<1, 1, 0, stream>>>(accs, Bsz, NA, NiRows, (float*)d_out);
}